// Round 6
// baseline (9757.630 us; speedup 1.0000x reference)
//
#include <hip/hip_runtime.h>
#include <math.h>

// ---------------- problem constants ----------------
#define K_BEAM  10
#define V_SZ    50257
#define E_SZ    128
#define H1_SZ   128
#define H2_SZ   64
#define Q_SZ    64
#define T_SZ    2048
#define MAXLEN  30
#define SEQ_LEN 31
#define SOS_TOK 1
#define EOS_TOK 2

#define NBLK 256            // stepB grid
#define NTHR 512            // threads per block (8 waves)
#define VC   197            // ceil(V_SZ / NBLK); last block vn = 22
#define XSTR 132            // sh_xs stride (bank-conflict-free for 4k+c pattern)

// ---------------- workspace layout (float indices; f64 slots at even idx) ----
#define ST_A_F   0          // double[4480]: h1[10][128],c1[10][128],h2[10][64],c2,ctx
#define ST_B_F   8960
#define SD_H1    0
#define SD_C1    1280
#define SD_H2    2560
#define SD_C2    3200
#define SD_CTX   3840
#define META_A_F 17920      // SC double[10](@0), FIN i32[10](@20), PREV i32[10](@30), SEQ i32[10][31](@40)
#define META_B_F 18272
#define M_SC     0
#define M_FIN    20
#define M_PREV   30
#define M_SEQ    40
#define XS_F     19936      // double[10][128]: {h2[64], ctx[64]} per beam (stepA -> stepB)
#define LSEM_F   83136      // double[256][10]
#define LSES_F   88256      // double[256][10]
#define CANDV_F  93376      // float[256][10][10]
#define CANDI_F  118976     // int[256][10][10]
#define B10V_F   144576     // double[10][10] per-beam top10 values
#define B10F_F   144776     // int[10][10]   per-beam top10 flat indices
// two-level election counters: per step, 8 group counters + 1 global, each on
// its own 128B line: slot(step,g) = (step*16 + g)*32 ints, g in [0,8]
#define CNT_F    145408
#define CNT_BYTES (MAXLEN * 16 * 32 * 4)

// ---------------- agent-scope atomic access (bypass non-coherent L2) ---------
// Used ONLY for intra-kernel cross-block traffic in stepB (cands/LSE/B10).
__device__ __forceinline__ double ldg_d(const double* p) {
  return __hip_atomic_load((double*)p, __ATOMIC_RELAXED, __HIP_MEMORY_SCOPE_AGENT);
}
__device__ __forceinline__ void stg_d(double* p, double v) {
  __hip_atomic_store(p, v, __ATOMIC_RELAXED, __HIP_MEMORY_SCOPE_AGENT);
}
__device__ __forceinline__ float ldg_f(const float* p) {
  return __hip_atomic_load((float*)p, __ATOMIC_RELAXED, __HIP_MEMORY_SCOPE_AGENT);
}
__device__ __forceinline__ void stg_f(float* p, float v) {
  __hip_atomic_store(p, v, __ATOMIC_RELAXED, __HIP_MEMORY_SCOPE_AGENT);
}
__device__ __forceinline__ int ldg_i(const int* p) {
  return __hip_atomic_load((int*)p, __ATOMIC_RELAXED, __HIP_MEMORY_SCOPE_AGENT);
}
__device__ __forceinline__ void stg_i(int* p, int v) {
  __hip_atomic_store(p, v, __ATOMIC_RELAXED, __HIP_MEMORY_SCOPE_AGENT);
}

// ---------------- wave helpers ----------------
__device__ __forceinline__ void wave_merge_ms_d(double& m, double& s) {
  #pragma unroll
  for (int off = 32; off > 0; off >>= 1) {
    double om = __shfl_down(m, off, 64);
    double os = __shfl_down(s, off, 64);
    double nm = fmax(m, om);
    s = s * exp(m - nm) + os * exp(om - nm);
    m = nm;
  }
}
__device__ __forceinline__ void wave_argmax_f(float& v, int& i) {
  #pragma unroll
  for (int off = 32; off > 0; off >>= 1) {
    float ov = __shfl_down(v, off, 64);
    int   oi = __shfl_down(i, off, 64);
    if (ov > v || (ov == v && oi < i)) { v = ov; i = oi; }
  }
}

// merge 100 per-beam candidates (B10V/B10F) -> global top-10. Wave 0 executes.
// SC=true uses L2-bypass loads (same-kernel stg-written data); SC=false plain.
template <bool SC>
__device__ __forceinline__ void merge100(const float* ws, double* selv, int* self_, int lane) {
  const double* bv = (const double*)(ws + B10V_F);
  const int*    bf = (const int*)(ws + B10F_F);
  double av = (lane < 100) ? (SC ? ldg_d(&bv[lane]) : bv[lane]) : -1e302;
  int    af = (lane < 100) ? (SC ? ldg_i(&bf[lane]) : bf[lane]) : 0x7fffffff;
  const int c1 = lane + 64;
  double cv = (c1 < 100) ? (SC ? ldg_d(&bv[c1]) : bv[c1]) : -1e302;
  int    cf = (c1 < 100) ? (SC ? ldg_i(&bf[c1]) : bf[c1]) : 0x7fffffff;
  #pragma unroll
  for (int pick = 0; pick < 10; ++pick) {
    bool tb = (cv > av) || (cv == av && cf < af);
    double lv = tb ? cv : av;
    int    lf = tb ? cf : af;
    int    ls = tb ? c1 : lane;
    #pragma unroll
    for (int off = 32; off > 0; off >>= 1) {
      double ov = __shfl_down(lv, off, 64);
      int    of = __shfl_down(lf, off, 64);
      int    os = __shfl_down(ls, off, 64);
      if (ov > lv || (ov == lv && of < lf)) { lv = ov; lf = of; ls = os; }
    }
    ls = __shfl(ls, 0, 64);
    if (lane == 0) { selv[pick] = lv; self_[pick] = lf; }
    if (ls == lane) { av = -1e302; af = 0x7fffffff; }
    if (ls == c1)   { cv = -1e302; cf = 0x7fffffff; }
  }
}

// ================= stepA: pick decode + LSTM1/2 + q + attention (grid 10) ====
__global__ __launch_bounds__(NTHR) void stepA_kernel(
    float* __restrict__ ws, int step,
    const float* __restrict__ embedding,
    const float* __restrict__ W_ih1, const float* __restrict__ W_hh1,
    const float* __restrict__ b_ih1, const float* __restrict__ b_hh1,
    const float* __restrict__ W_ih2, const float* __restrict__ W_hh2,
    const float* __restrict__ b_ih2, const float* __restrict__ b_hh2,
    const float* __restrict__ Wq, const float* __restrict__ bq,
    const float* __restrict__ enc_key, const float* __restrict__ enc_values,
    const float* __restrict__ maskp)
{
  const int tid  = threadIdx.x;
  const int b    = blockIdx.x;
  const int lane = tid & 63;
  const int wv   = tid >> 6;

  __shared__ double sh_e[T_SZ];
  __shared__ double sh_red[NTHR];
  __shared__ double sh_xin[192];
  __shared__ double sh_h1p[128];
  __shared__ double sh_g1[512];
  __shared__ double sh_h1n[128];
  __shared__ double sh_h2p[64];
  __shared__ double sh_gt2[256];
  __shared__ double sh_h2n[64];
  __shared__ double sh_qs[64];
  __shared__ double sh_selv[10];
  __shared__ int    sh_self[10];
  __shared__ int    sh_pb, sh_tok;

  const int par = step & 1;
  const double* S = (const double*)(ws + (par == 0 ? ST_A_F : ST_B_F));
  double*       D = (double*)(ws + (par == 0 ? ST_B_F : ST_A_F));
  const float* msrc = ws + (par == 0 ? META_A_F : META_B_F);
  float*       mdst = ws + (par == 0 ? META_B_F : META_A_F);

  // ---- step 0: init own beam's state (block-local, then read below) ----
  if (step == 0) {
    double* SA = (double*)(ws + ST_A_F);
    if (tid < 128) { SA[SD_H1 + b*H1_SZ + tid] = 0.0; SA[SD_C1 + b*H1_SZ + tid] = 0.0; }
    if (tid >= 128 && tid < 192) {
      int i2 = tid - 128;
      SA[SD_H2 + b*H2_SZ + i2] = 0.0; SA[SD_C2 + b*H2_SZ + i2] = 0.0;
      SA[SD_CTX + b*Q_SZ + i2] = 0.0;
    }
    float* mA = ws + META_A_F;
    if (tid == 0) {
      ((double*)(mA + M_SC))[b] = 0.0;
      ((int*)(mA + M_FIN))[b] = 0;
      ((int*)(mA + M_PREV))[b] = SOS_TOK;
    }
    if (tid < SEQ_LEN) ((int*)(mA + M_SEQ))[b*SEQ_LEN + tid] = SOS_TOK;
    __syncthreads();
  }

  // ---- decode pick for this beam ----
  if (step == 0) {
    if (tid == 0) {
      int tok = ((const int*)(msrc + M_PREV))[b];
      double sc = ((const double*)(msrc + M_SC))[b];
      int fin = ((const int*)(msrc + M_FIN))[b];
      sh_pb = b; sh_tok = tok;
      ((double*)(mdst + M_SC))[b] = sc;
      ((int*)(mdst + M_FIN))[b] = fin;
      ((int*)(mdst + M_PREV))[b] = tok;
    }
  } else {
    if (wv == 0) merge100<false>(ws, sh_selv, sh_self, lane);  // redundant per block
    __syncthreads();
    if (tid == 0) {
      int f = sh_self[b];
      int pb = f / V_SZ; int tok = f - pb*V_SZ;
      pb = min(max(pb, 0), K_BEAM - 1); tok = min(max(tok, 0), V_SZ - 1);
      double sc = sh_selv[b];
      int fin = ((const int*)(msrc + M_FIN))[pb] | (tok == EOS_TOK);
      sh_pb = pb; sh_tok = tok;
      ((double*)(mdst + M_SC))[b] = sc;
      ((int*)(mdst + M_FIN))[b] = fin;
      ((int*)(mdst + M_PREV))[b] = tok;
    }
  }
  __syncthreads();
  const int pb = sh_pb, tok = sh_tok;

  // seq copy + input staging
  if (tid < SEQ_LEN) {
    int v = ((const int*)(msrc + M_SEQ))[pb*SEQ_LEN + tid];
    if (step > 0 && tid == step) v = tok;
    ((int*)(mdst + M_SEQ))[b*SEQ_LEN + tid] = v;
  }
  if (tid < 128)                     sh_xin[tid] = (double)embedding[(size_t)tok*E_SZ + tid];
  else if (tid < 192)                sh_xin[tid] = S[SD_CTX + pb*Q_SZ + (tid - 128)];
  if (tid >= 256 && tid < 384)       sh_h1p[tid - 256] = S[SD_H1 + pb*H1_SZ + (tid - 256)];
  __syncthreads();

  // ---- LSTM1 gates: 512 rows, 1 row/thread ----
  {
    const int r = tid;
    double acc = (double)b_ih1[r] + (double)b_hh1[r];
    const float4* wi = (const float4*)(W_ih1 + (size_t)r*192);
    #pragma unroll 8
    for (int j = 0; j < 48; ++j) {
      float4 w = wi[j];
      acc += (double)w.x*sh_xin[4*j]   + (double)w.y*sh_xin[4*j+1]
           + (double)w.z*sh_xin[4*j+2] + (double)w.w*sh_xin[4*j+3];
    }
    const float4* wh = (const float4*)(W_hh1 + (size_t)r*128);
    #pragma unroll 8
    for (int j = 0; j < 32; ++j) {
      float4 w = wh[j];
      acc += (double)w.x*sh_h1p[4*j]   + (double)w.y*sh_h1p[4*j+1]
           + (double)w.z*sh_h1p[4*j+2] + (double)w.w*sh_h1p[4*j+3];
    }
    sh_g1[r] = acc;
  }
  __syncthreads();
  // LSTM1 activation
  if (tid < 128) {
    double ig = 1.0/(1.0 + exp(-sh_g1[tid]));
    double fg = 1.0/(1.0 + exp(-sh_g1[128 + tid]));
    double gg = tanh(sh_g1[256 + tid]);
    double og = 1.0/(1.0 + exp(-sh_g1[384 + tid]));
    double c = fg * S[SD_C1 + pb*H1_SZ + tid] + ig*gg;
    double h = og * tanh(c);
    D[SD_C1 + b*H1_SZ + tid] = c; D[SD_H1 + b*H1_SZ + tid] = h;
    sh_h1n[tid] = h;
  }
  if (tid >= 128 && tid < 192) sh_h2p[tid - 128] = S[SD_H2 + pb*H2_SZ + (tid - 128)];
  __syncthreads();

  // ---- LSTM2 gates: 256 rows ----
  if (tid < 256) {
    const int r = tid;
    double acc = (double)b_ih2[r] + (double)b_hh2[r];
    const float4* wi2 = (const float4*)(W_ih2 + (size_t)r*128);
    #pragma unroll 8
    for (int j = 0; j < 32; ++j) {
      float4 w = wi2[j];
      acc += (double)w.x*sh_h1n[4*j]   + (double)w.y*sh_h1n[4*j+1]
           + (double)w.z*sh_h1n[4*j+2] + (double)w.w*sh_h1n[4*j+3];
    }
    const float4* wh2 = (const float4*)(W_hh2 + (size_t)r*64);
    #pragma unroll 8
    for (int j = 0; j < 16; ++j) {
      float4 w = wh2[j];
      acc += (double)w.x*sh_h2p[4*j]   + (double)w.y*sh_h2p[4*j+1]
           + (double)w.z*sh_h2p[4*j+2] + (double)w.w*sh_h2p[4*j+3];
    }
    sh_gt2[r] = acc;
  }
  __syncthreads();
  // LSTM2 activation + h2 out
  if (tid < 64) {
    double ig = 1.0/(1.0 + exp(-sh_gt2[tid]));
    double fg = 1.0/(1.0 + exp(-sh_gt2[64 + tid]));
    double gg = tanh(sh_gt2[128 + tid]);
    double og = 1.0/(1.0 + exp(-sh_gt2[192 + tid]));
    double c = fg * S[SD_C2 + pb*H2_SZ + tid] + ig*gg;
    double h = og * tanh(c);
    D[SD_C2 + b*H2_SZ + tid] = c; D[SD_H2 + b*H2_SZ + tid] = h;
    sh_h2n[tid] = h;
    ((double*)(ws + XS_F))[b*128 + tid] = h;
  }
  __syncthreads();
  // q
  if (tid < 64) {
    double acc = (double)bq[tid];
    const float4* wr = (const float4*)(Wq + (size_t)tid*64);
    #pragma unroll
    for (int j = 0; j < 16; ++j) {
      float4 w = wr[j];
      acc += (double)w.x*sh_h2n[4*j]   + (double)w.y*sh_h2n[4*j+1]
           + (double)w.z*sh_h2n[4*j+2] + (double)w.w*sh_h2n[4*j+3];
    }
    sh_qs[tid] = acc;
  }
  __syncthreads();

  // ---- attention: energies, softmax, masked renorm, ctx ----
  double lmax = -1e300;
  for (int t = tid; t < T_SZ; t += NTHR) {
    const float4* kr = (const float4*)(enc_key + (size_t)t*64);
    double e = 0.0;
    #pragma unroll
    for (int j = 0; j < 16; ++j) {
      float4 k2 = kr[j];
      e += (double)k2.x*sh_qs[4*j]   + (double)k2.y*sh_qs[4*j+1]
         + (double)k2.z*sh_qs[4*j+2] + (double)k2.w*sh_qs[4*j+3];
    }
    sh_e[t] = e;
    lmax = fmax(lmax, e);
  }
  sh_red[tid] = lmax; __syncthreads();
  for (int s2 = 256; s2 > 0; s2 >>= 1) { if (tid < s2) sh_red[tid] = fmax(sh_red[tid], sh_red[tid + s2]); __syncthreads(); }
  const double mx = sh_red[0]; __syncthreads();
  double lsum = 0.0;
  for (int t = tid; t < T_SZ; t += NTHR) lsum += exp(sh_e[t] - mx);
  sh_red[tid] = lsum; __syncthreads();
  for (int s2 = 256; s2 > 0; s2 >>= 1) { if (tid < s2) sh_red[tid] += sh_red[tid + s2]; __syncthreads(); }
  const double Ss = sh_red[0]; __syncthreads();
  double lms = 0.0;
  for (int t = tid; t < T_SZ; t += NTHR) {
    double w = (double)maskp[t] * (exp(sh_e[t] - mx) / Ss);
    sh_e[t] = w;
    lms += w;
  }
  sh_red[tid] = lms; __syncthreads();
  for (int s2 = 256; s2 > 0; s2 >>= 1) { if (tid < s2) sh_red[tid] += sh_red[tid + s2]; __syncthreads(); }
  const double ms = fmax(sh_red[0], 2e-30); __syncthreads();
  {
    const int v = tid & 63, g = tid >> 6;   // 8 groups of 64
    double acc = 0.0;
    for (int k = 0; k < 256; ++k) {
      int t = g + 8*k;
      acc += sh_e[t] * (double)enc_values[(size_t)t*64 + v];
    }
    sh_red[tid] = acc;
  }
  __syncthreads();
  if (tid < 64) {
    double cv = 0.0;
    #pragma unroll
    for (int g = 0; g < 8; ++g) cv += sh_red[g*64 + tid];
    cv /= ms;
    D[SD_CTX + b*Q_SZ + tid] = cv;
    ((double*)(ws + XS_F))[b*128 + 64 + tid] = cv;
  }
}

// ================= stepB: logits + cands + last-block SEL (+final) ==========
__global__ __launch_bounds__(NTHR) void stepB_kernel(
    float* __restrict__ ws, int step, float* __restrict__ out,
    const float* __restrict__ Wc, const float* __restrict__ bc)
{
  const int tid  = threadIdx.x;
  const int blk  = blockIdx.x;
  const int lane = tid & 63;
  const int wv   = tid >> 6;

  __shared__ double sh_xs[K_BEAM*XSTR];  // stride 132: conflict-free GEMV reads
  __shared__ float  sh_lg[VC*K_BEAM];
  __shared__ double sh_wtv[80];
  __shared__ int    sh_wti[80];
  __shared__ double sh_baseArr[K_BEAM];
  __shared__ double sh_scj[K_BEAM];
  __shared__ int    sh_finj[K_BEAM];
  __shared__ double sh_selv[10];
  __shared__ int    sh_self[10];
  __shared__ int    sh_last;
  __shared__ int    sh_seqF[K_BEAM*SEQ_LEN];
  __shared__ int    sh_fpb[K_BEAM], sh_ftok[K_BEAM];

  const int v0 = blk * VC;
  const int vn = min(VC, V_SZ - v0);

  // ---- stage XS (plain loads: launch-boundary coherent) ----
  for (int i2 = tid; i2 < K_BEAM*128; i2 += NTHR) {
    int b2 = i2 >> 7, j = i2 & 127;
    sh_xs[b2*XSTR + j] = ((const double*)(ws + XS_F))[i2];
  }
  __syncthreads();

  // ---- logits GEMV: 8 lanes/row, 8 rows/wave-iteration -------------------
  // Vector load = 8 rows x one aligned 128B chunk = 8 full cachelines (1KB
  // useful); 4 independent loads/lane (MLP=4). Lane-tree reduce over k.
  {
    const int g = lane >> 3, k = lane & 7;
    for (int r0 = wv * 8; r0 < vn; r0 += 64) {
      const int r = r0 + g;
      const bool act = (r < vn);
      float4 rw0, rw1, rw2, rw3;
      double bcv = 0.0;
      if (act) {
        const float4* wr4 = (const float4*)(Wc + (size_t)(v0 + r)*128);
        rw0 = wr4[k]; rw1 = wr4[k + 8]; rw2 = wr4[k + 16]; rw3 = wr4[k + 24];
        bcv = (double)bc[v0 + r];
      } else {
        rw0 = rw1 = rw2 = rw3 = make_float4(0.f, 0.f, 0.f, 0.f);
      }
      #pragma unroll
      for (int b2 = 0; b2 < K_BEAM; ++b2) {
        const double* xb = &sh_xs[b2*XSTR];
        double p = 0.0;
        {
          const double* xp = xb + (k + 0)*4;
          p += (double)rw0.x*xp[0]; p += (double)rw0.y*xp[1];
          p += (double)rw0.z*xp[2]; p += (double)rw0.w*xp[3];
        }
        {
          const double* xp = xb + (k + 8)*4;
          p += (double)rw1.x*xp[0]; p += (double)rw1.y*xp[1];
          p += (double)rw1.z*xp[2]; p += (double)rw1.w*xp[3];
        }
        {
          const double* xp = xb + (k + 16)*4;
          p += (double)rw2.x*xp[0]; p += (double)rw2.y*xp[1];
          p += (double)rw2.z*xp[2]; p += (double)rw2.w*xp[3];
        }
        {
          const double* xp = xb + (k + 24)*4;
          p += (double)rw3.x*xp[0]; p += (double)rw3.y*xp[1];
          p += (double)rw3.z*xp[2]; p += (double)rw3.w*xp[3];
        }
        p += __shfl_xor(p, 1, 64);
        p += __shfl_xor(p, 2, 64);
        p += __shfl_xor(p, 4, 64);
        if (act && k == 0) sh_lg[r*K_BEAM + b2] = (float)(p + bcv);
      }
    }
  }
  __syncthreads();

  // ---- LSE partials + per-block top-10 per beam (sc stores: read intra-kernel by tail)
  {
    double* lse_m = (double*)(ws + LSEM_F);
    double* lse_s = (double*)(ws + LSES_F);
    float*  cvv   = ws + CANDV_F;
    int*    cii   = (int*)(ws + CANDI_F);
    for (int b2 = wv; b2 < K_BEAM; b2 += 8) {
      double m = -1e300, s = 0.0;
      for (int vl = lane; vl < vn; vl += 64) {
        double val = (double)sh_lg[vl*K_BEAM + b2];
        double nm = fmax(m, val);
        s = s*exp(m - nm) + exp(val - nm); m = nm;
      }
      wave_merge_ms_d(m, s);
      if (lane == 0) { stg_d(&lse_m[blk*K_BEAM + b2], m); stg_d(&lse_s[blk*K_BEAM + b2], s); }
      #pragma unroll
      for (int pick = 0; pick < 10; ++pick) {
        float bv = -3e38f; int bi = 0x7ffffff0;
        for (int vl = lane; vl < vn; vl += 64) {
          float val = sh_lg[vl*K_BEAM + b2];
          if (val > bv || (val == bv && vl < bi)) { bv = val; bi = vl; }
        }
        wave_argmax_f(bv, bi);
        bv = __shfl(bv, 0, 64); bi = __shfl(bi, 0, 64);
        int wi = min(max(bi, 0), vn - 1);
        if (lane == 0) {
          stg_f(&cvv[(blk*K_BEAM + b2)*10 + pick], bv);
          stg_i(&cii[(blk*K_BEAM + b2)*10 + pick], v0 + wi);
        }
        if (bi >= 0 && bi < vn && (bi & 63) == lane) sh_lg[bi*K_BEAM + b2] = -3e38f;
      }
    }
  }

  // ---- arrival: two-level election (8 groups of 32 -> global); last continues
  asm volatile("s_waitcnt vmcnt(0)" ::: "memory");
  __syncthreads();
  if (tid == 0) {
    int* cbase = (int*)(ws + CNT_F);
    int* cg = cbase + (step*16 + (blk >> 5)) * 32;
    int* cG = cbase + (step*16 + 8) * 32;
    int last = 0;
    int o = __hip_atomic_fetch_add(cg, 1, __ATOMIC_ACQ_REL, __HIP_MEMORY_SCOPE_AGENT);
    if (o == 31) {
      int og = __hip_atomic_fetch_add(cG, 1, __ATOMIC_ACQ_REL, __HIP_MEMORY_SCOPE_AGENT);
      last = (og == 7);
    }
    sh_last = last;
  }
  __syncthreads();
  if (!sh_last) return;

  // =================== tail: per-beam SEL for all 10 beams ===================
  const int par = step & 1;
  const float* mcur = ws + (par == 0 ? META_B_F : META_A_F);   // META written this step (prev launch)
  if (tid < K_BEAM) {
    sh_scj[tid]  = ((const double*)(mcur + M_SC))[tid];
    sh_finj[tid] = ((const int*)(mcur + M_FIN))[tid];
  }
  // per-beam LSE base (one wave per beam; same merge order as verified SEL)
  for (int j = wv; j < K_BEAM; j += 8) {
    double m = -1e300, s = 0.0;
    for (int c = lane; c < NBLK; c += 64) {
      double mc  = ldg_d(&((const double*)(ws + LSEM_F))[c*K_BEAM + j]);
      double sc2 = ldg_d(&((const double*)(ws + LSES_F))[c*K_BEAM + j]);
      double nm = fmax(m, mc);
      s = s*exp(m - nm) + sc2*exp(mc - nm); m = nm;
    }
    wave_merge_ms_d(m, s);
    if (lane == 0) sh_baseArr[j] = ((const double*)(mcur + M_SC))[j] - (m + log(s));
  }
  __syncthreads();

  for (int j = 0; j < K_BEAM; ++j) {
    const double scj = sh_scj[j];
    const int finj   = sh_finj[j];
    const bool masked = finj || (step == 0 && j > 0);
    const double base = sh_baseArr[j];

    // each wave: local top-10 over its 320 candidates (2560 total)
    float rv[5]; int ri[5];
    #pragma unroll
    for (int k = 0; k < 5; ++k) {
      int c = wv*320 + 64*k + lane;
      int blkc = c / 10, p = c - blkc*10;
      int idx = (blkc*K_BEAM + j)*10 + p;
      rv[k] = ldg_f(&(ws + CANDV_F)[idx]);
      ri[k] = ldg_i(&((const int*)(ws + CANDI_F))[idx]);
    }
    #pragma unroll
    for (int pick = 0; pick < 10; ++pick) {
      double lv = -1e301; int li = 0x7ffffff0;
      if (!masked) {
        #pragma unroll
        for (int k = 0; k < 5; ++k) {
          double val = base + (double)rv[k];
          int v = ri[k];
          if (val > lv || (val == lv && v < li)) { lv = val; li = v; }
        }
      }
      #pragma unroll
      for (int off = 32; off > 0; off >>= 1) {
        double ov = __shfl_down(lv, off, 64);
        int    oi = __shfl_down(li, off, 64);
        if (ov > lv || (ov == lv && oi < li)) { lv = ov; li = oi; }
      }
      lv = __shfl(lv, 0, 64); li = __shfl(li, 0, 64);
      if (!masked) {
        #pragma unroll
        for (int k = 0; k < 5; ++k) if (ri[k] == li) rv[k] = -3e38f;
      }
      if (lane == 0) { sh_wtv[wv*10 + pick] = lv; sh_wti[wv*10 + pick] = li; }
    }
    __syncthreads();

    // wave 0: merge 80 -> 10, write B10 (sc stores; next launch reads via L3)
    if (wv == 0) {
      double av = (lane < 80) ? sh_wtv[lane] : -1e305;
      int    ai = (lane < 80) ? sh_wti[lane] : 0x7fffffff;
      const int c1 = lane + 64;
      double bv2 = (c1 < 80) ? sh_wtv[c1] : -1e305;
      int    bi2 = (c1 < 80) ? sh_wti[c1] : 0x7fffffff;
      #pragma unroll
      for (int pick = 0; pick < 10; ++pick) {
        bool tb = (bv2 > av) || (bv2 == av && bi2 < ai);
        double lv = tb ? bv2 : av;
        int    li = tb ? bi2 : ai;
        int    ls = tb ? c1  : lane;
        #pragma unroll
        for (int off = 32; off > 0; off >>= 1) {
          double ov = __shfl_down(lv, off, 64);
          int    oi = __shfl_down(li, off, 64);
          int    os = __shfl_down(ls, off, 64);
          if (ov > lv || (ov == lv && oi < li)) { lv = ov; li = oi; ls = os; }
        }
        ls = __shfl(ls, 0, 64);
        if (ls == lane) { av  = -1e305; ai  = 0x7fffffff; }
        if (ls == c1)   { bv2 = -1e305; bi2 = 0x7fffffff; }
        if (lane == 0) {
          double outv; int outf;
          if (finj) {
            outv = (pick == 0) ? scj : -1e301;
            outf = (pick == 0) ? (j*V_SZ + EOS_TOK) : 0x7ffffff0;
          } else if (step == 0 && j > 0) {
            outv = -1e301; outf = 0x7ffffff0;
          } else {
            outv = lv;
            outf = j*V_SZ + min(max(li, 0), V_SZ - 1);
          }
          stg_d(&((double*)(ws + B10V_F))[j*10 + pick], outv);
          stg_i(&((int*)(ws + B10F_F))[j*10 + pick], outf);
        }
      }
    }
    __syncthreads();
  }

  // =================== final output (folded into last step's tail) ===========
  if (step == MAXLEN - 1) {
    asm volatile("s_waitcnt vmcnt(0)" ::: "memory");
    __syncthreads();
    if (wv == 0) merge100<true>(ws, sh_selv, sh_self, lane);
    __syncthreads();
    const float* mA = ws + META_A_F;              // dst of step 29 (odd -> A)
    const int* seqA = (const int*)(mA + M_SEQ);
    if (tid < K_BEAM) {
      int f = sh_self[tid];
      int pb = f / V_SZ, tk2 = f - pb*V_SZ;
      sh_fpb[tid]  = min(max(pb, 0), K_BEAM - 1);
      sh_ftok[tid] = min(max(tk2, 0), V_SZ - 1);
    }
    __syncthreads();
    for (int t = tid; t < K_BEAM*SEQ_LEN; t += NTHR) {
      int j2 = t / SEQ_LEN, p = t - j2*SEQ_LEN;
      sh_seqF[t] = (p == MAXLEN) ? sh_ftok[j2] : seqA[sh_fpb[j2]*SEQ_LEN + p];
    }
    __syncthreads();
    if (tid < K_BEAM) {
      int first = -1;
      for (int p = 1; p <= MAXLEN; ++p)
        if (sh_seqF[tid*SEQ_LEN + p] == EOS_TOK) { first = p - 1; break; }
      double len = (first >= 0) ? (double)(first + 2) : (double)(MAXLEN + 2);
      double scv = sh_selv[tid];
      out[K_BEAM*SEQ_LEN + tid] = (float)scv;
      out[K_BEAM*SEQ_LEN + K_BEAM + tid] = (float)(scv / pow(len, 1.2));
    }
    for (int t = tid; t < K_BEAM*SEQ_LEN; t += NTHR) out[t] = (float)sh_seqF[t];
  }
}

// ---------------- host ----------------
extern "C" void kernel_launch(void* const* d_in, const int* in_sizes, int n_in,
                              void* d_out, int out_size, void* d_ws, size_t ws_size,
                              hipStream_t stream) {
  (void)in_sizes; (void)n_in; (void)out_size; (void)ws_size;
  const float* enc_key    = (const float*)d_in[0];
  const float* enc_values = (const float*)d_in[1];
  const float* maskp      = (const float*)d_in[2];
  const float* embedding  = (const float*)d_in[3];
  const float* W_ih1      = (const float*)d_in[4];
  const float* W_hh1      = (const float*)d_in[5];
  const float* b_ih1      = (const float*)d_in[6];
  const float* b_hh1      = (const float*)d_in[7];
  const float* W_ih2      = (const float*)d_in[8];
  const float* W_hh2      = (const float*)d_in[9];
  const float* b_ih2      = (const float*)d_in[10];
  const float* b_hh2      = (const float*)d_in[11];
  const float* Wq         = (const float*)d_in[12];
  const float* bq         = (const float*)d_in[13];
  const float* Wc         = (const float*)d_in[14];
  const float* bc         = (const float*)d_in[15];
  float* ws  = (float*)d_ws;
  float* out = (float*)d_out;

  // zero per-step election counters (graph-capturable; re-runs on replay)
  hipMemsetAsync((char*)d_ws + (size_t)CNT_F * 4, 0, CNT_BYTES, stream);

  for (int i = 0; i < MAXLEN; ++i) {
    stepA_kernel<<<K_BEAM, NTHR, 0, stream>>>(ws, i, embedding,
        W_ih1, W_hh1, b_ih1, b_hh1, W_ih2, W_hh2, b_ih2, b_hh2,
        Wq, bq, enc_key, enc_values, maskp);
    stepB_kernel<<<NBLK, NTHR, 0, stream>>>(ws, i, out, Wc, bc);
  }
}

// Round 7
// 6835.624 us; speedup vs baseline: 1.4275x; 1.4275x over previous
//
#include <hip/hip_runtime.h>
#include <math.h>

// ---------------- problem constants ----------------
#define K_BEAM  10
#define V_SZ    50257
#define E_SZ    128
#define H1_SZ   128
#define H2_SZ   64
#define Q_SZ    64
#define T_SZ    2048
#define MAXLEN  30
#define SEQ_LEN 31
#define SOS_TOK 1
#define EOS_TOK 2

#define NBLK 256            // stepB grid
#define NTHR 512            // threads per block (8 waves)
#define VC   197            // ceil(V_SZ / NBLK); last block vn = 22
#define XSTR 132            // sh_xs stride

// ---------------- workspace layout (float indices; f64 slots at even idx) ----
#define ST_A_F   0          // double[4480]: h1[10][128],c1[10][128],h2[10][64],c2,ctx
#define ST_B_F   8960
#define SD_H1    0
#define SD_C1    1280
#define SD_H2    2560
#define SD_C2    3200
#define SD_CTX   3840
#define META_A_F 17920      // SC double[10](@0), FIN i32[10](@20), PREV i32[10](@30), SEQ i32[10][31](@40)
#define META_B_F 18272
#define M_SC     0
#define M_FIN    20
#define M_PREV   30
#define M_SEQ    40
#define XS_F     19936      // double[10][128]: {h2[64], ctx[64]} per beam (stepA -> stepB)
#define LSEM_F   83136      // double[256][10]
#define LSES_F   88256      // double[256][10]
#define CANDV_F  93376      // float[256][10][10]
#define CANDI_F  118976     // int[256][10][10]
#define B10V_F   144576     // double[10][10] per-beam top10 values
#define B10F_F   144776     // int[10][10]   per-beam top10 flat indices

// ---------------- wave helpers ----------------
__device__ __forceinline__ void wave_merge_ms_d(double& m, double& s) {
  #pragma unroll
  for (int off = 32; off > 0; off >>= 1) {
    double om = __shfl_down(m, off, 64);
    double os = __shfl_down(s, off, 64);
    double nm = fmax(m, om);
    s = s * exp(m - nm) + os * exp(om - nm);
    m = nm;
  }
}
__device__ __forceinline__ void wave_argmax_f(float& v, int& i) {
  #pragma unroll
  for (int off = 32; off > 0; off >>= 1) {
    float ov = __shfl_down(v, off, 64);
    int   oi = __shfl_down(i, off, 64);
    if (ov > v || (ov == v && oi < i)) { v = ov; i = oi; }
  }
}

// merge 100 per-beam candidates (B10V/B10F) -> global top-10. Wave 0 executes.
// Plain loads: B10 is written in a previous dispatch (launch-boundary coherent).
__device__ __forceinline__ void merge100(const float* ws, double* selv, int* self_, int lane) {
  const double* bv = (const double*)(ws + B10V_F);
  const int*    bf = (const int*)(ws + B10F_F);
  double av = (lane < 100) ? bv[lane] : -1e302;
  int    af = (lane < 100) ? bf[lane] : 0x7fffffff;
  const int c1 = lane + 64;
  double cv = (c1 < 100) ? bv[c1] : -1e302;
  int    cf = (c1 < 100) ? bf[c1] : 0x7fffffff;
  #pragma unroll
  for (int pick = 0; pick < 10; ++pick) {
    bool tb = (cv > av) || (cv == av && cf < af);
    double lv = tb ? cv : av;
    int    lf = tb ? cf : af;
    int    ls = tb ? c1 : lane;
    #pragma unroll
    for (int off = 32; off > 0; off >>= 1) {
      double ov = __shfl_down(lv, off, 64);
      int    of = __shfl_down(lf, off, 64);
      int    os = __shfl_down(ls, off, 64);
      if (ov > lv || (ov == lv && of < lf)) { lv = ov; lf = of; ls = os; }
    }
    ls = __shfl(ls, 0, 64);
    if (lane == 0) { selv[pick] = lv; self_[pick] = lf; }
    if (ls == lane) { av = -1e302; af = 0x7fffffff; }
    if (ls == c1)   { cv = -1e302; cf = 0x7fffffff; }
  }
}

// ================= stepA: pick decode + LSTM1/2 + q + attention (grid 10) ====
__global__ __launch_bounds__(NTHR) void stepA_kernel(
    float* __restrict__ ws, int step,
    const float* __restrict__ embedding,
    const float* __restrict__ W_ih1, const float* __restrict__ W_hh1,
    const float* __restrict__ b_ih1, const float* __restrict__ b_hh1,
    const float* __restrict__ W_ih2, const float* __restrict__ W_hh2,
    const float* __restrict__ b_ih2, const float* __restrict__ b_hh2,
    const float* __restrict__ Wq, const float* __restrict__ bq,
    const float* __restrict__ enc_key, const float* __restrict__ enc_values,
    const float* __restrict__ maskp)
{
  const int tid  = threadIdx.x;
  const int b    = blockIdx.x;
  const int lane = tid & 63;
  const int wv   = tid >> 6;

  __shared__ double sh_e[T_SZ];
  __shared__ double sh_red[NTHR];
  __shared__ double sh_xin[192];
  __shared__ double sh_h1p[128];
  __shared__ double sh_g1[512];
  __shared__ double sh_h1n[128];
  __shared__ double sh_h2p[64];
  __shared__ double sh_gt2[256];
  __shared__ double sh_h2n[64];
  __shared__ double sh_qs[64];
  __shared__ double sh_selv[10];
  __shared__ int    sh_self[10];
  __shared__ int    sh_pb, sh_tok;

  const int par = step & 1;
  const double* S = (const double*)(ws + (par == 0 ? ST_A_F : ST_B_F));
  double*       D = (double*)(ws + (par == 0 ? ST_B_F : ST_A_F));
  const float* msrc = ws + (par == 0 ? META_A_F : META_B_F);
  float*       mdst = ws + (par == 0 ? META_B_F : META_A_F);

  // ---- step 0: init own beam's state (block-local, then read below) ----
  if (step == 0) {
    double* SA = (double*)(ws + ST_A_F);
    if (tid < 128) { SA[SD_H1 + b*H1_SZ + tid] = 0.0; SA[SD_C1 + b*H1_SZ + tid] = 0.0; }
    if (tid >= 128 && tid < 192) {
      int i2 = tid - 128;
      SA[SD_H2 + b*H2_SZ + i2] = 0.0; SA[SD_C2 + b*H2_SZ + i2] = 0.0;
      SA[SD_CTX + b*Q_SZ + i2] = 0.0;
    }
    float* mA = ws + META_A_F;
    if (tid == 0) {
      ((double*)(mA + M_SC))[b] = 0.0;
      ((int*)(mA + M_FIN))[b] = 0;
      ((int*)(mA + M_PREV))[b] = SOS_TOK;
    }
    if (tid < SEQ_LEN) ((int*)(mA + M_SEQ))[b*SEQ_LEN + tid] = SOS_TOK;
    __syncthreads();
  }

  // ---- decode pick for this beam ----
  if (step == 0) {
    if (tid == 0) {
      int tok = ((const int*)(msrc + M_PREV))[b];
      double sc = ((const double*)(msrc + M_SC))[b];
      int fin = ((const int*)(msrc + M_FIN))[b];
      sh_pb = b; sh_tok = tok;
      ((double*)(mdst + M_SC))[b] = sc;
      ((int*)(mdst + M_FIN))[b] = fin;
      ((int*)(mdst + M_PREV))[b] = tok;
    }
  } else {
    if (wv == 0) merge100(ws, sh_selv, sh_self, lane);  // redundant per block
    __syncthreads();
    if (tid == 0) {
      int f = sh_self[b];
      int pb = f / V_SZ; int tok = f - pb*V_SZ;
      pb = min(max(pb, 0), K_BEAM - 1); tok = min(max(tok, 0), V_SZ - 1);
      double sc = sh_selv[b];
      int fin = ((const int*)(msrc + M_FIN))[pb] | (tok == EOS_TOK);
      sh_pb = pb; sh_tok = tok;
      ((double*)(mdst + M_SC))[b] = sc;
      ((int*)(mdst + M_FIN))[b] = fin;
      ((int*)(mdst + M_PREV))[b] = tok;
    }
  }
  __syncthreads();
  const int pb = sh_pb, tok = sh_tok;

  // seq copy + input staging
  if (tid < SEQ_LEN) {
    int v = ((const int*)(msrc + M_SEQ))[pb*SEQ_LEN + tid];
    if (step > 0 && tid == step) v = tok;
    ((int*)(mdst + M_SEQ))[b*SEQ_LEN + tid] = v;
  }
  if (tid < 128)                     sh_xin[tid] = (double)embedding[(size_t)tok*E_SZ + tid];
  else if (tid < 192)                sh_xin[tid] = S[SD_CTX + pb*Q_SZ + (tid - 128)];
  if (tid >= 256 && tid < 384)       sh_h1p[tid - 256] = S[SD_H1 + pb*H1_SZ + (tid - 256)];
  __syncthreads();

  // ---- LSTM1 gates: 512 rows, 1 row/thread ----
  {
    const int r = tid;
    double acc = (double)b_ih1[r] + (double)b_hh1[r];
    const float4* wi = (const float4*)(W_ih1 + (size_t)r*192);
    #pragma unroll 8
    for (int j = 0; j < 48; ++j) {
      float4 w = wi[j];
      acc += (double)w.x*sh_xin[4*j]   + (double)w.y*sh_xin[4*j+1]
           + (double)w.z*sh_xin[4*j+2] + (double)w.w*sh_xin[4*j+3];
    }
    const float4* wh = (const float4*)(W_hh1 + (size_t)r*128);
    #pragma unroll 8
    for (int j = 0; j < 32; ++j) {
      float4 w = wh[j];
      acc += (double)w.x*sh_h1p[4*j]   + (double)w.y*sh_h1p[4*j+1]
           + (double)w.z*sh_h1p[4*j+2] + (double)w.w*sh_h1p[4*j+3];
    }
    sh_g1[r] = acc;
  }
  __syncthreads();
  // LSTM1 activation
  if (tid < 128) {
    double ig = 1.0/(1.0 + exp(-sh_g1[tid]));
    double fg = 1.0/(1.0 + exp(-sh_g1[128 + tid]));
    double gg = tanh(sh_g1[256 + tid]);
    double og = 1.0/(1.0 + exp(-sh_g1[384 + tid]));
    double c = fg * S[SD_C1 + pb*H1_SZ + tid] + ig*gg;
    double h = og * tanh(c);
    D[SD_C1 + b*H1_SZ + tid] = c; D[SD_H1 + b*H1_SZ + tid] = h;
    sh_h1n[tid] = h;
  }
  if (tid >= 128 && tid < 192) sh_h2p[tid - 128] = S[SD_H2 + pb*H2_SZ + (tid - 128)];
  __syncthreads();

  // ---- LSTM2 gates: 256 rows ----
  if (tid < 256) {
    const int r = tid;
    double acc = (double)b_ih2[r] + (double)b_hh2[r];
    const float4* wi2 = (const float4*)(W_ih2 + (size_t)r*128);
    #pragma unroll 8
    for (int j = 0; j < 32; ++j) {
      float4 w = wi2[j];
      acc += (double)w.x*sh_h1n[4*j]   + (double)w.y*sh_h1n[4*j+1]
           + (double)w.z*sh_h1n[4*j+2] + (double)w.w*sh_h1n[4*j+3];
    }
    const float4* wh2 = (const float4*)(W_hh2 + (size_t)r*64);
    #pragma unroll 8
    for (int j = 0; j < 16; ++j) {
      float4 w = wh2[j];
      acc += (double)w.x*sh_h2p[4*j]   + (double)w.y*sh_h2p[4*j+1]
           + (double)w.z*sh_h2p[4*j+2] + (double)w.w*sh_h2p[4*j+3];
    }
    sh_gt2[r] = acc;
  }
  __syncthreads();
  // LSTM2 activation + h2 out
  if (tid < 64) {
    double ig = 1.0/(1.0 + exp(-sh_gt2[tid]));
    double fg = 1.0/(1.0 + exp(-sh_gt2[64 + tid]));
    double gg = tanh(sh_gt2[128 + tid]);
    double og = 1.0/(1.0 + exp(-sh_gt2[192 + tid]));
    double c = fg * S[SD_C2 + pb*H2_SZ + tid] + ig*gg;
    double h = og * tanh(c);
    D[SD_C2 + b*H2_SZ + tid] = c; D[SD_H2 + b*H2_SZ + tid] = h;
    sh_h2n[tid] = h;
    ((double*)(ws + XS_F))[b*128 + tid] = h;
  }
  __syncthreads();
  // q
  if (tid < 64) {
    double acc = (double)bq[tid];
    const float4* wr = (const float4*)(Wq + (size_t)tid*64);
    #pragma unroll
    for (int j = 0; j < 16; ++j) {
      float4 w = wr[j];
      acc += (double)w.x*sh_h2n[4*j]   + (double)w.y*sh_h2n[4*j+1]
           + (double)w.z*sh_h2n[4*j+2] + (double)w.w*sh_h2n[4*j+3];
    }
    sh_qs[tid] = acc;
  }
  __syncthreads();

  // ---- attention: energies, softmax, masked renorm, ctx ----
  double lmax = -1e300;
  for (int t = tid; t < T_SZ; t += NTHR) {
    const float4* kr = (const float4*)(enc_key + (size_t)t*64);
    double e = 0.0;
    #pragma unroll
    for (int j = 0; j < 16; ++j) {
      float4 k2 = kr[j];
      e += (double)k2.x*sh_qs[4*j]   + (double)k2.y*sh_qs[4*j+1]
         + (double)k2.z*sh_qs[4*j+2] + (double)k2.w*sh_qs[4*j+3];
    }
    sh_e[t] = e;
    lmax = fmax(lmax, e);
  }
  sh_red[tid] = lmax; __syncthreads();
  for (int s2 = 256; s2 > 0; s2 >>= 1) { if (tid < s2) sh_red[tid] = fmax(sh_red[tid], sh_red[tid + s2]); __syncthreads(); }
  const double mx = sh_red[0]; __syncthreads();
  double lsum = 0.0;
  for (int t = tid; t < T_SZ; t += NTHR) lsum += exp(sh_e[t] - mx);
  sh_red[tid] = lsum; __syncthreads();
  for (int s2 = 256; s2 > 0; s2 >>= 1) { if (tid < s2) sh_red[tid] += sh_red[tid + s2]; __syncthreads(); }
  const double Ss = sh_red[0]; __syncthreads();
  double lms = 0.0;
  for (int t = tid; t < T_SZ; t += NTHR) {
    double w = (double)maskp[t] * (exp(sh_e[t] - mx) / Ss);
    sh_e[t] = w;
    lms += w;
  }
  sh_red[tid] = lms; __syncthreads();
  for (int s2 = 256; s2 > 0; s2 >>= 1) { if (tid < s2) sh_red[tid] += sh_red[tid + s2]; __syncthreads(); }
  const double ms = fmax(sh_red[0], 2e-30); __syncthreads();
  {
    const int v = tid & 63, g = tid >> 6;   // 8 groups of 64
    double acc = 0.0;
    for (int k = 0; k < 256; ++k) {
      int t = g + 8*k;
      acc += sh_e[t] * (double)enc_values[(size_t)t*64 + v];
    }
    sh_red[tid] = acc;
  }
  __syncthreads();
  if (tid < 64) {
    double cv = 0.0;
    #pragma unroll
    for (int g = 0; g < 8; ++g) cv += sh_red[g*64 + tid];
    cv /= ms;
    D[SD_CTX + b*Q_SZ + tid] = cv;
    ((double*)(ws + XS_F))[b*128 + 64 + tid] = cv;
  }
}

// ================= stepB: logits + LSE partials + block top-10 (grid 256) ====
__global__ __launch_bounds__(NTHR, 2) void stepB_kernel(
    float* __restrict__ ws, int step,
    const float* __restrict__ Wc, const float* __restrict__ bc)
{
  const int tid  = threadIdx.x;
  const int blk  = blockIdx.x;
  const int lane = tid & 63;
  const int wv   = tid >> 6;

  __shared__ double sh_xs[K_BEAM*XSTR];  // stride 132
  __shared__ float  sh_lg[VC*K_BEAM];

  const int v0 = blk * VC;
  const int vn = min(VC, V_SZ - v0);

  // ---- stage XS (plain loads: launch-boundary coherent) ----
  for (int i2 = tid; i2 < K_BEAM*128; i2 += NTHR) {
    int b2 = i2 >> 7, j = i2 & 127;
    sh_xs[b2*XSTR + j] = ((const double*)(ws + XS_F))[i2];
  }
  __syncthreads();

  // ---- logits GEMV: 8 lanes/row, 8 rows/wave-iteration ----
  // Wave load = 8 rows x aligned 128B chunks (fully-used cachelines), 4
  // independent loads/lane (MLP=4). Beam loop split 2x5 to bound live f64
  // accumulators; per-beam FP order identical to the verified kernel.
  {
    const int g = lane >> 3, k = lane & 7;
    for (int r0 = wv * 8; r0 < vn; r0 += 64) {
      const int r = r0 + g;
      const bool act = (r < vn);
      float4 rw0, rw1, rw2, rw3;
      double bcv = 0.0;
      if (act) {
        const float4* wr4 = (const float4*)(Wc + (size_t)(v0 + r)*128);
        rw0 = wr4[k]; rw1 = wr4[k + 8]; rw2 = wr4[k + 16]; rw3 = wr4[k + 24];
        bcv = (double)bc[v0 + r];
      } else {
        rw0 = rw1 = rw2 = rw3 = make_float4(0.f, 0.f, 0.f, 0.f);
      }
      #pragma unroll
      for (int bh = 0; bh < 2; ++bh) {
        #pragma unroll
        for (int b5 = 0; b5 < 5; ++b5) {
          const int b2 = bh*5 + b5;
          const double* xb = &sh_xs[b2*XSTR];
          double p = 0.0;
          {
            const double* xp = xb + (k + 0)*4;
            p += (double)rw0.x*xp[0]; p += (double)rw0.y*xp[1];
            p += (double)rw0.z*xp[2]; p += (double)rw0.w*xp[3];
          }
          {
            const double* xp = xb + (k + 8)*4;
            p += (double)rw1.x*xp[0]; p += (double)rw1.y*xp[1];
            p += (double)rw1.z*xp[2]; p += (double)rw1.w*xp[3];
          }
          {
            const double* xp = xb + (k + 16)*4;
            p += (double)rw2.x*xp[0]; p += (double)rw2.y*xp[1];
            p += (double)rw2.z*xp[2]; p += (double)rw2.w*xp[3];
          }
          {
            const double* xp = xb + (k + 24)*4;
            p += (double)rw3.x*xp[0]; p += (double)rw3.y*xp[1];
            p += (double)rw3.z*xp[2]; p += (double)rw3.w*xp[3];
          }
          p += __shfl_xor(p, 1, 64);
          p += __shfl_xor(p, 2, 64);
          p += __shfl_xor(p, 4, 64);
          if (act && k == 0) sh_lg[r*K_BEAM + b2] = (float)(p + bcv);
        }
      }
    }
  }
  __syncthreads();

  // ---- LSE partials + per-block top-10 per beam (plain stores; next
  //      dispatch reads them across the launch boundary) ----
  {
    double* lse_m = (double*)(ws + LSEM_F);
    double* lse_s = (double*)(ws + LSES_F);
    float*  cvv   = ws + CANDV_F;
    int*    cii   = (int*)(ws + CANDI_F);
    for (int b2 = wv; b2 < K_BEAM; b2 += 8) {
      double m = -1e300, s = 0.0;
      for (int vl = lane; vl < vn; vl += 64) {
        double val = (double)sh_lg[vl*K_BEAM + b2];
        double nm = fmax(m, val);
        s = s*exp(m - nm) + exp(val - nm); m = nm;
      }
      wave_merge_ms_d(m, s);
      if (lane == 0) { lse_m[blk*K_BEAM + b2] = m; lse_s[blk*K_BEAM + b2] = s; }
      #pragma unroll
      for (int pick = 0; pick < 10; ++pick) {
        float bv = -3e38f; int bi = 0x7ffffff0;
        for (int vl = lane; vl < vn; vl += 64) {
          float val = sh_lg[vl*K_BEAM + b2];
          if (val > bv || (val == bv && vl < bi)) { bv = val; bi = vl; }
        }
        wave_argmax_f(bv, bi);
        bv = __shfl(bv, 0, 64); bi = __shfl(bi, 0, 64);
        int wi = min(max(bi, 0), vn - 1);
        if (lane == 0) {
          cvv[(blk*K_BEAM + b2)*10 + pick] = bv;
          cii[(blk*K_BEAM + b2)*10 + pick] = v0 + wi;
        }
        if (bi >= 0 && bi < vn && (bi & 63) == lane) sh_lg[bi*K_BEAM + b2] = -3e38f;
      }
    }
  }
}

// ================= stepC: per-beam SEL, one block per beam (grid 10) ========
__global__ __launch_bounds__(NTHR) void stepC_kernel(float* __restrict__ ws, int step)
{
  const int tid  = threadIdx.x;
  const int j    = blockIdx.x;
  const int lane = tid & 63;
  const int wv   = tid >> 6;

  __shared__ double sh_wtv[80];
  __shared__ int    sh_wti[80];
  __shared__ double sh_base;

  const int par = step & 1;
  const float* mcur = ws + (par == 0 ? META_B_F : META_A_F);   // META written this step by stepA
  const double scj = ((const double*)(mcur + M_SC))[j];
  const int finj   = ((const int*)(mcur + M_FIN))[j];
  const bool masked = finj || (step == 0 && j > 0);

  // per-beam LSE base (same merge order as verified SEL)
  if (wv == 0) {
    double m = -1e300, s = 0.0;
    for (int c = lane; c < NBLK; c += 64) {
      double mc  = ((const double*)(ws + LSEM_F))[c*K_BEAM + j];
      double sc2 = ((const double*)(ws + LSES_F))[c*K_BEAM + j];
      double nm = fmax(m, mc);
      s = s*exp(m - nm) + sc2*exp(mc - nm); m = nm;
    }
    wave_merge_ms_d(m, s);
    if (lane == 0) sh_base = scj - (m + log(s));
  }
  __syncthreads();
  const double base = sh_base;

  // each wave: local top-10 over its 320 candidates (2560 total)
  float rv[5]; int ri[5];
  #pragma unroll
  for (int k = 0; k < 5; ++k) {
    int c = wv*320 + 64*k + lane;
    int blkc = c / 10, p = c - blkc*10;
    int idx = (blkc*K_BEAM + j)*10 + p;
    rv[k] = (ws + CANDV_F)[idx];
    ri[k] = ((const int*)(ws + CANDI_F))[idx];
  }
  #pragma unroll
  for (int pick = 0; pick < 10; ++pick) {
    double lv = -1e301; int li = 0x7ffffff0;
    if (!masked) {
      #pragma unroll
      for (int k = 0; k < 5; ++k) {
        double val = base + (double)rv[k];
        int v = ri[k];
        if (val > lv || (val == lv && v < li)) { lv = val; li = v; }
      }
    }
    #pragma unroll
    for (int off = 32; off > 0; off >>= 1) {
      double ov = __shfl_down(lv, off, 64);
      int    oi = __shfl_down(li, off, 64);
      if (ov > lv || (ov == lv && oi < li)) { lv = ov; li = oi; }
    }
    lv = __shfl(lv, 0, 64); li = __shfl(li, 0, 64);
    if (!masked) {
      #pragma unroll
      for (int k = 0; k < 5; ++k) if (ri[k] == li) rv[k] = -3e38f;
    }
    if (lane == 0) { sh_wtv[wv*10 + pick] = lv; sh_wti[wv*10 + pick] = li; }
  }
  __syncthreads();

  // wave 0: merge 80 -> 10, write B10 (plain stores)
  if (wv == 0) {
    double av = (lane < 80) ? sh_wtv[lane] : -1e305;
    int    ai = (lane < 80) ? sh_wti[lane] : 0x7fffffff;
    const int c1 = lane + 64;
    double bv2 = (c1 < 80) ? sh_wtv[c1] : -1e305;
    int    bi2 = (c1 < 80) ? sh_wti[c1] : 0x7fffffff;
    #pragma unroll
    for (int pick = 0; pick < 10; ++pick) {
      bool tb = (bv2 > av) || (bv2 == av && bi2 < ai);
      double lv = tb ? bv2 : av;
      int    li = tb ? bi2 : ai;
      int    ls = tb ? c1  : lane;
      #pragma unroll
      for (int off = 32; off > 0; off >>= 1) {
        double ov = __shfl_down(lv, off, 64);
        int    oi = __shfl_down(li, off, 64);
        int    os = __shfl_down(ls, off, 64);
        if (ov > lv || (ov == lv && oi < li)) { lv = ov; li = oi; ls = os; }
      }
      ls = __shfl(ls, 0, 64);
      if (ls == lane) { av  = -1e305; ai  = 0x7fffffff; }
      if (ls == c1)   { bv2 = -1e305; bi2 = 0x7fffffff; }
      if (lane == 0) {
        double outv; int outf;
        if (finj) {
          outv = (pick == 0) ? scj : -1e301;
          outf = (pick == 0) ? (j*V_SZ + EOS_TOK) : 0x7ffffff0;
        } else if (step == 0 && j > 0) {
          outv = -1e301; outf = 0x7ffffff0;
        } else {
          outv = lv;
          outf = j*V_SZ + min(max(li, 0), V_SZ - 1);
        }
        ((double*)(ws + B10V_F))[j*10 + pick] = outv;
        ((int*)(ws + B10F_F))[j*10 + pick] = outf;
      }
    }
  }
}

// ================= final: merge100 + gather + output (1 block) ==============
__global__ __launch_bounds__(NTHR) void final_kernel(float* __restrict__ ws,
                                                     float* __restrict__ out)
{
  const int tid  = threadIdx.x;
  const int lane = tid & 63;
  const int wv   = tid >> 6;
  __shared__ double sh_selv[10];
  __shared__ int    sh_self[10];
  __shared__ int    sh_seqF[K_BEAM*SEQ_LEN];
  __shared__ int    sh_fpb[K_BEAM], sh_ftok[K_BEAM];

  if (wv == 0) merge100(ws, sh_selv, sh_self, lane);
  __syncthreads();
  const float* mA = ws + META_A_F;              // dst of step 29 (odd -> A)
  const int* seqA = (const int*)(mA + M_SEQ);
  if (tid < K_BEAM) {
    int f = sh_self[tid];
    int pb = f / V_SZ, tk2 = f - pb*V_SZ;
    sh_fpb[tid]  = min(max(pb, 0), K_BEAM - 1);
    sh_ftok[tid] = min(max(tk2, 0), V_SZ - 1);
  }
  __syncthreads();
  for (int t = tid; t < K_BEAM*SEQ_LEN; t += NTHR) {
    int j2 = t / SEQ_LEN, p = t - j2*SEQ_LEN;
    sh_seqF[t] = (p == MAXLEN) ? sh_ftok[j2] : seqA[sh_fpb[j2]*SEQ_LEN + p];
  }
  __syncthreads();
  if (tid < K_BEAM) {
    int first = -1;
    for (int p = 1; p <= MAXLEN; ++p)
      if (sh_seqF[tid*SEQ_LEN + p] == EOS_TOK) { first = p - 1; break; }
    double len = (first >= 0) ? (double)(first + 2) : (double)(MAXLEN + 2);
    double scv = sh_selv[tid];
    out[K_BEAM*SEQ_LEN + tid] = (float)scv;
    out[K_BEAM*SEQ_LEN + K_BEAM + tid] = (float)(scv / pow(len, 1.2));
  }
  for (int t = tid; t < K_BEAM*SEQ_LEN; t += NTHR) out[t] = (float)sh_seqF[t];
}

// ---------------- host ----------------
extern "C" void kernel_launch(void* const* d_in, const int* in_sizes, int n_in,
                              void* d_out, int out_size, void* d_ws, size_t ws_size,
                              hipStream_t stream) {
  (void)in_sizes; (void)n_in; (void)out_size; (void)ws_size;
  const float* enc_key    = (const float*)d_in[0];
  const float* enc_values = (const float*)d_in[1];
  const float* maskp      = (const float*)d_in[2];
  const float* embedding  = (const float*)d_in[3];
  const float* W_ih1      = (const float*)d_in[4];
  const float* W_hh1      = (const float*)d_in[5];
  const float* b_ih1      = (const float*)d_in[6];
  const float* b_hh1      = (const float*)d_in[7];
  const float* W_ih2      = (const float*)d_in[8];
  const float* W_hh2      = (const float*)d_in[9];
  const float* b_ih2      = (const float*)d_in[10];
  const float* b_hh2      = (const float*)d_in[11];
  const float* Wq         = (const float*)d_in[12];
  const float* bq         = (const float*)d_in[13];
  const float* Wc         = (const float*)d_in[14];
  const float* bc         = (const float*)d_in[15];
  float* ws  = (float*)d_ws;
  float* out = (float*)d_out;

  for (int i = 0; i < MAXLEN; ++i) {
    stepA_kernel<<<K_BEAM, NTHR, 0, stream>>>(ws, i, embedding,
        W_ih1, W_hh1, b_ih1, b_hh1, W_ih2, W_hh2, b_ih2, b_hh2,
        Wq, bq, enc_key, enc_values, maskp);
    stepB_kernel<<<NBLK, NTHR, 0, stream>>>(ws, i, Wc, bc);
    stepC_kernel<<<K_BEAM, NTHR, 0, stream>>>(ws, i);
  }
  final_kernel<<<1, NTHR, 0, stream>>>(ws, out);
}

// Round 8
// 5071.594 us; speedup vs baseline: 1.9240x; 1.3478x over previous
//
#include <hip/hip_runtime.h>
#include <math.h>

// ---------------- problem constants ----------------
#define K_BEAM  10
#define V_SZ    50257
#define E_SZ    128
#define H1_SZ   128
#define H2_SZ   64
#define Q_SZ    64
#define T_SZ    2048
#define MAXLEN  30
#define SEQ_LEN 31
#define SOS_TOK 1
#define EOS_TOK 2

#define NBLK 256            // stepB grid
#define NTHR 512            // threads per block (8 waves)
#define VC   197            // ceil(V_SZ / NBLK); last block vn = 22
#define XSTR 132            // sh_xs stride

// ---------------- workspace layout (float indices; f64 slots at even idx) ----
#define ST_A_F   0          // double[4480]: h1[10][128],c1[10][128],h2[10][64],c2,ctx
#define ST_B_F   8960
#define SD_H1    0
#define SD_C1    1280
#define SD_H2    2560
#define SD_C2    3200
#define SD_CTX   3840
#define META_A_F 17920      // SC double[10](@0), FIN i32[10](@20), PREV i32[10](@30), SEQ i32[10][31](@40)
#define META_B_F 18272
#define M_SC     0
#define M_FIN    20
#define M_PREV   30
#define M_SEQ    40
#define XS_F     19936      // double[10][128]: {h2[64], ctx[64]} per beam (stepA -> stepB)
#define LSEM_F   83136      // double[256][10]
#define LSES_F   88256      // double[256][10]
#define CANDV_F  93376      // float[256][10][10]
#define CANDI_F  118976     // int[256][10][10]
#define B10V_F   144576     // double[10][10] per-beam top10 values
#define B10F_F   144776     // int[10][10]   per-beam top10 flat indices

// ---------------- wave helpers ----------------
__device__ __forceinline__ void wave_merge_ms_d(double& m, double& s) {
  #pragma unroll
  for (int off = 32; off > 0; off >>= 1) {
    double om = __shfl_down(m, off, 64);
    double os = __shfl_down(s, off, 64);
    double nm = fmax(m, om);
    s = s * exp(m - nm) + os * exp(om - nm);
    m = nm;
  }
}
__device__ __forceinline__ void wave_argmax_f(float& v, int& i) {
  #pragma unroll
  for (int off = 32; off > 0; off >>= 1) {
    float ov = __shfl_down(v, off, 64);
    int   oi = __shfl_down(i, off, 64);
    if (ov > v || (ov == v && oi < i)) { v = ov; i = oi; }
  }
}

// merge 100 per-beam candidates (B10V/B10F) -> global top-10. Wave 0 executes.
// Plain loads: B10 is written in a previous dispatch (launch-boundary coherent).
__device__ __forceinline__ void merge100(const float* ws, double* selv, int* self_, int lane) {
  const double* bv = (const double*)(ws + B10V_F);
  const int*    bf = (const int*)(ws + B10F_F);
  double av = (lane < 100) ? bv[lane] : -1e302;
  int    af = (lane < 100) ? bf[lane] : 0x7fffffff;
  const int c1 = lane + 64;
  double cv = (c1 < 100) ? bv[c1] : -1e302;
  int    cf = (c1 < 100) ? bf[c1] : 0x7fffffff;
  #pragma unroll
  for (int pick = 0; pick < 10; ++pick) {
    bool tb = (cv > av) || (cv == av && cf < af);
    double lv = tb ? cv : av;
    int    lf = tb ? cf : af;
    int    ls = tb ? c1 : lane;
    #pragma unroll
    for (int off = 32; off > 0; off >>= 1) {
      double ov = __shfl_down(lv, off, 64);
      int    of = __shfl_down(lf, off, 64);
      int    os = __shfl_down(ls, off, 64);
      if (ov > lv || (ov == lv && of < lf)) { lv = ov; lf = of; ls = os; }
    }
    ls = __shfl(ls, 0, 64);
    if (lane == 0) { selv[pick] = lv; self_[pick] = lf; }
    if (ls == lane) { av = -1e302; af = 0x7fffffff; }
    if (ls == c1)   { cv = -1e302; cf = 0x7fffffff; }
  }
}

// ================= stepA: pick decode + LSTM1/2 + q + attention (grid 10) ====
// __launch_bounds__(512,2): 256-VGPR budget so the explicit load staging below
// stays in registers (R5 lesson: without the budget the compiler re-serializes).
// All staging preserves the per-accumulator FMA order -> bit-identical results.
__global__ __launch_bounds__(NTHR, 2) void stepA_kernel(
    float* __restrict__ ws, int step,
    const float* __restrict__ embedding,
    const float* __restrict__ W_ih1, const float* __restrict__ W_hh1,
    const float* __restrict__ b_ih1, const float* __restrict__ b_hh1,
    const float* __restrict__ W_ih2, const float* __restrict__ W_hh2,
    const float* __restrict__ b_ih2, const float* __restrict__ b_hh2,
    const float* __restrict__ Wq, const float* __restrict__ bq,
    const float* __restrict__ enc_key, const float* __restrict__ enc_values,
    const float* __restrict__ maskp)
{
  const int tid  = threadIdx.x;
  const int b    = blockIdx.x;
  const int lane = tid & 63;
  const int wv   = tid >> 6;

  __shared__ double sh_e[T_SZ];
  __shared__ double sh_red[NTHR];
  __shared__ double sh_xin[192];
  __shared__ double sh_h1p[128];
  __shared__ double sh_g1[512];
  __shared__ double sh_h1n[128];
  __shared__ double sh_h2p[64];
  __shared__ double sh_gt2[256];
  __shared__ double sh_h2n[64];
  __shared__ double sh_qs[64];
  __shared__ double sh_selv[10];
  __shared__ int    sh_self[10];
  __shared__ int    sh_pb, sh_tok;

  const int par = step & 1;
  const double* S = (const double*)(ws + (par == 0 ? ST_A_F : ST_B_F));
  double*       D = (double*)(ws + (par == 0 ? ST_B_F : ST_A_F));
  const float* msrc = ws + (par == 0 ? META_A_F : META_B_F);
  float*       mdst = ws + (par == 0 ? META_B_F : META_A_F);

  // ---- step 0: init own beam's state (block-local, then read below) ----
  if (step == 0) {
    double* SA = (double*)(ws + ST_A_F);
    if (tid < 128) { SA[SD_H1 + b*H1_SZ + tid] = 0.0; SA[SD_C1 + b*H1_SZ + tid] = 0.0; }
    if (tid >= 128 && tid < 192) {
      int i2 = tid - 128;
      SA[SD_H2 + b*H2_SZ + i2] = 0.0; SA[SD_C2 + b*H2_SZ + i2] = 0.0;
      SA[SD_CTX + b*Q_SZ + i2] = 0.0;
    }
    float* mA = ws + META_A_F;
    if (tid == 0) {
      ((double*)(mA + M_SC))[b] = 0.0;
      ((int*)(mA + M_FIN))[b] = 0;
      ((int*)(mA + M_PREV))[b] = SOS_TOK;
    }
    if (tid < SEQ_LEN) ((int*)(mA + M_SEQ))[b*SEQ_LEN + tid] = SOS_TOK;
    __syncthreads();
  }

  // ---- decode pick for this beam ----
  if (step == 0) {
    if (tid == 0) {
      int tok = ((const int*)(msrc + M_PREV))[b];
      double sc = ((const double*)(msrc + M_SC))[b];
      int fin = ((const int*)(msrc + M_FIN))[b];
      sh_pb = b; sh_tok = tok;
      ((double*)(mdst + M_SC))[b] = sc;
      ((int*)(mdst + M_FIN))[b] = fin;
      ((int*)(mdst + M_PREV))[b] = tok;
    }
  } else {
    if (wv == 0) merge100(ws, sh_selv, sh_self, lane);  // redundant per block
    __syncthreads();
    if (tid == 0) {
      int f = sh_self[b];
      int pb = f / V_SZ; int tok = f - pb*V_SZ;
      pb = min(max(pb, 0), K_BEAM - 1); tok = min(max(tok, 0), V_SZ - 1);
      double sc = sh_selv[b];
      int fin = ((const int*)(msrc + M_FIN))[pb] | (tok == EOS_TOK);
      sh_pb = pb; sh_tok = tok;
      ((double*)(mdst + M_SC))[b] = sc;
      ((int*)(mdst + M_FIN))[b] = fin;
      ((int*)(mdst + M_PREV))[b] = tok;
    }
  }
  __syncthreads();
  const int pb = sh_pb, tok = sh_tok;

  // seq copy + input staging
  if (tid < SEQ_LEN) {
    int v = ((const int*)(msrc + M_SEQ))[pb*SEQ_LEN + tid];
    if (step > 0 && tid == step) v = tok;
    ((int*)(mdst + M_SEQ))[b*SEQ_LEN + tid] = v;
  }
  if (tid < 128)                     sh_xin[tid] = (double)embedding[(size_t)tok*E_SZ + tid];
  else if (tid < 192)                sh_xin[tid] = S[SD_CTX + pb*Q_SZ + (tid - 128)];
  if (tid >= 256 && tid < 384)       sh_h1p[tid - 256] = S[SD_H1 + pb*H1_SZ + (tid - 256)];
  __syncthreads();

  // ---- LSTM1 gates: 512 rows, 1 row/thread; 12/8-deep staged loads ----
  {
    const int r = tid;
    double acc = (double)b_ih1[r] + (double)b_hh1[r];
    const float4* wi = (const float4*)(W_ih1 + (size_t)r*192);
    float4 st[12];
    for (int j0 = 0; j0 < 48; j0 += 12) {
      #pragma unroll
      for (int u = 0; u < 12; ++u) st[u] = wi[j0 + u];
      #pragma unroll
      for (int u = 0; u < 12; ++u) {
        const int j = j0 + u;
        acc += (double)st[u].x*sh_xin[4*j]   + (double)st[u].y*sh_xin[4*j+1]
             + (double)st[u].z*sh_xin[4*j+2] + (double)st[u].w*sh_xin[4*j+3];
      }
    }
    const float4* wh = (const float4*)(W_hh1 + (size_t)r*128);
    for (int j0 = 0; j0 < 32; j0 += 8) {
      #pragma unroll
      for (int u = 0; u < 8; ++u) st[u] = wh[j0 + u];
      #pragma unroll
      for (int u = 0; u < 8; ++u) {
        const int j = j0 + u;
        acc += (double)st[u].x*sh_h1p[4*j]   + (double)st[u].y*sh_h1p[4*j+1]
             + (double)st[u].z*sh_h1p[4*j+2] + (double)st[u].w*sh_h1p[4*j+3];
      }
    }
    sh_g1[r] = acc;
  }
  __syncthreads();
  // LSTM1 activation
  if (tid < 128) {
    double ig = 1.0/(1.0 + exp(-sh_g1[tid]));
    double fg = 1.0/(1.0 + exp(-sh_g1[128 + tid]));
    double gg = tanh(sh_g1[256 + tid]);
    double og = 1.0/(1.0 + exp(-sh_g1[384 + tid]));
    double c = fg * S[SD_C1 + pb*H1_SZ + tid] + ig*gg;
    double h = og * tanh(c);
    D[SD_C1 + b*H1_SZ + tid] = c; D[SD_H1 + b*H1_SZ + tid] = h;
    sh_h1n[tid] = h;
  }
  if (tid >= 128 && tid < 192) sh_h2p[tid - 128] = S[SD_H2 + pb*H2_SZ + (tid - 128)];
  __syncthreads();

  // ---- LSTM2 gates: 256 rows; 8-deep staged loads ----
  if (tid < 256) {
    const int r = tid;
    double acc = (double)b_ih2[r] + (double)b_hh2[r];
    const float4* wi2 = (const float4*)(W_ih2 + (size_t)r*128);
    float4 st[8];
    for (int j0 = 0; j0 < 32; j0 += 8) {
      #pragma unroll
      for (int u = 0; u < 8; ++u) st[u] = wi2[j0 + u];
      #pragma unroll
      for (int u = 0; u < 8; ++u) {
        const int j = j0 + u;
        acc += (double)st[u].x*sh_h1n[4*j]   + (double)st[u].y*sh_h1n[4*j+1]
             + (double)st[u].z*sh_h1n[4*j+2] + (double)st[u].w*sh_h1n[4*j+3];
      }
    }
    const float4* wh2 = (const float4*)(W_hh2 + (size_t)r*64);
    for (int j0 = 0; j0 < 16; j0 += 8) {
      #pragma unroll
      for (int u = 0; u < 8; ++u) st[u] = wh2[j0 + u];
      #pragma unroll
      for (int u = 0; u < 8; ++u) {
        const int j = j0 + u;
        acc += (double)st[u].x*sh_h2p[4*j]   + (double)st[u].y*sh_h2p[4*j+1]
             + (double)st[u].z*sh_h2p[4*j+2] + (double)st[u].w*sh_h2p[4*j+3];
      }
    }
    sh_gt2[r] = acc;
  }
  __syncthreads();
  // LSTM2 activation + h2 out
  if (tid < 64) {
    double ig = 1.0/(1.0 + exp(-sh_gt2[tid]));
    double fg = 1.0/(1.0 + exp(-sh_gt2[64 + tid]));
    double gg = tanh(sh_gt2[128 + tid]);
    double og = 1.0/(1.0 + exp(-sh_gt2[192 + tid]));
    double c = fg * S[SD_C2 + pb*H2_SZ + tid] + ig*gg;
    double h = og * tanh(c);
    D[SD_C2 + b*H2_SZ + tid] = c; D[SD_H2 + b*H2_SZ + tid] = h;
    sh_h2n[tid] = h;
    ((double*)(ws + XS_F))[b*128 + tid] = h;
  }
  __syncthreads();
  // q: 16-deep staged row load
  if (tid < 64) {
    double acc = (double)bq[tid];
    const float4* wr = (const float4*)(Wq + (size_t)tid*64);
    float4 st[16];
    #pragma unroll
    for (int u = 0; u < 16; ++u) st[u] = wr[u];
    #pragma unroll
    for (int j = 0; j < 16; ++j) {
      acc += (double)st[j].x*sh_h2n[4*j]   + (double)st[j].y*sh_h2n[4*j+1]
           + (double)st[j].z*sh_h2n[4*j+2] + (double)st[j].w*sh_h2n[4*j+3];
    }
    sh_qs[tid] = acc;
  }
  __syncthreads();

  // ---- attention: energies (16-deep staged), softmax, masked renorm, ctx ----
  double lmax = -1e300;
  for (int t = tid; t < T_SZ; t += NTHR) {
    const float4* kr = (const float4*)(enc_key + (size_t)t*64);
    float4 st[16];
    #pragma unroll
    for (int u = 0; u < 16; ++u) st[u] = kr[u];
    double e = 0.0;
    #pragma unroll
    for (int j = 0; j < 16; ++j) {
      e += (double)st[j].x*sh_qs[4*j]   + (double)st[j].y*sh_qs[4*j+1]
         + (double)st[j].z*sh_qs[4*j+2] + (double)st[j].w*sh_qs[4*j+3];
    }
    sh_e[t] = e;
    lmax = fmax(lmax, e);
  }
  sh_red[tid] = lmax; __syncthreads();
  for (int s2 = 256; s2 > 0; s2 >>= 1) { if (tid < s2) sh_red[tid] = fmax(sh_red[tid], sh_red[tid + s2]); __syncthreads(); }
  const double mx = sh_red[0]; __syncthreads();
  double lsum = 0.0;
  for (int t = tid; t < T_SZ; t += NTHR) lsum += exp(sh_e[t] - mx);
  sh_red[tid] = lsum; __syncthreads();
  for (int s2 = 256; s2 > 0; s2 >>= 1) { if (tid < s2) sh_red[tid] += sh_red[tid + s2]; __syncthreads(); }
  const double Ss = sh_red[0]; __syncthreads();
  double lms = 0.0;
  for (int t = tid; t < T_SZ; t += NTHR) {
    double w = (double)maskp[t] * (exp(sh_e[t] - mx) / Ss);
    sh_e[t] = w;
    lms += w;
  }
  sh_red[tid] = lms; __syncthreads();
  for (int s2 = 256; s2 > 0; s2 >>= 1) { if (tid < s2) sh_red[tid] += sh_red[tid + s2]; __syncthreads(); }
  const double ms = fmax(sh_red[0], 2e-30); __syncthreads();
  {
    const int v = tid & 63, g = tid >> 6;   // 8 groups of 64
    double acc = 0.0;
    float ev[8];
    for (int k0 = 0; k0 < 256; k0 += 8) {
      #pragma unroll
      for (int u = 0; u < 8; ++u)
        ev[u] = enc_values[(size_t)(g + 8*(k0 + u))*64 + v];
      #pragma unroll
      for (int u = 0; u < 8; ++u)
        acc += sh_e[g + 8*(k0 + u)] * (double)ev[u];
    }
    sh_red[tid] = acc;
  }
  __syncthreads();
  if (tid < 64) {
    double cv = 0.0;
    #pragma unroll
    for (int g = 0; g < 8; ++g) cv += sh_red[g*64 + tid];
    cv /= ms;
    D[SD_CTX + b*Q_SZ + tid] = cv;
    ((double*)(ws + XS_F))[b*128 + 64 + tid] = cv;
  }
}

// ================= stepB: logits + LSE partials + block top-10 (grid 256) ====
__global__ __launch_bounds__(NTHR, 2) void stepB_kernel(
    float* __restrict__ ws, int step,
    const float* __restrict__ Wc, const float* __restrict__ bc)
{
  const int tid  = threadIdx.x;
  const int blk  = blockIdx.x;
  const int lane = tid & 63;
  const int wv   = tid >> 6;

  __shared__ double sh_xs[K_BEAM*XSTR];  // stride 132
  __shared__ float  sh_lg[VC*K_BEAM];

  const int v0 = blk * VC;
  const int vn = min(VC, V_SZ - v0);

  // ---- stage XS (plain loads: launch-boundary coherent) ----
  for (int i2 = tid; i2 < K_BEAM*128; i2 += NTHR) {
    int b2 = i2 >> 7, j = i2 & 127;
    sh_xs[b2*XSTR + j] = ((const double*)(ws + XS_F))[i2];
  }
  __syncthreads();

  // ---- logits GEMV: 8 lanes/row, 8 rows/wave-iteration ----
  {
    const int g = lane >> 3, k = lane & 7;
    for (int r0 = wv * 8; r0 < vn; r0 += 64) {
      const int r = r0 + g;
      const bool act = (r < vn);
      float4 rw0, rw1, rw2, rw3;
      double bcv = 0.0;
      if (act) {
        const float4* wr4 = (const float4*)(Wc + (size_t)(v0 + r)*128);
        rw0 = wr4[k]; rw1 = wr4[k + 8]; rw2 = wr4[k + 16]; rw3 = wr4[k + 24];
        bcv = (double)bc[v0 + r];
      } else {
        rw0 = rw1 = rw2 = rw3 = make_float4(0.f, 0.f, 0.f, 0.f);
      }
      #pragma unroll
      for (int bh = 0; bh < 2; ++bh) {
        #pragma unroll
        for (int b5 = 0; b5 < 5; ++b5) {
          const int b2 = bh*5 + b5;
          const double* xb = &sh_xs[b2*XSTR];
          double p = 0.0;
          {
            const double* xp = xb + (k + 0)*4;
            p += (double)rw0.x*xp[0]; p += (double)rw0.y*xp[1];
            p += (double)rw0.z*xp[2]; p += (double)rw0.w*xp[3];
          }
          {
            const double* xp = xb + (k + 8)*4;
            p += (double)rw1.x*xp[0]; p += (double)rw1.y*xp[1];
            p += (double)rw1.z*xp[2]; p += (double)rw1.w*xp[3];
          }
          {
            const double* xp = xb + (k + 16)*4;
            p += (double)rw2.x*xp[0]; p += (double)rw2.y*xp[1];
            p += (double)rw2.z*xp[2]; p += (double)rw2.w*xp[3];
          }
          {
            const double* xp = xb + (k + 24)*4;
            p += (double)rw3.x*xp[0]; p += (double)rw3.y*xp[1];
            p += (double)rw3.z*xp[2]; p += (double)rw3.w*xp[3];
          }
          p += __shfl_xor(p, 1, 64);
          p += __shfl_xor(p, 2, 64);
          p += __shfl_xor(p, 4, 64);
          if (act && k == 0) sh_lg[r*K_BEAM + b2] = (float)(p + bcv);
        }
      }
    }
  }
  __syncthreads();

  // ---- LSE partials + per-block top-10 per beam (plain stores) ----
  {
    double* lse_m = (double*)(ws + LSEM_F);
    double* lse_s = (double*)(ws + LSES_F);
    float*  cvv   = ws + CANDV_F;
    int*    cii   = (int*)(ws + CANDI_F);
    for (int b2 = wv; b2 < K_BEAM; b2 += 8) {
      double m = -1e300, s = 0.0;
      for (int vl = lane; vl < vn; vl += 64) {
        double val = (double)sh_lg[vl*K_BEAM + b2];
        double nm = fmax(m, val);
        s = s*exp(m - nm) + exp(val - nm); m = nm;
      }
      wave_merge_ms_d(m, s);
      if (lane == 0) { lse_m[blk*K_BEAM + b2] = m; lse_s[blk*K_BEAM + b2] = s; }
      #pragma unroll
      for (int pick = 0; pick < 10; ++pick) {
        float bv = -3e38f; int bi = 0x7ffffff0;
        for (int vl = lane; vl < vn; vl += 64) {
          float val = sh_lg[vl*K_BEAM + b2];
          if (val > bv || (val == bv && vl < bi)) { bv = val; bi = vl; }
        }
        wave_argmax_f(bv, bi);
        bv = __shfl(bv, 0, 64); bi = __shfl(bi, 0, 64);
        int wi = min(max(bi, 0), vn - 1);
        if (lane == 0) {
          cvv[(blk*K_BEAM + b2)*10 + pick] = bv;
          cii[(blk*K_BEAM + b2)*10 + pick] = v0 + wi;
        }
        if (bi >= 0 && bi < vn && (bi & 63) == lane) sh_lg[bi*K_BEAM + b2] = -3e38f;
      }
    }
  }
}

// ================= stepC: per-beam SEL, one block per beam (grid 10) ========
__global__ __launch_bounds__(NTHR) void stepC_kernel(float* __restrict__ ws, int step)
{
  const int tid  = threadIdx.x;
  const int j    = blockIdx.x;
  const int lane = tid & 63;
  const int wv   = tid >> 6;

  __shared__ double sh_wtv[80];
  __shared__ int    sh_wti[80];
  __shared__ double sh_base;

  const int par = step & 1;
  const float* mcur = ws + (par == 0 ? META_B_F : META_A_F);   // META written this step by stepA
  const double scj = ((const double*)(mcur + M_SC))[j];
  const int finj   = ((const int*)(mcur + M_FIN))[j];
  const bool masked = finj || (step == 0 && j > 0);

  // per-beam LSE base (same merge order as verified SEL)
  if (wv == 0) {
    double m = -1e300, s = 0.0;
    for (int c = lane; c < NBLK; c += 64) {
      double mc  = ((const double*)(ws + LSEM_F))[c*K_BEAM + j];
      double sc2 = ((const double*)(ws + LSES_F))[c*K_BEAM + j];
      double nm = fmax(m, mc);
      s = s*exp(m - nm) + sc2*exp(mc - nm); m = nm;
    }
    wave_merge_ms_d(m, s);
    if (lane == 0) sh_base = scj - (m + log(s));
  }
  __syncthreads();
  const double base = sh_base;

  // each wave: local top-10 over its 320 candidates (2560 total)
  float rv[5]; int ri[5];
  #pragma unroll
  for (int k = 0; k < 5; ++k) {
    int c = wv*320 + 64*k + lane;
    int blkc = c / 10, p = c - blkc*10;
    int idx = (blkc*K_BEAM + j)*10 + p;
    rv[k] = (ws + CANDV_F)[idx];
    ri[k] = ((const int*)(ws + CANDI_F))[idx];
  }
  #pragma unroll
  for (int pick = 0; pick < 10; ++pick) {
    double lv = -1e301; int li = 0x7ffffff0;
    if (!masked) {
      #pragma unroll
      for (int k = 0; k < 5; ++k) {
        double val = base + (double)rv[k];
        int v = ri[k];
        if (val > lv || (val == lv && v < li)) { lv = val; li = v; }
      }
    }
    #pragma unroll
    for (int off = 32; off > 0; off >>= 1) {
      double ov = __shfl_down(lv, off, 64);
      int    oi = __shfl_down(li, off, 64);
      if (ov > lv || (ov == lv && oi < li)) { lv = ov; li = oi; }
    }
    lv = __shfl(lv, 0, 64); li = __shfl(li, 0, 64);
    if (!masked) {
      #pragma unroll
      for (int k = 0; k < 5; ++k) if (ri[k] == li) rv[k] = -3e38f;
    }
    if (lane == 0) { sh_wtv[wv*10 + pick] = lv; sh_wti[wv*10 + pick] = li; }
  }
  __syncthreads();

  // wave 0: merge 80 -> 10, write B10 (plain stores)
  if (wv == 0) {
    double av = (lane < 80) ? sh_wtv[lane] : -1e305;
    int    ai = (lane < 80) ? sh_wti[lane] : 0x7fffffff;
    const int c1 = lane + 64;
    double bv2 = (c1 < 80) ? sh_wtv[c1] : -1e305;
    int    bi2 = (c1 < 80) ? sh_wti[c1] : 0x7fffffff;
    #pragma unroll
    for (int pick = 0; pick < 10; ++pick) {
      bool tb = (bv2 > av) || (bv2 == av && bi2 < ai);
      double lv = tb ? bv2 : av;
      int    li = tb ? bi2 : ai;
      int    ls = tb ? c1  : lane;
      #pragma unroll
      for (int off = 32; off > 0; off >>= 1) {
        double ov = __shfl_down(lv, off, 64);
        int    oi = __shfl_down(li, off, 64);
        int    os = __shfl_down(ls, off, 64);
        if (ov > lv || (ov == lv && oi < li)) { lv = ov; li = oi; ls = os; }
      }
      ls = __shfl(ls, 0, 64);
      if (ls == lane) { av  = -1e305; ai  = 0x7fffffff; }
      if (ls == c1)   { bv2 = -1e305; bi2 = 0x7fffffff; }
      if (lane == 0) {
        double outv; int outf;
        if (finj) {
          outv = (pick == 0) ? scj : -1e301;
          outf = (pick == 0) ? (j*V_SZ + EOS_TOK) : 0x7ffffff0;
        } else if (step == 0 && j > 0) {
          outv = -1e301; outf = 0x7ffffff0;
        } else {
          outv = lv;
          outf = j*V_SZ + min(max(li, 0), V_SZ - 1);
        }
        ((double*)(ws + B10V_F))[j*10 + pick] = outv;
        ((int*)(ws + B10F_F))[j*10 + pick] = outf;
      }
    }
  }
}

// ================= final: merge100 + gather + output (1 block) ==============
__global__ __launch_bounds__(NTHR) void final_kernel(float* __restrict__ ws,
                                                     float* __restrict__ out)
{
  const int tid  = threadIdx.x;
  const int lane = tid & 63;
  const int wv   = tid >> 6;
  __shared__ double sh_selv[10];
  __shared__ int    sh_self[10];
  __shared__ int    sh_seqF[K_BEAM*SEQ_LEN];
  __shared__ int    sh_fpb[K_BEAM], sh_ftok[K_BEAM];

  if (wv == 0) merge100(ws, sh_selv, sh_self, lane);
  __syncthreads();
  const float* mA = ws + META_A_F;              // dst of step 29 (odd -> A)
  const int* seqA = (const int*)(mA + M_SEQ);
  if (tid < K_BEAM) {
    int f = sh_self[tid];
    int pb = f / V_SZ, tk2 = f - pb*V_SZ;
    sh_fpb[tid]  = min(max(pb, 0), K_BEAM - 1);
    sh_ftok[tid] = min(max(tk2, 0), V_SZ - 1);
  }
  __syncthreads();
  for (int t = tid; t < K_BEAM*SEQ_LEN; t += NTHR) {
    int j2 = t / SEQ_LEN, p = t - j2*SEQ_LEN;
    sh_seqF[t] = (p == MAXLEN) ? sh_ftok[j2] : seqA[sh_fpb[j2]*SEQ_LEN + p];
  }
  __syncthreads();
  if (tid < K_BEAM) {
    int first = -1;
    for (int p = 1; p <= MAXLEN; ++p)
      if (sh_seqF[tid*SEQ_LEN + p] == EOS_TOK) { first = p - 1; break; }
    double len = (first >= 0) ? (double)(first + 2) : (double)(MAXLEN + 2);
    double scv = sh_selv[tid];
    out[K_BEAM*SEQ_LEN + tid] = (float)scv;
    out[K_BEAM*SEQ_LEN + K_BEAM + tid] = (float)(scv / pow(len, 1.2));
  }
  for (int t = tid; t < K_BEAM*SEQ_LEN; t += NTHR) out[t] = (float)sh_seqF[t];
}

// ---------------- host ----------------
extern "C" void kernel_launch(void* const* d_in, const int* in_sizes, int n_in,
                              void* d_out, int out_size, void* d_ws, size_t ws_size,
                              hipStream_t stream) {
  (void)in_sizes; (void)n_in; (void)out_size; (void)ws_size;
  const float* enc_key    = (const float*)d_in[0];
  const float* enc_values = (const float*)d_in[1];
  const float* maskp      = (const float*)d_in[2];
  const float* embedding  = (const float*)d_in[3];
  const float* W_ih1      = (const float*)d_in[4];
  const float* W_hh1      = (const float*)d_in[5];
  const float* b_ih1      = (const float*)d_in[6];
  const float* b_hh1      = (const float*)d_in[7];
  const float* W_ih2      = (const float*)d_in[8];
  const float* W_hh2      = (const float*)d_in[9];
  const float* b_ih2      = (const float*)d_in[10];
  const float* b_hh2      = (const float*)d_in[11];
  const float* Wq         = (const float*)d_in[12];
  const float* bq         = (const float*)d_in[13];
  const float* Wc         = (const float*)d_in[14];
  const float* bc         = (const float*)d_in[15];
  float* ws  = (float*)d_ws;
  float* out = (float*)d_out;

  for (int i = 0; i < MAXLEN; ++i) {
    stepA_kernel<<<K_BEAM, NTHR, 0, stream>>>(ws, i, embedding,
        W_ih1, W_hh1, b_ih1, b_hh1, W_ih2, W_hh2, b_ih2, b_hh2,
        Wq, bq, enc_key, enc_values, maskp);
    stepB_kernel<<<NBLK, NTHR, 0, stream>>>(ws, i, Wc, bc);
    stepC_kernel<<<K_BEAM, NTHR, 0, stream>>>(ws, i);
  }
  final_kernel<<<1, NTHR, 0, stream>>>(ws, out);
}

// Round 10
// 3971.189 us; speedup vs baseline: 2.4571x; 1.2771x over previous
//
#include <hip/hip_runtime.h>
#include <math.h>

// ---------------- problem constants ----------------
#define K_BEAM  10
#define V_SZ    50257
#define E_SZ    128
#define H1_SZ   128
#define H2_SZ   64
#define Q_SZ    64
#define T_SZ    2048
#define MAXLEN  30
#define SEQ_LEN 31
#define SOS_TOK 1
#define EOS_TOK 2

#define NBLK 256            // stepB grid
#define NTHR 512            // threads per block (8 waves)
#define VC   197            // ceil(V_SZ / NBLK); last block vn = 22
#define XSTR 132            // sh_xs stride

// ---------------- workspace layout (float indices; f64 slots at even idx) ----
#define ST_A_F   0          // double[4480]: h1[10][128],c1[10][128],h2[10][64],c2,ctx
#define ST_B_F   8960
#define SD_H1    0
#define SD_C1    1280
#define SD_H2    2560
#define SD_C2    3200
#define SD_CTX   3840
#define META_A_F 17920      // SC double[10](@0), FIN i32[10](@20), PREV i32[10](@30), SEQ i32[10][31](@40)
#define META_B_F 18272
#define M_SC     0
#define M_FIN    20
#define M_PREV   30
#define M_SEQ    40
#define XS_F     19936      // double[10][128]: {h2[64], ctx[64]} per beam (stepA -> stepB)
#define LSEM_F   83136      // double[256][10]
#define LSES_F   88256      // double[256][10]
#define CANDV_F  93376      // float[256][10][10]
#define CANDI_F  118976     // int[256][10][10]
#define B10V_F   144576     // double[10][10] per-beam top10 values
#define B10F_F   144776     // int[10][10]   per-beam top10 flat indices

// ---------------- wave helpers ----------------
__device__ __forceinline__ void wave_merge_ms_d(double& m, double& s) {
  #pragma unroll
  for (int off = 32; off > 0; off >>= 1) {
    double om = __shfl_down(m, off, 64);
    double os = __shfl_down(s, off, 64);
    double nm = fmax(m, om);
    s = s * exp(m - nm) + os * exp(om - nm);
    m = nm;
  }
}
__device__ __forceinline__ void wave_argmax_f(float& v, int& i) {
  #pragma unroll
  for (int off = 32; off > 0; off >>= 1) {
    float ov = __shfl_down(v, off, 64);
    int   oi = __shfl_down(i, off, 64);
    if (ov > v || (ov == v && oi < i)) { v = ov; i = oi; }
  }
}

// merge 100 per-beam candidates (B10V/B10F) -> global top-10. Wave 0 executes.
// Plain loads: B10 is written in a previous dispatch (launch-boundary coherent).
__device__ __forceinline__ void merge100(const float* ws, double* selv, int* self_, int lane) {
  const double* bv = (const double*)(ws + B10V_F);
  const int*    bf = (const int*)(ws + B10F_F);
  double av = (lane < 100) ? bv[lane] : -1e302;
  int    af = (lane < 100) ? bf[lane] : 0x7fffffff;
  const int c1 = lane + 64;
  double cv = (c1 < 100) ? bv[c1] : -1e302;
  int    cf = (c1 < 100) ? bf[c1] : 0x7fffffff;
  #pragma unroll
  for (int pick = 0; pick < 10; ++pick) {
    bool tb = (cv > av) || (cv == av && cf < af);
    double lv = tb ? cv : av;
    int    lf = tb ? cf : af;
    int    ls = tb ? c1 : lane;
    #pragma unroll
    for (int off = 32; off > 0; off >>= 1) {
      double ov = __shfl_down(lv, off, 64);
      int    of = __shfl_down(lf, off, 64);
      int    os = __shfl_down(ls, off, 64);
      if (ov > lv || (ov == lv && of < lf)) { lv = ov; lf = of; ls = os; }
    }
    ls = __shfl(ls, 0, 64);
    if (lane == 0) { selv[pick] = lv; self_[pick] = lf; }
    if (ls == lane) { av = -1e302; af = 0x7fffffff; }
    if (ls == c1)   { cv = -1e302; cf = 0x7fffffff; }
  }
}

// ================= stepA: pick decode + LSTM1/2 + q + attention (grid 10) ====
// __launch_bounds__(512,2): 256-VGPR budget so the explicit load staging below
// stays in registers. All staging preserves per-accumulator FMA order.
__global__ __launch_bounds__(NTHR, 2) void stepA_kernel(
    float* __restrict__ ws, int step,
    const float* __restrict__ embedding,
    const float* __restrict__ W_ih1, const float* __restrict__ W_hh1,
    const float* __restrict__ b_ih1, const float* __restrict__ b_hh1,
    const float* __restrict__ W_ih2, const float* __restrict__ W_hh2,
    const float* __restrict__ b_ih2, const float* __restrict__ b_hh2,
    const float* __restrict__ Wq, const float* __restrict__ bq,
    const float* __restrict__ enc_key, const float* __restrict__ enc_values,
    const float* __restrict__ maskp)
{
  const int tid  = threadIdx.x;
  const int b    = blockIdx.x;
  const int lane = tid & 63;
  const int wv   = tid >> 6;

  __shared__ double sh_e[T_SZ];
  __shared__ double sh_red[NTHR];
  __shared__ double sh_xin[192];
  __shared__ double sh_h1p[128];
  __shared__ double sh_g1[512];
  __shared__ double sh_h1n[128];
  __shared__ double sh_h2p[64];
  __shared__ double sh_gt2[256];
  __shared__ double sh_h2n[64];
  __shared__ double sh_qs[64];
  __shared__ double sh_selv[10];
  __shared__ int    sh_self[10];
  __shared__ int    sh_pb, sh_tok;

  const int par = step & 1;
  const double* S = (const double*)(ws + (par == 0 ? ST_A_F : ST_B_F));
  double*       D = (double*)(ws + (par == 0 ? ST_B_F : ST_A_F));
  const float* msrc = ws + (par == 0 ? META_A_F : META_B_F);
  float*       mdst = ws + (par == 0 ? META_B_F : META_A_F);

  // ---- step 0: init own beam's state (block-local, then read below) ----
  if (step == 0) {
    double* SA = (double*)(ws + ST_A_F);
    if (tid < 128) { SA[SD_H1 + b*H1_SZ + tid] = 0.0; SA[SD_C1 + b*H1_SZ + tid] = 0.0; }
    if (tid >= 128 && tid < 192) {
      int i2 = tid - 128;
      SA[SD_H2 + b*H2_SZ + i2] = 0.0; SA[SD_C2 + b*H2_SZ + i2] = 0.0;
      SA[SD_CTX + b*Q_SZ + i2] = 0.0;
    }
    float* mA = ws + META_A_F;
    if (tid == 0) {
      ((double*)(mA + M_SC))[b] = 0.0;
      ((int*)(mA + M_FIN))[b] = 0;
      ((int*)(mA + M_PREV))[b] = SOS_TOK;
    }
    if (tid < SEQ_LEN) ((int*)(mA + M_SEQ))[b*SEQ_LEN + tid] = SOS_TOK;
    __syncthreads();
  }

  // ---- decode pick for this beam ----
  if (step == 0) {
    if (tid == 0) {
      int tok = ((const int*)(msrc + M_PREV))[b];
      double sc = ((const double*)(msrc + M_SC))[b];
      int fin = ((const int*)(msrc + M_FIN))[b];
      sh_pb = b; sh_tok = tok;
      ((double*)(mdst + M_SC))[b] = sc;
      ((int*)(mdst + M_FIN))[b] = fin;
      ((int*)(mdst + M_PREV))[b] = tok;
    }
  } else {
    if (wv == 0) merge100(ws, sh_selv, sh_self, lane);  // redundant per block
    __syncthreads();
    if (tid == 0) {
      int f = sh_self[b];
      int pb = f / V_SZ; int tok = f - pb*V_SZ;
      pb = min(max(pb, 0), K_BEAM - 1); tok = min(max(tok, 0), V_SZ - 1);
      double sc = sh_selv[b];
      int fin = ((const int*)(msrc + M_FIN))[pb] | (tok == EOS_TOK);
      sh_pb = pb; sh_tok = tok;
      ((double*)(mdst + M_SC))[b] = sc;
      ((int*)(mdst + M_FIN))[b] = fin;
      ((int*)(mdst + M_PREV))[b] = tok;
    }
  }
  __syncthreads();
  const int pb = sh_pb, tok = sh_tok;

  // seq copy + input staging
  if (tid < SEQ_LEN) {
    int v = ((const int*)(msrc + M_SEQ))[pb*SEQ_LEN + tid];
    if (step > 0 && tid == step) v = tok;
    ((int*)(mdst + M_SEQ))[b*SEQ_LEN + tid] = v;
  }
  if (tid < 128)                     sh_xin[tid] = (double)embedding[(size_t)tok*E_SZ + tid];
  else if (tid < 192)                sh_xin[tid] = S[SD_CTX + pb*Q_SZ + (tid - 128)];
  if (tid >= 256 && tid < 384)       sh_h1p[tid - 256] = S[SD_H1 + pb*H1_SZ + (tid - 256)];
  __syncthreads();

  // ---- LSTM1 gates: 512 rows, 1 row/thread; 12/8-deep staged loads ----
  {
    const int r = tid;
    double acc = (double)b_ih1[r] + (double)b_hh1[r];
    const float4* wi = (const float4*)(W_ih1 + (size_t)r*192);
    float4 st[12];
    for (int j0 = 0; j0 < 48; j0 += 12) {
      #pragma unroll
      for (int u = 0; u < 12; ++u) st[u] = wi[j0 + u];
      #pragma unroll
      for (int u = 0; u < 12; ++u) {
        const int j = j0 + u;
        acc += (double)st[u].x*sh_xin[4*j]   + (double)st[u].y*sh_xin[4*j+1]
             + (double)st[u].z*sh_xin[4*j+2] + (double)st[u].w*sh_xin[4*j+3];
      }
    }
    const float4* wh = (const float4*)(W_hh1 + (size_t)r*128);
    for (int j0 = 0; j0 < 32; j0 += 8) {
      #pragma unroll
      for (int u = 0; u < 8; ++u) st[u] = wh[j0 + u];
      #pragma unroll
      for (int u = 0; u < 8; ++u) {
        const int j = j0 + u;
        acc += (double)st[u].x*sh_h1p[4*j]   + (double)st[u].y*sh_h1p[4*j+1]
             + (double)st[u].z*sh_h1p[4*j+2] + (double)st[u].w*sh_h1p[4*j+3];
      }
    }
    sh_g1[r] = acc;
  }
  __syncthreads();
  // LSTM1 activation
  if (tid < 128) {
    double ig = 1.0/(1.0 + exp(-sh_g1[tid]));
    double fg = 1.0/(1.0 + exp(-sh_g1[128 + tid]));
    double gg = tanh(sh_g1[256 + tid]);
    double og = 1.0/(1.0 + exp(-sh_g1[384 + tid]));
    double c = fg * S[SD_C1 + pb*H1_SZ + tid] + ig*gg;
    double h = og * tanh(c);
    D[SD_C1 + b*H1_SZ + tid] = c; D[SD_H1 + b*H1_SZ + tid] = h;
    sh_h1n[tid] = h;
  }
  if (tid >= 128 && tid < 192) sh_h2p[tid - 128] = S[SD_H2 + pb*H2_SZ + (tid - 128)];
  __syncthreads();

  // ---- LSTM2 gates: 256 rows; 8-deep staged loads ----
  if (tid < 256) {
    const int r = tid;
    double acc = (double)b_ih2[r] + (double)b_hh2[r];
    const float4* wi2 = (const float4*)(W_ih2 + (size_t)r*128);
    float4 st[8];
    for (int j0 = 0; j0 < 32; j0 += 8) {
      #pragma unroll
      for (int u = 0; u < 8; ++u) st[u] = wi2[j0 + u];
      #pragma unroll
      for (int u = 0; u < 8; ++u) {
        const int j = j0 + u;
        acc += (double)st[u].x*sh_h1n[4*j]   + (double)st[u].y*sh_h1n[4*j+1]
             + (double)st[u].z*sh_h1n[4*j+2] + (double)st[u].w*sh_h1n[4*j+3];
      }
    }
    const float4* wh2 = (const float4*)(W_hh2 + (size_t)r*64);
    for (int j0 = 0; j0 < 16; j0 += 8) {
      #pragma unroll
      for (int u = 0; u < 8; ++u) st[u] = wh2[j0 + u];
      #pragma unroll
      for (int u = 0; u < 8; ++u) {
        const int j = j0 + u;
        acc += (double)st[u].x*sh_h2p[4*j]   + (double)st[u].y*sh_h2p[4*j+1]
             + (double)st[u].z*sh_h2p[4*j+2] + (double)st[u].w*sh_h2p[4*j+3];
      }
    }
    sh_gt2[r] = acc;
  }
  __syncthreads();
  // LSTM2 activation + h2 out
  if (tid < 64) {
    double ig = 1.0/(1.0 + exp(-sh_gt2[tid]));
    double fg = 1.0/(1.0 + exp(-sh_gt2[64 + tid]));
    double gg = tanh(sh_gt2[128 + tid]);
    double og = 1.0/(1.0 + exp(-sh_gt2[192 + tid]));
    double c = fg * S[SD_C2 + pb*H2_SZ + tid] + ig*gg;
    double h = og * tanh(c);
    D[SD_C2 + b*H2_SZ + tid] = c; D[SD_H2 + b*H2_SZ + tid] = h;
    sh_h2n[tid] = h;
    ((double*)(ws + XS_F))[b*128 + tid] = h;
  }
  __syncthreads();
  // q: 16-deep staged row load
  if (tid < 64) {
    double acc = (double)bq[tid];
    const float4* wr = (const float4*)(Wq + (size_t)tid*64);
    float4 st[16];
    #pragma unroll
    for (int u = 0; u < 16; ++u) st[u] = wr[u];
    #pragma unroll
    for (int j = 0; j < 16; ++j) {
      acc += (double)st[j].x*sh_h2n[4*j]   + (double)st[j].y*sh_h2n[4*j+1]
           + (double)st[j].z*sh_h2n[4*j+2] + (double)st[j].w*sh_h2n[4*j+3];
    }
    sh_qs[tid] = acc;
  }
  __syncthreads();

  // ---- attention: energies (16-deep staged), softmax, masked renorm, ctx ----
  double lmax = -1e300;
  for (int t = tid; t < T_SZ; t += NTHR) {
    const float4* kr = (const float4*)(enc_key + (size_t)t*64);
    float4 st[16];
    #pragma unroll
    for (int u = 0; u < 16; ++u) st[u] = kr[u];
    double e = 0.0;
    #pragma unroll
    for (int j = 0; j < 16; ++j) {
      e += (double)st[j].x*sh_qs[4*j]   + (double)st[j].y*sh_qs[4*j+1]
         + (double)st[j].z*sh_qs[4*j+2] + (double)st[j].w*sh_qs[4*j+3];
    }
    sh_e[t] = e;
    lmax = fmax(lmax, e);
  }
  sh_red[tid] = lmax; __syncthreads();
  for (int s2 = 256; s2 > 0; s2 >>= 1) { if (tid < s2) sh_red[tid] = fmax(sh_red[tid], sh_red[tid + s2]); __syncthreads(); }
  const double mx = sh_red[0]; __syncthreads();
  double lsum = 0.0;
  for (int t = tid; t < T_SZ; t += NTHR) lsum += exp(sh_e[t] - mx);
  sh_red[tid] = lsum; __syncthreads();
  for (int s2 = 256; s2 > 0; s2 >>= 1) { if (tid < s2) sh_red[tid] += sh_red[tid + s2]; __syncthreads(); }
  const double Ss = sh_red[0]; __syncthreads();
  double lms = 0.0;
  for (int t = tid; t < T_SZ; t += NTHR) {
    double w = (double)maskp[t] * (exp(sh_e[t] - mx) / Ss);
    sh_e[t] = w;
    lms += w;
  }
  sh_red[tid] = lms; __syncthreads();
  for (int s2 = 256; s2 > 0; s2 >>= 1) { if (tid < s2) sh_red[tid] += sh_red[tid + s2]; __syncthreads(); }
  const double ms = fmax(sh_red[0], 2e-30); __syncthreads();
  {
    const int v = tid & 63, g = tid >> 6;   // 8 groups of 64
    double acc = 0.0;
    float ev[8];
    for (int k0 = 0; k0 < 256; k0 += 8) {
      #pragma unroll
      for (int u = 0; u < 8; ++u)
        ev[u] = enc_values[(size_t)(g + 8*(k0 + u))*64 + v];
      #pragma unroll
      for (int u = 0; u < 8; ++u)
        acc += sh_e[g + 8*(k0 + u)] * (double)ev[u];
    }
    sh_red[tid] = acc;
  }
  __syncthreads();
  if (tid < 64) {
    double cv = 0.0;
    #pragma unroll
    for (int g = 0; g < 8; ++g) cv += sh_red[g*64 + tid];
    cv /= ms;
    D[SD_CTX + b*Q_SZ + tid] = cv;
    ((double*)(ws + XS_F))[b*128 + 64 + tid] = cv;
  }
}

// ================= stepB: logits + LSE partials + block top-10 (grid 256) ====
__global__ __launch_bounds__(NTHR, 2) void stepB_kernel(
    float* __restrict__ ws, int step,
    const float* __restrict__ Wc, const float* __restrict__ bc)
{
  const int tid  = threadIdx.x;
  const int blk  = blockIdx.x;
  const int lane = tid & 63;
  const int wv   = tid >> 6;

  __shared__ double sh_xs[K_BEAM*XSTR];  // stride 132
  __shared__ float  sh_lg[VC*K_BEAM];

  const int v0 = blk * VC;
  const int vn = min(VC, V_SZ - v0);

  // ---- stage XS (plain loads: launch-boundary coherent) ----
  for (int i2 = tid; i2 < K_BEAM*128; i2 += NTHR) {
    int b2 = i2 >> 7, j = i2 & 127;
    sh_xs[b2*XSTR + j] = ((const double*)(ws + XS_F))[i2];
  }
  __syncthreads();

  // ---- logits GEMV: 8 lanes/row, 8 rows/wave-iteration ----
  // unroll 1 on the beam loop: ONE p-chain live at a time (R8 post-mortem:
  // full unroll interleaved 10 chains -> 128-VGPR cap exceeded -> 60 MB/dispatch
  // scratch spill). Per-accumulator FMA order unchanged -> bit-identical.
  {
    const int g = lane >> 3, k = lane & 7;
    for (int r0 = wv * 8; r0 < vn; r0 += 64) {
      const int r = r0 + g;
      const bool act = (r < vn);
      float4 rw0, rw1, rw2, rw3;
      double bcv = 0.0;
      if (act) {
        const float4* wr4 = (const float4*)(Wc + (size_t)(v0 + r)*128);
        rw0 = wr4[k]; rw1 = wr4[k + 8]; rw2 = wr4[k + 16]; rw3 = wr4[k + 24];
        bcv = (double)bc[v0 + r];
      } else {
        rw0 = rw1 = rw2 = rw3 = make_float4(0.f, 0.f, 0.f, 0.f);
      }
      #pragma unroll 1
      for (int b2 = 0; b2 < K_BEAM; ++b2) {
        const double* xb = &sh_xs[b2*XSTR];
        double p = 0.0;
        {
          const double* xp = xb + (k + 0)*4;
          p += (double)rw0.x*xp[0]; p += (double)rw0.y*xp[1];
          p += (double)rw0.z*xp[2]; p += (double)rw0.w*xp[3];
        }
        {
          const double* xp = xb + (k + 8)*4;
          p += (double)rw1.x*xp[0]; p += (double)rw1.y*xp[1];
          p += (double)rw1.z*xp[2]; p += (double)rw1.w*xp[3];
        }
        {
          const double* xp = xb + (k + 16)*4;
          p += (double)rw2.x*xp[0]; p += (double)rw2.y*xp[1];
          p += (double)rw2.z*xp[2]; p += (double)rw2.w*xp[3];
        }
        {
          const double* xp = xb + (k + 24)*4;
          p += (double)rw3.x*xp[0]; p += (double)rw3.y*xp[1];
          p += (double)rw3.z*xp[2]; p += (double)rw3.w*xp[3];
        }
        p += __shfl_xor(p, 1, 64);
        p += __shfl_xor(p, 2, 64);
        p += __shfl_xor(p, 4, 64);
        if (act && k == 0) sh_lg[r*K_BEAM + b2] = (float)(p + bcv);
      }
    }
  }
  __syncthreads();

  // ---- LSE partials + per-block top-10 per beam (plain stores) ----
  {
    double* lse_m = (double*)(ws + LSEM_F);
    double* lse_s = (double*)(ws + LSES_F);
    float*  cvv   = ws + CANDV_F;
    int*    cii   = (int*)(ws + CANDI_F);
    for (int b2 = wv; b2 < K_BEAM; b2 += 8) {
      double m = -1e300, s = 0.0;
      for (int vl = lane; vl < vn; vl += 64) {
        double val = (double)sh_lg[vl*K_BEAM + b2];
        double nm = fmax(m, val);
        s = s*exp(m - nm) + exp(val - nm); m = nm;
      }
      wave_merge_ms_d(m, s);
      if (lane == 0) { lse_m[blk*K_BEAM + b2] = m; lse_s[blk*K_BEAM + b2] = s; }
      #pragma unroll
      for (int pick = 0; pick < 10; ++pick) {
        float bv = -3e38f; int bi = 0x7ffffff0;
        for (int vl = lane; vl < vn; vl += 64) {
          float val = sh_lg[vl*K_BEAM + b2];
          if (val > bv || (val == bv && vl < bi)) { bv = val; bi = vl; }
        }
        wave_argmax_f(bv, bi);
        bv = __shfl(bv, 0, 64); bi = __shfl(bi, 0, 64);
        int wi = min(max(bi, 0), vn - 1);
        if (lane == 0) {
          cvv[(blk*K_BEAM + b2)*10 + pick] = bv;
          cii[(blk*K_BEAM + b2)*10 + pick] = v0 + wi;
        }
        if (bi >= 0 && bi < vn && (bi & 63) == lane) sh_lg[bi*K_BEAM + b2] = -3e38f;
      }
    }
  }
}

// ================= stepC: per-beam SEL, one block per beam (grid 10) ========
__global__ __launch_bounds__(NTHR) void stepC_kernel(float* __restrict__ ws, int step)
{
  const int tid  = threadIdx.x;
  const int j    = blockIdx.x;
  const int lane = tid & 63;
  const int wv   = tid >> 6;

  __shared__ double sh_wtv[80];
  __shared__ int    sh_wti[80];
  __shared__ double sh_base;

  const int par = step & 1;
  const float* mcur = ws + (par == 0 ? META_B_F : META_A_F);   // META written this step by stepA
  const double scj = ((const double*)(mcur + M_SC))[j];
  const int finj   = ((const int*)(mcur + M_FIN))[j];
  const bool masked = finj || (step == 0 && j > 0);

  // per-beam LSE base (same merge order as verified SEL)
  if (wv == 0) {
    double m = -1e300, s = 0.0;
    for (int c = lane; c < NBLK; c += 64) {
      double mc  = ((const double*)(ws + LSEM_F))[c*K_BEAM + j];
      double sc2 = ((const double*)(ws + LSES_F))[c*K_BEAM + j];
      double nm = fmax(m, mc);
      s = s*exp(m - nm) + sc2*exp(mc - nm); m = nm;
    }
    wave_merge_ms_d(m, s);
    if (lane == 0) sh_base = scj - (m + log(s));
  }
  __syncthreads();
  const double base = sh_base;

  // each wave: local top-10 over its 320 candidates (2560 total)
  float rv[5]; int ri[5];
  #pragma unroll
  for (int k = 0; k < 5; ++k) {
    int c = wv*320 + 64*k + lane;
    int blkc = c / 10, p = c - blkc*10;
    int idx = (blkc*K_BEAM + j)*10 + p;
    rv[k] = (ws + CANDV_F)[idx];
    ri[k] = ((const int*)(ws + CANDI_F))[idx];
  }
  #pragma unroll
  for (int pick = 0; pick < 10; ++pick) {
    double lv = -1e301; int li = 0x7ffffff0;
    if (!masked) {
      #pragma unroll
      for (int k = 0; k < 5; ++k) {
        double val = base + (double)rv[k];
        int v = ri[k];
        if (val > lv || (val == lv && v < li)) { lv = val; li = v; }
      }
    }
    #pragma unroll
    for (int off = 32; off > 0; off >>= 1) {
      double ov = __shfl_down(lv, off, 64);
      int    oi = __shfl_down(li, off, 64);
      if (ov > lv || (ov == lv && oi < li)) { lv = ov; li = oi; }
    }
    lv = __shfl(lv, 0, 64); li = __shfl(li, 0, 64);
    if (!masked) {
      #pragma unroll
      for (int k = 0; k < 5; ++k) if (ri[k] == li) rv[k] = -3e38f;
    }
    if (lane == 0) { sh_wtv[wv*10 + pick] = lv; sh_wti[wv*10 + pick] = li; }
  }
  __syncthreads();

  // wave 0: merge 80 -> 10, write B10 (plain stores)
  if (wv == 0) {
    double av = (lane < 80) ? sh_wtv[lane] : -1e305;
    int    ai = (lane < 80) ? sh_wti[lane] : 0x7fffffff;
    const int c1 = lane + 64;
    double bv2 = (c1 < 80) ? sh_wtv[c1] : -1e305;
    int    bi2 = (c1 < 80) ? sh_wti[c1] : 0x7fffffff;
    #pragma unroll
    for (int pick = 0; pick < 10; ++pick) {
      bool tb = (bv2 > av) || (bv2 == av && bi2 < ai);
      double lv = tb ? bv2 : av;
      int    li = tb ? bi2 : ai;
      int    ls = tb ? c1  : lane;
      #pragma unroll
      for (int off = 32; off > 0; off >>= 1) {
        double ov = __shfl_down(lv, off, 64);
        int    oi = __shfl_down(li, off, 64);
        int    os = __shfl_down(ls, off, 64);
        if (ov > lv || (ov == lv && oi < li)) { lv = ov; li = oi; ls = os; }
      }
      ls = __shfl(ls, 0, 64);
      if (ls == lane) { av  = -1e305; ai  = 0x7fffffff; }
      if (ls == c1)   { bv2 = -1e305; bi2 = 0x7fffffff; }
      if (lane == 0) {
        double outv; int outf;
        if (finj) {
          outv = (pick == 0) ? scj : -1e301;
          outf = (pick == 0) ? (j*V_SZ + EOS_TOK) : 0x7ffffff0;
        } else if (step == 0 && j > 0) {
          outv = -1e301; outf = 0x7ffffff0;
        } else {
          outv = lv;
          outf = j*V_SZ + min(max(li, 0), V_SZ - 1);
        }
        ((double*)(ws + B10V_F))[j*10 + pick] = outv;
        ((int*)(ws + B10F_F))[j*10 + pick] = outf;
      }
    }
  }
}

// ================= final: merge100 + gather + output (1 block) ==============
__global__ __launch_bounds__(NTHR) void final_kernel(float* __restrict__ ws,
                                                     float* __restrict__ out)
{
  const int tid  = threadIdx.x;
  const int lane = tid & 63;
  const int wv   = tid >> 6;
  __shared__ double sh_selv[10];
  __shared__ int    sh_self[10];
  __shared__ int    sh_seqF[K_BEAM*SEQ_LEN];
  __shared__ int    sh_fpb[K_BEAM], sh_ftok[K_BEAM];

  if (wv == 0) merge100(ws, sh_selv, sh_self, lane);
  __syncthreads();
  const float* mA = ws + META_A_F;              // dst of step 29 (odd -> A)
  const int* seqA = (const int*)(mA + M_SEQ);
  if (tid < K_BEAM) {
    int f = sh_self[tid];
    int pb = f / V_SZ, tk2 = f - pb*V_SZ;
    sh_fpb[tid]  = min(max(pb, 0), K_BEAM - 1);
    sh_ftok[tid] = min(max(tk2, 0), V_SZ - 1);
  }
  __syncthreads();
  for (int t = tid; t < K_BEAM*SEQ_LEN; t += NTHR) {
    int j2 = t / SEQ_LEN, p = t - j2*SEQ_LEN;
    sh_seqF[t] = (p == MAXLEN) ? sh_ftok[j2] : seqA[sh_fpb[j2]*SEQ_LEN + p];
  }
  __syncthreads();
  if (tid < K_BEAM) {
    int first = -1;
    for (int p = 1; p <= MAXLEN; ++p)
      if (sh_seqF[tid*SEQ_LEN + p] == EOS_TOK) { first = p - 1; break; }
    double len = (first >= 0) ? (double)(first + 2) : (double)(MAXLEN + 2);
    double scv = sh_selv[tid];
    out[K_BEAM*SEQ_LEN + tid] = (float)scv;
    out[K_BEAM*SEQ_LEN + K_BEAM + tid] = (float)(scv / pow(len, 1.2));
  }
  for (int t = tid; t < K_BEAM*SEQ_LEN; t += NTHR) out[t] = (float)sh_seqF[t];
}

// ---------------- host ----------------
extern "C" void kernel_launch(void* const* d_in, const int* in_sizes, int n_in,
                              void* d_out, int out_size, void* d_ws, size_t ws_size,
                              hipStream_t stream) {
  (void)in_sizes; (void)n_in; (void)out_size; (void)ws_size;
  const float* enc_key    = (const float*)d_in[0];
  const float* enc_values = (const float*)d_in[1];
  const float* maskp      = (const float*)d_in[2];
  const float* embedding  = (const float*)d_in[3];
  const float* W_ih1      = (const float*)d_in[4];
  const float* W_hh1      = (const float*)d_in[5];
  const float* b_ih1      = (const float*)d_in[6];
  const float* b_hh1      = (const float*)d_in[7];
  const float* W_ih2      = (const float*)d_in[8];
  const float* W_hh2      = (const float*)d_in[9];
  const float* b_ih2      = (const float*)d_in[10];
  const float* b_hh2      = (const float*)d_in[11];
  const float* Wq         = (const float*)d_in[12];
  const float* bq         = (const float*)d_in[13];
  const float* Wc         = (const float*)d_in[14];
  const float* bc         = (const float*)d_in[15];
  float* ws  = (float*)d_ws;
  float* out = (float*)d_out;

  for (int i = 0; i < MAXLEN; ++i) {
    stepA_kernel<<<K_BEAM, NTHR, 0, stream>>>(ws, i, embedding,
        W_ih1, W_hh1, b_ih1, b_hh1, W_ih2, W_hh2, b_ih2, b_hh2,
        Wq, bq, enc_key, enc_values, maskp);
    stepB_kernel<<<NBLK, NTHR, 0, stream>>>(ws, i, Wc, bc);
    stepC_kernel<<<K_BEAM, NTHR, 0, stream>>>(ws, i);
  }
  final_kernel<<<1, NTHR, 0, stream>>>(ws, out);
}

// Round 11
// 3809.576 us; speedup vs baseline: 2.5613x; 1.0424x over previous
//
#include <hip/hip_runtime.h>
#include <math.h>

// ---------------- problem constants ----------------
#define K_BEAM  10
#define V_SZ    50257
#define E_SZ    128
#define H1_SZ   128
#define H2_SZ   64
#define Q_SZ    64
#define T_SZ    2048
#define MAXLEN  30
#define SEQ_LEN 31
#define SOS_TOK 1
#define EOS_TOK 2

#define NBLK 256            // stepB grid
#define NTHR 512            // threads per block (8 waves)
#define VC   197            // ceil(V_SZ / NBLK); last block vn = 22
#define XSTR 132            // sh_xs stride

// ---------------- workspace layout (float indices; f64 slots at even idx) ----
#define ST_A_F   0          // double[4480]: h1[10][128],c1[10][128],h2[10][64],c2,ctx
#define ST_B_F   8960
#define SD_H1    0
#define SD_C1    1280
#define SD_H2    2560
#define SD_C2    3200
#define SD_CTX   3840
#define META_A_F 17920      // SC double[10](@0), FIN i32[10](@20), PREV i32[10](@30), SEQ i32[10][31](@40)
#define META_B_F 18272
#define M_SC     0
#define M_FIN    20
#define M_PREV   30
#define M_SEQ    40
#define XS_F     19936      // double[10][128]: {h2[64], ctx[64]} per beam (stepA -> stepB)
#define LSEM_F   83136      // double[256][10]
#define LSES_F   88256      // double[256][10]
#define CANDV_F  93376      // float[256][10][10]
#define CANDI_F  118976     // int[256][10][10]
#define B10V_F   144576     // double[10][10] per-beam top10 values
#define B10F_F   144776     // int[10][10]   per-beam top10 flat indices

// ---------------- wave helpers ----------------
__device__ __forceinline__ void wave_merge_ms_d(double& m, double& s) {
  #pragma unroll
  for (int off = 32; off > 0; off >>= 1) {
    double om = __shfl_down(m, off, 64);
    double os = __shfl_down(s, off, 64);
    double nm = fmax(m, om);
    s = s * exp(m - nm) + os * exp(om - nm);
    m = nm;
  }
}
__device__ __forceinline__ void wave_argmax_f(float& v, int& i) {
  #pragma unroll
  for (int off = 32; off > 0; off >>= 1) {
    float ov = __shfl_down(v, off, 64);
    int   oi = __shfl_down(i, off, 64);
    if (ov > v || (ov == v && oi < i)) { v = ov; i = oi; }
  }
}

// merge 100 per-beam candidates (B10V/B10F) -> global top-10. Wave 0 executes.
// Plain loads: B10 is written in a previous dispatch (launch-boundary coherent).
__device__ __forceinline__ void merge100(const float* ws, double* selv, int* self_, int lane) {
  const double* bv = (const double*)(ws + B10V_F);
  const int*    bf = (const int*)(ws + B10F_F);
  double av = (lane < 100) ? bv[lane] : -1e302;
  int    af = (lane < 100) ? bf[lane] : 0x7fffffff;
  const int c1 = lane + 64;
  double cv = (c1 < 100) ? bv[c1] : -1e302;
  int    cf = (c1 < 100) ? bf[c1] : 0x7fffffff;
  #pragma unroll
  for (int pick = 0; pick < 10; ++pick) {
    bool tb = (cv > av) || (cv == av && cf < af);
    double lv = tb ? cv : av;
    int    lf = tb ? cf : af;
    int    ls = tb ? c1 : lane;
    #pragma unroll
    for (int off = 32; off > 0; off >>= 1) {
      double ov = __shfl_down(lv, off, 64);
      int    of = __shfl_down(lf, off, 64);
      int    os = __shfl_down(ls, off, 64);
      if (ov > lv || (ov == lv && of < lf)) { lv = ov; lf = of; ls = os; }
    }
    ls = __shfl(ls, 0, 64);
    if (lane == 0) { selv[pick] = lv; self_[pick] = lf; }
    if (ls == lane) { av = -1e302; af = 0x7fffffff; }
    if (ls == c1)   { cv = -1e302; cf = 0x7fffffff; }
  }
}

// ================= stepA: pick decode + LSTM1/2 + q + attention ==============
// Grid 80, but only blocks with blockIdx%8==0 work (beam = blockIdx/8).
// XCD-pin: consecutive blockIdx round-robin across the 8 XCDs [guide §1, m09],
// so the 10 worker blocks all land on ONE XCD and share its L2 -> the ~850KB
// weights + ~1MB enc are L2-filled once per step instead of ~10x (R10 PMC:
// stepA fetch-bound, 7.8MB @ 116 GB/s = its whole 70us). Perf-only heuristic:
// if the mapping differs, behavior is identical to R10's grid-10 launch.
// __launch_bounds__(512,2): 256-VGPR budget so the staged loads stay in regs.
// All staging preserves per-accumulator FMA order -> bit-identical results.
__global__ __launch_bounds__(NTHR, 2) void stepA_kernel(
    float* __restrict__ ws, int step,
    const float* __restrict__ embedding,
    const float* __restrict__ W_ih1, const float* __restrict__ W_hh1,
    const float* __restrict__ b_ih1, const float* __restrict__ b_hh1,
    const float* __restrict__ W_ih2, const float* __restrict__ W_hh2,
    const float* __restrict__ b_ih2, const float* __restrict__ b_hh2,
    const float* __restrict__ Wq, const float* __restrict__ bq,
    const float* __restrict__ enc_key, const float* __restrict__ enc_values,
    const float* __restrict__ maskp)
{
  const int blk = blockIdx.x;
  if (blk & 7) return;                 // XCD-pin: keep only blocks 0,8,...,72
  const int b = blk >> 3;

  const int tid  = threadIdx.x;
  const int lane = tid & 63;
  const int wv   = tid >> 6;

  __shared__ double sh_e[T_SZ];
  __shared__ double sh_red[NTHR];
  __shared__ double sh_xin[192];
  __shared__ double sh_h1p[128];
  __shared__ double sh_g1[512];
  __shared__ double sh_h1n[128];
  __shared__ double sh_h2p[64];
  __shared__ double sh_gt2[256];
  __shared__ double sh_h2n[64];
  __shared__ double sh_qs[64];
  __shared__ double sh_selv[10];
  __shared__ int    sh_self[10];
  __shared__ int    sh_pb, sh_tok;

  const int par = step & 1;
  const double* S = (const double*)(ws + (par == 0 ? ST_A_F : ST_B_F));
  double*       D = (double*)(ws + (par == 0 ? ST_B_F : ST_A_F));
  const float* msrc = ws + (par == 0 ? META_A_F : META_B_F);
  float*       mdst = ws + (par == 0 ? META_B_F : META_A_F);

  // ---- step 0: init own beam's state (block-local, then read below) ----
  if (step == 0) {
    double* SA = (double*)(ws + ST_A_F);
    if (tid < 128) { SA[SD_H1 + b*H1_SZ + tid] = 0.0; SA[SD_C1 + b*H1_SZ + tid] = 0.0; }
    if (tid >= 128 && tid < 192) {
      int i2 = tid - 128;
      SA[SD_H2 + b*H2_SZ + i2] = 0.0; SA[SD_C2 + b*H2_SZ + i2] = 0.0;
      SA[SD_CTX + b*Q_SZ + i2] = 0.0;
    }
    float* mA = ws + META_A_F;
    if (tid == 0) {
      ((double*)(mA + M_SC))[b] = 0.0;
      ((int*)(mA + M_FIN))[b] = 0;
      ((int*)(mA + M_PREV))[b] = SOS_TOK;
    }
    if (tid < SEQ_LEN) ((int*)(mA + M_SEQ))[b*SEQ_LEN + tid] = SOS_TOK;
    __syncthreads();
  }

  // ---- decode pick for this beam ----
  if (step == 0) {
    if (tid == 0) {
      int tok = ((const int*)(msrc + M_PREV))[b];
      double sc = ((const double*)(msrc + M_SC))[b];
      int fin = ((const int*)(msrc + M_FIN))[b];
      sh_pb = b; sh_tok = tok;
      ((double*)(mdst + M_SC))[b] = sc;
      ((int*)(mdst + M_FIN))[b] = fin;
      ((int*)(mdst + M_PREV))[b] = tok;
    }
  } else {
    if (wv == 0) merge100(ws, sh_selv, sh_self, lane);  // redundant per block
    __syncthreads();
    if (tid == 0) {
      int f = sh_self[b];
      int pb = f / V_SZ; int tok = f - pb*V_SZ;
      pb = min(max(pb, 0), K_BEAM - 1); tok = min(max(tok, 0), V_SZ - 1);
      double sc = sh_selv[b];
      int fin = ((const int*)(msrc + M_FIN))[pb] | (tok == EOS_TOK);
      sh_pb = pb; sh_tok = tok;
      ((double*)(mdst + M_SC))[b] = sc;
      ((int*)(mdst + M_FIN))[b] = fin;
      ((int*)(mdst + M_PREV))[b] = tok;
    }
  }
  __syncthreads();
  const int pb = sh_pb, tok = sh_tok;

  // seq copy + input staging
  if (tid < SEQ_LEN) {
    int v = ((const int*)(msrc + M_SEQ))[pb*SEQ_LEN + tid];
    if (step > 0 && tid == step) v = tok;
    ((int*)(mdst + M_SEQ))[b*SEQ_LEN + tid] = v;
  }
  if (tid < 128)                     sh_xin[tid] = (double)embedding[(size_t)tok*E_SZ + tid];
  else if (tid < 192)                sh_xin[tid] = S[SD_CTX + pb*Q_SZ + (tid - 128)];
  if (tid >= 256 && tid < 384)       sh_h1p[tid - 256] = S[SD_H1 + pb*H1_SZ + (tid - 256)];
  __syncthreads();

  // ---- LSTM1 gates: 512 rows, 1 row/thread; 12/8-deep staged loads ----
  {
    const int r = tid;
    double acc = (double)b_ih1[r] + (double)b_hh1[r];
    const float4* wi = (const float4*)(W_ih1 + (size_t)r*192);
    float4 st[12];
    for (int j0 = 0; j0 < 48; j0 += 12) {
      #pragma unroll
      for (int u = 0; u < 12; ++u) st[u] = wi[j0 + u];
      #pragma unroll
      for (int u = 0; u < 12; ++u) {
        const int j = j0 + u;
        acc += (double)st[u].x*sh_xin[4*j]   + (double)st[u].y*sh_xin[4*j+1]
             + (double)st[u].z*sh_xin[4*j+2] + (double)st[u].w*sh_xin[4*j+3];
      }
    }
    const float4* wh = (const float4*)(W_hh1 + (size_t)r*128);
    for (int j0 = 0; j0 < 32; j0 += 8) {
      #pragma unroll
      for (int u = 0; u < 8; ++u) st[u] = wh[j0 + u];
      #pragma unroll
      for (int u = 0; u < 8; ++u) {
        const int j = j0 + u;
        acc += (double)st[u].x*sh_h1p[4*j]   + (double)st[u].y*sh_h1p[4*j+1]
             + (double)st[u].z*sh_h1p[4*j+2] + (double)st[u].w*sh_h1p[4*j+3];
      }
    }
    sh_g1[r] = acc;
  }
  __syncthreads();
  // LSTM1 activation
  if (tid < 128) {
    double ig = 1.0/(1.0 + exp(-sh_g1[tid]));
    double fg = 1.0/(1.0 + exp(-sh_g1[128 + tid]));
    double gg = tanh(sh_g1[256 + tid]);
    double og = 1.0/(1.0 + exp(-sh_g1[384 + tid]));
    double c = fg * S[SD_C1 + pb*H1_SZ + tid] + ig*gg;
    double h = og * tanh(c);
    D[SD_C1 + b*H1_SZ + tid] = c; D[SD_H1 + b*H1_SZ + tid] = h;
    sh_h1n[tid] = h;
  }
  if (tid >= 128 && tid < 192) sh_h2p[tid - 128] = S[SD_H2 + pb*H2_SZ + (tid - 128)];
  __syncthreads();

  // ---- LSTM2 gates: 256 rows; 8-deep staged loads ----
  if (tid < 256) {
    const int r = tid;
    double acc = (double)b_ih2[r] + (double)b_hh2[r];
    const float4* wi2 = (const float4*)(W_ih2 + (size_t)r*128);
    float4 st[8];
    for (int j0 = 0; j0 < 32; j0 += 8) {
      #pragma unroll
      for (int u = 0; u < 8; ++u) st[u] = wi2[j0 + u];
      #pragma unroll
      for (int u = 0; u < 8; ++u) {
        const int j = j0 + u;
        acc += (double)st[u].x*sh_h1n[4*j]   + (double)st[u].y*sh_h1n[4*j+1]
             + (double)st[u].z*sh_h1n[4*j+2] + (double)st[u].w*sh_h1n[4*j+3];
      }
    }
    const float4* wh2 = (const float4*)(W_hh2 + (size_t)r*64);
    for (int j0 = 0; j0 < 16; j0 += 8) {
      #pragma unroll
      for (int u = 0; u < 8; ++u) st[u] = wh2[j0 + u];
      #pragma unroll
      for (int u = 0; u < 8; ++u) {
        const int j = j0 + u;
        acc += (double)st[u].x*sh_h2p[4*j]   + (double)st[u].y*sh_h2p[4*j+1]
             + (double)st[u].z*sh_h2p[4*j+2] + (double)st[u].w*sh_h2p[4*j+3];
      }
    }
    sh_gt2[r] = acc;
  }
  __syncthreads();
  // LSTM2 activation + h2 out
  if (tid < 64) {
    double ig = 1.0/(1.0 + exp(-sh_gt2[tid]));
    double fg = 1.0/(1.0 + exp(-sh_gt2[64 + tid]));
    double gg = tanh(sh_gt2[128 + tid]);
    double og = 1.0/(1.0 + exp(-sh_gt2[192 + tid]));
    double c = fg * S[SD_C2 + pb*H2_SZ + tid] + ig*gg;
    double h = og * tanh(c);
    D[SD_C2 + b*H2_SZ + tid] = c; D[SD_H2 + b*H2_SZ + tid] = h;
    sh_h2n[tid] = h;
    ((double*)(ws + XS_F))[b*128 + tid] = h;
  }
  __syncthreads();
  // q: 16-deep staged row load
  if (tid < 64) {
    double acc = (double)bq[tid];
    const float4* wr = (const float4*)(Wq + (size_t)tid*64);
    float4 st[16];
    #pragma unroll
    for (int u = 0; u < 16; ++u) st[u] = wr[u];
    #pragma unroll
    for (int j = 0; j < 16; ++j) {
      acc += (double)st[j].x*sh_h2n[4*j]   + (double)st[j].y*sh_h2n[4*j+1]
           + (double)st[j].z*sh_h2n[4*j+2] + (double)st[j].w*sh_h2n[4*j+3];
    }
    sh_qs[tid] = acc;
  }
  __syncthreads();

  // ---- attention: energies (16-deep staged), softmax, masked renorm, ctx ----
  double lmax = -1e300;
  for (int t = tid; t < T_SZ; t += NTHR) {
    const float4* kr = (const float4*)(enc_key + (size_t)t*64);
    float4 st[16];
    #pragma unroll
    for (int u = 0; u < 16; ++u) st[u] = kr[u];
    double e = 0.0;
    #pragma unroll
    for (int j = 0; j < 16; ++j) {
      e += (double)st[j].x*sh_qs[4*j]   + (double)st[j].y*sh_qs[4*j+1]
         + (double)st[j].z*sh_qs[4*j+2] + (double)st[j].w*sh_qs[4*j+3];
    }
    sh_e[t] = e;
    lmax = fmax(lmax, e);
  }
  sh_red[tid] = lmax; __syncthreads();
  for (int s2 = 256; s2 > 0; s2 >>= 1) { if (tid < s2) sh_red[tid] = fmax(sh_red[tid], sh_red[tid + s2]); __syncthreads(); }
  const double mx = sh_red[0]; __syncthreads();
  double lsum = 0.0;
  for (int t = tid; t < T_SZ; t += NTHR) lsum += exp(sh_e[t] - mx);
  sh_red[tid] = lsum; __syncthreads();
  for (int s2 = 256; s2 > 0; s2 >>= 1) { if (tid < s2) sh_red[tid] += sh_red[tid + s2]; __syncthreads(); }
  const double Ss = sh_red[0]; __syncthreads();
  double lms = 0.0;
  for (int t = tid; t < T_SZ; t += NTHR) {
    double w = (double)maskp[t] * (exp(sh_e[t] - mx) / Ss);
    sh_e[t] = w;
    lms += w;
  }
  sh_red[tid] = lms; __syncthreads();
  for (int s2 = 256; s2 > 0; s2 >>= 1) { if (tid < s2) sh_red[tid] += sh_red[tid + s2]; __syncthreads(); }
  const double ms = fmax(sh_red[0], 2e-30); __syncthreads();
  {
    const int v = tid & 63, g = tid >> 6;   // 8 groups of 64
    double acc = 0.0;
    float ev[8];
    for (int k0 = 0; k0 < 256; k0 += 8) {
      #pragma unroll
      for (int u = 0; u < 8; ++u)
        ev[u] = enc_values[(size_t)(g + 8*(k0 + u))*64 + v];
      #pragma unroll
      for (int u = 0; u < 8; ++u)
        acc += sh_e[g + 8*(k0 + u)] * (double)ev[u];
    }
    sh_red[tid] = acc;
  }
  __syncthreads();
  if (tid < 64) {
    double cv = 0.0;
    #pragma unroll
    for (int g = 0; g < 8; ++g) cv += sh_red[g*64 + tid];
    cv /= ms;
    D[SD_CTX + b*Q_SZ + tid] = cv;
    ((double*)(ws + XS_F))[b*128 + 64 + tid] = cv;
  }
}

// ================= stepB: logits + LSE partials + block top-10 (grid 256) ====
__global__ __launch_bounds__(NTHR, 2) void stepB_kernel(
    float* __restrict__ ws, int step,
    const float* __restrict__ Wc, const float* __restrict__ bc)
{
  const int tid  = threadIdx.x;
  const int blk  = blockIdx.x;
  const int lane = tid & 63;
  const int wv   = tid >> 6;

  __shared__ double sh_xs[K_BEAM*XSTR];  // stride 132
  __shared__ float  sh_lg[VC*K_BEAM];

  const int v0 = blk * VC;
  const int vn = min(VC, V_SZ - v0);

  // ---- stage XS (plain loads: launch-boundary coherent) ----
  for (int i2 = tid; i2 < K_BEAM*128; i2 += NTHR) {
    int b2 = i2 >> 7, j = i2 & 127;
    sh_xs[b2*XSTR + j] = ((const double*)(ws + XS_F))[i2];
  }
  __syncthreads();

  // ---- logits GEMV: 8 lanes/row, 8 rows/wave-iteration ----
  // unroll 1 on the beam loop: ONE p-chain live at a time (R8 post-mortem:
  // full unroll interleaved 10 chains -> 128-VGPR cap exceeded -> 60 MB/dispatch
  // scratch spill; R10: unroll1 removed the spill, stepB left top-5).
  {
    const int g = lane >> 3, k = lane & 7;
    for (int r0 = wv * 8; r0 < vn; r0 += 64) {
      const int r = r0 + g;
      const bool act = (r < vn);
      float4 rw0, rw1, rw2, rw3;
      double bcv = 0.0;
      if (act) {
        const float4* wr4 = (const float4*)(Wc + (size_t)(v0 + r)*128);
        rw0 = wr4[k]; rw1 = wr4[k + 8]; rw2 = wr4[k + 16]; rw3 = wr4[k + 24];
        bcv = (double)bc[v0 + r];
      } else {
        rw0 = rw1 = rw2 = rw3 = make_float4(0.f, 0.f, 0.f, 0.f);
      }
      #pragma unroll 1
      for (int b2 = 0; b2 < K_BEAM; ++b2) {
        const double* xb = &sh_xs[b2*XSTR];
        double p = 0.0;
        {
          const double* xp = xb + (k + 0)*4;
          p += (double)rw0.x*xp[0]; p += (double)rw0.y*xp[1];
          p += (double)rw0.z*xp[2]; p += (double)rw0.w*xp[3];
        }
        {
          const double* xp = xb + (k + 8)*4;
          p += (double)rw1.x*xp[0]; p += (double)rw1.y*xp[1];
          p += (double)rw1.z*xp[2]; p += (double)rw1.w*xp[3];
        }
        {
          const double* xp = xb + (k + 16)*4;
          p += (double)rw2.x*xp[0]; p += (double)rw2.y*xp[1];
          p += (double)rw2.z*xp[2]; p += (double)rw2.w*xp[3];
        }
        {
          const double* xp = xb + (k + 24)*4;
          p += (double)rw3.x*xp[0]; p += (double)rw3.y*xp[1];
          p += (double)rw3.z*xp[2]; p += (double)rw3.w*xp[3];
        }
        p += __shfl_xor(p, 1, 64);
        p += __shfl_xor(p, 2, 64);
        p += __shfl_xor(p, 4, 64);
        if (act && k == 0) sh_lg[r*K_BEAM + b2] = (float)(p + bcv);
      }
    }
  }
  __syncthreads();

  // ---- LSE partials + per-block top-10 per beam (plain stores) ----
  {
    double* lse_m = (double*)(ws + LSEM_F);
    double* lse_s = (double*)(ws + LSES_F);
    float*  cvv   = ws + CANDV_F;
    int*    cii   = (int*)(ws + CANDI_F);
    for (int b2 = wv; b2 < K_BEAM; b2 += 8) {
      double m = -1e300, s = 0.0;
      for (int vl = lane; vl < vn; vl += 64) {
        double val = (double)sh_lg[vl*K_BEAM + b2];
        double nm = fmax(m, val);
        s = s*exp(m - nm) + exp(val - nm); m = nm;
      }
      wave_merge_ms_d(m, s);
      if (lane == 0) { lse_m[blk*K_BEAM + b2] = m; lse_s[blk*K_BEAM + b2] = s; }
      #pragma unroll
      for (int pick = 0; pick < 10; ++pick) {
        float bv = -3e38f; int bi = 0x7ffffff0;
        for (int vl = lane; vl < vn; vl += 64) {
          float val = sh_lg[vl*K_BEAM + b2];
          if (val > bv || (val == bv && vl < bi)) { bv = val; bi = vl; }
        }
        wave_argmax_f(bv, bi);
        bv = __shfl(bv, 0, 64); bi = __shfl(bi, 0, 64);
        int wi = min(max(bi, 0), vn - 1);
        if (lane == 0) {
          cvv[(blk*K_BEAM + b2)*10 + pick] = bv;
          cii[(blk*K_BEAM + b2)*10 + pick] = v0 + wi;
        }
        if (bi >= 0 && bi < vn && (bi & 63) == lane) sh_lg[bi*K_BEAM + b2] = -3e38f;
      }
    }
  }
}

// ================= stepC: per-beam SEL, one block per beam (grid 10) ========
__global__ __launch_bounds__(NTHR) void stepC_kernel(float* __restrict__ ws, int step)
{
  const int tid  = threadIdx.x;
  const int j    = blockIdx.x;
  const int lane = tid & 63;
  const int wv   = tid >> 6;

  __shared__ double sh_wtv[80];
  __shared__ int    sh_wti[80];
  __shared__ double sh_base;

  const int par = step & 1;
  const float* mcur = ws + (par == 0 ? META_B_F : META_A_F);   // META written this step by stepA
  const double scj = ((const double*)(mcur + M_SC))[j];
  const int finj   = ((const int*)(mcur + M_FIN))[j];
  const bool masked = finj || (step == 0 && j > 0);

  // per-beam LSE base (same merge order as verified SEL)
  if (wv == 0) {
    double m = -1e300, s = 0.0;
    for (int c = lane; c < NBLK; c += 64) {
      double mc  = ((const double*)(ws + LSEM_F))[c*K_BEAM + j];
      double sc2 = ((const double*)(ws + LSES_F))[c*K_BEAM + j];
      double nm = fmax(m, mc);
      s = s*exp(m - nm) + sc2*exp(mc - nm); m = nm;
    }
    wave_merge_ms_d(m, s);
    if (lane == 0) sh_base = scj - (m + log(s));
  }
  __syncthreads();
  const double base = sh_base;

  // each wave: local top-10 over its 320 candidates (2560 total)
  float rv[5]; int ri[5];
  #pragma unroll
  for (int k = 0; k < 5; ++k) {
    int c = wv*320 + 64*k + lane;
    int blkc = c / 10, p = c - blkc*10;
    int idx = (blkc*K_BEAM + j)*10 + p;
    rv[k] = (ws + CANDV_F)[idx];
    ri[k] = ((const int*)(ws + CANDI_F))[idx];
  }
  #pragma unroll
  for (int pick = 0; pick < 10; ++pick) {
    double lv = -1e301; int li = 0x7ffffff0;
    if (!masked) {
      #pragma unroll
      for (int k = 0; k < 5; ++k) {
        double val = base + (double)rv[k];
        int v = ri[k];
        if (val > lv || (val == lv && v < li)) { lv = val; li = v; }
      }
    }
    #pragma unroll
    for (int off = 32; off > 0; off >>= 1) {
      double ov = __shfl_down(lv, off, 64);
      int    oi = __shfl_down(li, off, 64);
      if (ov > lv || (ov == lv && oi < li)) { lv = ov; li = oi; }
    }
    lv = __shfl(lv, 0, 64); li = __shfl(li, 0, 64);
    if (!masked) {
      #pragma unroll
      for (int k = 0; k < 5; ++k) if (ri[k] == li) rv[k] = -3e38f;
    }
    if (lane == 0) { sh_wtv[wv*10 + pick] = lv; sh_wti[wv*10 + pick] = li; }
  }
  __syncthreads();

  // wave 0: merge 80 -> 10, write B10 (plain stores)
  if (wv == 0) {
    double av = (lane < 80) ? sh_wtv[lane] : -1e305;
    int    ai = (lane < 80) ? sh_wti[lane] : 0x7fffffff;
    const int c1 = lane + 64;
    double bv2 = (c1 < 80) ? sh_wtv[c1] : -1e305;
    int    bi2 = (c1 < 80) ? sh_wti[c1] : 0x7fffffff;
    #pragma unroll
    for (int pick = 0; pick < 10; ++pick) {
      bool tb = (bv2 > av) || (bv2 == av && bi2 < ai);
      double lv = tb ? bv2 : av;
      int    li = tb ? bi2 : ai;
      int    ls = tb ? c1  : lane;
      #pragma unroll
      for (int off = 32; off > 0; off >>= 1) {
        double ov = __shfl_down(lv, off, 64);
        int    oi = __shfl_down(li, off, 64);
        int    os = __shfl_down(ls, off, 64);
        if (ov > lv || (ov == lv && oi < li)) { lv = ov; li = oi; ls = os; }
      }
      ls = __shfl(ls, 0, 64);
      if (ls == lane) { av  = -1e305; ai  = 0x7fffffff; }
      if (ls == c1)   { bv2 = -1e305; bi2 = 0x7fffffff; }
      if (lane == 0) {
        double outv; int outf;
        if (finj) {
          outv = (pick == 0) ? scj : -1e301;
          outf = (pick == 0) ? (j*V_SZ + EOS_TOK) : 0x7ffffff0;
        } else if (step == 0 && j > 0) {
          outv = -1e301; outf = 0x7ffffff0;
        } else {
          outv = lv;
          outf = j*V_SZ + min(max(li, 0), V_SZ - 1);
        }
        ((double*)(ws + B10V_F))[j*10 + pick] = outv;
        ((int*)(ws + B10F_F))[j*10 + pick] = outf;
      }
    }
  }
}

// ================= final: merge100 + gather + output (1 block) ==============
__global__ __launch_bounds__(NTHR) void final_kernel(float* __restrict__ ws,
                                                     float* __restrict__ out)
{
  const int tid  = threadIdx.x;
  const int lane = tid & 63;
  const int wv   = tid >> 6;
  __shared__ double sh_selv[10];
  __shared__ int    sh_self[10];
  __shared__ int    sh_seqF[K_BEAM*SEQ_LEN];
  __shared__ int    sh_fpb[K_BEAM], sh_ftok[K_BEAM];

  if (wv == 0) merge100(ws, sh_selv, sh_self, lane);
  __syncthreads();
  const float* mA = ws + META_A_F;              // dst of step 29 (odd -> A)
  const int* seqA = (const int*)(mA + M_SEQ);
  if (tid < K_BEAM) {
    int f = sh_self[tid];
    int pb = f / V_SZ, tk2 = f - pb*V_SZ;
    sh_fpb[tid]  = min(max(pb, 0), K_BEAM - 1);
    sh_ftok[tid] = min(max(tk2, 0), V_SZ - 1);
  }
  __syncthreads();
  for (int t = tid; t < K_BEAM*SEQ_LEN; t += NTHR) {
    int j2 = t / SEQ_LEN, p = t - j2*SEQ_LEN;
    sh_seqF[t] = (p == MAXLEN) ? sh_ftok[j2] : seqA[sh_fpb[j2]*SEQ_LEN + p];
  }
  __syncthreads();
  if (tid < K_BEAM) {
    int first = -1;
    for (int p = 1; p <= MAXLEN; ++p)
      if (sh_seqF[tid*SEQ_LEN + p] == EOS_TOK) { first = p - 1; break; }
    double len = (first >= 0) ? (double)(first + 2) : (double)(MAXLEN + 2);
    double scv = sh_selv[tid];
    out[K_BEAM*SEQ_LEN + tid] = (float)scv;
    out[K_BEAM*SEQ_LEN + K_BEAM + tid] = (float)(scv / pow(len, 1.2));
  }
  for (int t = tid; t < K_BEAM*SEQ_LEN; t += NTHR) out[t] = (float)sh_seqF[t];
}

// ---------------- host ----------------
extern "C" void kernel_launch(void* const* d_in, const int* in_sizes, int n_in,
                              void* d_out, int out_size, void* d_ws, size_t ws_size,
                              hipStream_t stream) {
  (void)in_sizes; (void)n_in; (void)out_size; (void)ws_size;
  const float* enc_key    = (const float*)d_in[0];
  const float* enc_values = (const float*)d_in[1];
  const float* maskp      = (const float*)d_in[2];
  const float* embedding  = (const float*)d_in[3];
  const float* W_ih1      = (const float*)d_in[4];
  const float* W_hh1      = (const float*)d_in[5];
  const float* b_ih1      = (const float*)d_in[6];
  const float* b_hh1      = (const float*)d_in[7];
  const float* W_ih2      = (const float*)d_in[8];
  const float* W_hh2      = (const float*)d_in[9];
  const float* b_ih2      = (const float*)d_in[10];
  const float* b_hh2      = (const float*)d_in[11];
  const float* Wq         = (const float*)d_in[12];
  const float* bq         = (const float*)d_in[13];
  const float* Wc         = (const float*)d_in[14];
  const float* bc         = (const float*)d_in[15];
  float* ws  = (float*)d_ws;
  float* out = (float*)d_out;

  for (int i = 0; i < MAXLEN; ++i) {
    stepA_kernel<<<8*K_BEAM, NTHR, 0, stream>>>(ws, i, embedding,
        W_ih1, W_hh1, b_ih1, b_hh1, W_ih2, W_hh2, b_ih2, b_hh2,
        Wq, bq, enc_key, enc_values, maskp);
    stepB_kernel<<<NBLK, NTHR, 0, stream>>>(ws, i, Wc, bc);
    stepC_kernel<<<K_BEAM, NTHR, 0, stream>>>(ws, i);
  }
  final_kernel<<<1, NTHR, 0, stream>>>(ws, out);
}

// Round 12
// 3686.211 us; speedup vs baseline: 2.6471x; 1.0335x over previous
//
#include <hip/hip_runtime.h>
#include <math.h>

// ---------------- problem constants ----------------
#define K_BEAM  10
#define V_SZ    50257
#define E_SZ    128
#define H1_SZ   128
#define H2_SZ   64
#define Q_SZ    64
#define T_SZ    2048
#define MAXLEN  30
#define SEQ_LEN 31
#define SOS_TOK 1
#define EOS_TOK 2

#define NBLK 256            // stepB grid
#define NTHR 512            // threads per block (8 waves)
#define VC   197            // ceil(V_SZ / NBLK); last block vn = 22
#define XSTR 132            // sh_xs stride

// ---------------- workspace layout (float indices; f64 slots at even idx) ----
#define ST_A_F   0          // double[4480]: h1[10][128],c1[10][128],h2[10][64],c2,ctx
#define ST_B_F   8960
#define SD_H1    0
#define SD_C1    1280
#define SD_H2    2560
#define SD_C2    3200
#define SD_CTX   3840
#define META_A_F 17920      // SC double[10](@0), FIN i32[10](@20), PREV i32[10](@30), SEQ i32[10][31](@40)
#define META_B_F 18272
#define M_SC     0
#define M_FIN    20
#define M_PREV   30
#define M_SEQ    40
#define XS_F     19936      // double[10][128]: h2 half used (stepA1 -> stepB)
#define LSEM_F   83136      // double[256][10]
#define LSES_F   88256      // double[256][10]
#define CANDV_F  93376      // float[256][10][10]
#define CANDI_F  118976     // int[256][10][10]
#define B10V_F   144576     // double[10][10] per-beam top10 values
#define B10F_F   144776     // int[10][10]   per-beam top10 flat indices
#define QD_F     150016     // double[10][64] q vectors (stepA1 -> energy)
#define ENG_F    151296     // double[10][2048] energies (energy -> ctx)
#define MC_F     192256     // double[10][8] chunk max
#define SCC_F    192416     // double[10][8] chunk sumexp
#define MSC_F    192576     // double[10][8] chunk msum
#define CTXC_F   192736     // double[10][8][64] chunk ctx partials
// ends 202976 floats = 812 KB (< 2.1 MB verified ws)

// ---------------- wave helpers ----------------
__device__ __forceinline__ void wave_merge_ms_d(double& m, double& s) {
  #pragma unroll
  for (int off = 32; off > 0; off >>= 1) {
    double om = __shfl_down(m, off, 64);
    double os = __shfl_down(s, off, 64);
    double nm = fmax(m, om);
    s = s * exp(m - nm) + os * exp(om - nm);
    m = nm;
  }
}
__device__ __forceinline__ void wave_argmax_f(float& v, int& i) {
  #pragma unroll
  for (int off = 32; off > 0; off >>= 1) {
    float ov = __shfl_down(v, off, 64);
    int   oi = __shfl_down(i, off, 64);
    if (ov > v || (ov == v && oi < i)) { v = ov; i = oi; }
  }
}

// merge 100 per-beam candidates (B10V/B10F) -> global top-10. Wave 0 executes.
__device__ __forceinline__ void merge100(const float* ws, double* selv, int* self_, int lane) {
  const double* bv = (const double*)(ws + B10V_F);
  const int*    bf = (const int*)(ws + B10F_F);
  double av = (lane < 100) ? bv[lane] : -1e302;
  int    af = (lane < 100) ? bf[lane] : 0x7fffffff;
  const int c1 = lane + 64;
  double cv = (c1 < 100) ? bv[c1] : -1e302;
  int    cf = (c1 < 100) ? bf[c1] : 0x7fffffff;
  #pragma unroll
  for (int pick = 0; pick < 10; ++pick) {
    bool tb = (cv > av) || (cv == av && cf < af);
    double lv = tb ? cv : av;
    int    lf = tb ? cf : af;
    int    ls = tb ? c1 : lane;
    #pragma unroll
    for (int off = 32; off > 0; off >>= 1) {
      double ov = __shfl_down(lv, off, 64);
      int    of = __shfl_down(lf, off, 64);
      int    os = __shfl_down(ls, off, 64);
      if (ov > lv || (ov == lv && of < lf)) { lv = ov; lf = of; ls = os; }
    }
    ls = __shfl(ls, 0, 64);
    if (lane == 0) { selv[pick] = lv; self_[pick] = lf; }
    if (ls == lane) { av = -1e302; af = 0x7fffffff; }
    if (ls == c1)   { cv = -1e302; cf = 0x7fffffff; }
  }
}

// ================= stepA1: pick decode + LSTM1/2 + q (grid 80, pin %8==0) ====
// R11 post-mortem: stepA was latency-chain-bound, not fetch-bound. Attention
// moved to energy/ctx kernels (8x parallel). This keeps only decode+LSTM+q.
__global__ __launch_bounds__(NTHR, 2) void stepA1_kernel(
    float* __restrict__ ws, int step,
    const float* __restrict__ embedding,
    const float* __restrict__ W_ih1, const float* __restrict__ W_hh1,
    const float* __restrict__ b_ih1, const float* __restrict__ b_hh1,
    const float* __restrict__ W_ih2, const float* __restrict__ W_hh2,
    const float* __restrict__ b_ih2, const float* __restrict__ b_hh2,
    const float* __restrict__ Wq, const float* __restrict__ bq)
{
  const int blk = blockIdx.x;
  if (blk & 7) return;                 // XCD-pin: blocks 0,8,...,72 (R11: 8x less fetch)
  const int b = blk >> 3;

  const int tid  = threadIdx.x;
  const int lane = tid & 63;
  const int wv   = tid >> 6;

  __shared__ double sh_xin[192];
  __shared__ double sh_h1p[128];
  __shared__ double sh_g1[512];
  __shared__ double sh_h1n[128];
  __shared__ double sh_h2p[64];
  __shared__ double sh_gt2[256];
  __shared__ double sh_h2n[64];
  __shared__ double sh_selv[10];
  __shared__ int    sh_self[10];
  __shared__ int    sh_pb, sh_tok;

  const int par = step & 1;
  const double* S = (const double*)(ws + (par == 0 ? ST_A_F : ST_B_F));
  double*       D = (double*)(ws + (par == 0 ? ST_B_F : ST_A_F));
  const float* msrc = ws + (par == 0 ? META_A_F : META_B_F);
  float*       mdst = ws + (par == 0 ? META_B_F : META_A_F);

  // ---- step 0: init own beam's state ----
  if (step == 0) {
    double* SA = (double*)(ws + ST_A_F);
    if (tid < 128) { SA[SD_H1 + b*H1_SZ + tid] = 0.0; SA[SD_C1 + b*H1_SZ + tid] = 0.0; }
    if (tid >= 128 && tid < 192) {
      int i2 = tid - 128;
      SA[SD_H2 + b*H2_SZ + i2] = 0.0; SA[SD_C2 + b*H2_SZ + i2] = 0.0;
      SA[SD_CTX + b*Q_SZ + i2] = 0.0;
    }
    float* mA = ws + META_A_F;
    if (tid == 0) {
      ((double*)(mA + M_SC))[b] = 0.0;
      ((int*)(mA + M_FIN))[b] = 0;
      ((int*)(mA + M_PREV))[b] = SOS_TOK;
    }
    if (tid < SEQ_LEN) ((int*)(mA + M_SEQ))[b*SEQ_LEN + tid] = SOS_TOK;
    __syncthreads();
  }

  // ---- decode pick for this beam ----
  if (step == 0) {
    if (tid == 0) {
      int tok = ((const int*)(msrc + M_PREV))[b];
      double sc = ((const double*)(msrc + M_SC))[b];
      int fin = ((const int*)(msrc + M_FIN))[b];
      sh_pb = b; sh_tok = tok;
      ((double*)(mdst + M_SC))[b] = sc;
      ((int*)(mdst + M_FIN))[b] = fin;
      ((int*)(mdst + M_PREV))[b] = tok;
    }
  } else {
    if (wv == 0) merge100(ws, sh_selv, sh_self, lane);
    __syncthreads();
    if (tid == 0) {
      int f = sh_self[b];
      int pb = f / V_SZ; int tok = f - pb*V_SZ;
      pb = min(max(pb, 0), K_BEAM - 1); tok = min(max(tok, 0), V_SZ - 1);
      double sc = sh_selv[b];
      int fin = ((const int*)(msrc + M_FIN))[pb] | (tok == EOS_TOK);
      sh_pb = pb; sh_tok = tok;
      ((double*)(mdst + M_SC))[b] = sc;
      ((int*)(mdst + M_FIN))[b] = fin;
      ((int*)(mdst + M_PREV))[b] = tok;
    }
  }
  __syncthreads();
  const int pb = sh_pb, tok = sh_tok;

  // seq copy + input staging
  if (tid < SEQ_LEN) {
    int v = ((const int*)(msrc + M_SEQ))[pb*SEQ_LEN + tid];
    if (step > 0 && tid == step) v = tok;
    ((int*)(mdst + M_SEQ))[b*SEQ_LEN + tid] = v;
  }
  if (tid < 128)                     sh_xin[tid] = (double)embedding[(size_t)tok*E_SZ + tid];
  else if (tid < 192)                sh_xin[tid] = S[SD_CTX + pb*Q_SZ + (tid - 128)];
  if (tid >= 256 && tid < 384)       sh_h1p[tid - 256] = S[SD_H1 + pb*H1_SZ + (tid - 256)];
  __syncthreads();

  // ---- LSTM1 gates: 512 rows, 1 row/thread; 12/8-deep staged loads ----
  {
    const int r = tid;
    double acc = (double)b_ih1[r] + (double)b_hh1[r];
    const float4* wi = (const float4*)(W_ih1 + (size_t)r*192);
    float4 st[12];
    for (int j0 = 0; j0 < 48; j0 += 12) {
      #pragma unroll
      for (int u = 0; u < 12; ++u) st[u] = wi[j0 + u];
      #pragma unroll
      for (int u = 0; u < 12; ++u) {
        const int j = j0 + u;
        acc += (double)st[u].x*sh_xin[4*j]   + (double)st[u].y*sh_xin[4*j+1]
             + (double)st[u].z*sh_xin[4*j+2] + (double)st[u].w*sh_xin[4*j+3];
      }
    }
    const float4* wh = (const float4*)(W_hh1 + (size_t)r*128);
    for (int j0 = 0; j0 < 32; j0 += 8) {
      #pragma unroll
      for (int u = 0; u < 8; ++u) st[u] = wh[j0 + u];
      #pragma unroll
      for (int u = 0; u < 8; ++u) {
        const int j = j0 + u;
        acc += (double)st[u].x*sh_h1p[4*j]   + (double)st[u].y*sh_h1p[4*j+1]
             + (double)st[u].z*sh_h1p[4*j+2] + (double)st[u].w*sh_h1p[4*j+3];
      }
    }
    sh_g1[r] = acc;
  }
  __syncthreads();
  // LSTM1 activation
  if (tid < 128) {
    double ig = 1.0/(1.0 + exp(-sh_g1[tid]));
    double fg = 1.0/(1.0 + exp(-sh_g1[128 + tid]));
    double gg = tanh(sh_g1[256 + tid]);
    double og = 1.0/(1.0 + exp(-sh_g1[384 + tid]));
    double c = fg * S[SD_C1 + pb*H1_SZ + tid] + ig*gg;
    double h = og * tanh(c);
    D[SD_C1 + b*H1_SZ + tid] = c; D[SD_H1 + b*H1_SZ + tid] = h;
    sh_h1n[tid] = h;
  }
  if (tid >= 128 && tid < 192) sh_h2p[tid - 128] = S[SD_H2 + pb*H2_SZ + (tid - 128)];
  __syncthreads();

  // ---- LSTM2 gates: 256 rows; 8-deep staged loads ----
  if (tid < 256) {
    const int r = tid;
    double acc = (double)b_ih2[r] + (double)b_hh2[r];
    const float4* wi2 = (const float4*)(W_ih2 + (size_t)r*128);
    float4 st[8];
    for (int j0 = 0; j0 < 32; j0 += 8) {
      #pragma unroll
      for (int u = 0; u < 8; ++u) st[u] = wi2[j0 + u];
      #pragma unroll
      for (int u = 0; u < 8; ++u) {
        const int j = j0 + u;
        acc += (double)st[u].x*sh_h1n[4*j]   + (double)st[u].y*sh_h1n[4*j+1]
             + (double)st[u].z*sh_h1n[4*j+2] + (double)st[u].w*sh_h1n[4*j+3];
      }
    }
    const float4* wh2 = (const float4*)(W_hh2 + (size_t)r*64);
    for (int j0 = 0; j0 < 16; j0 += 8) {
      #pragma unroll
      for (int u = 0; u < 8; ++u) st[u] = wh2[j0 + u];
      #pragma unroll
      for (int u = 0; u < 8; ++u) {
        const int j = j0 + u;
        acc += (double)st[u].x*sh_h2p[4*j]   + (double)st[u].y*sh_h2p[4*j+1]
             + (double)st[u].z*sh_h2p[4*j+2] + (double)st[u].w*sh_h2p[4*j+3];
      }
    }
    sh_gt2[r] = acc;
  }
  __syncthreads();
  // LSTM2 activation + h2 out
  if (tid < 64) {
    double ig = 1.0/(1.0 + exp(-sh_gt2[tid]));
    double fg = 1.0/(1.0 + exp(-sh_gt2[64 + tid]));
    double gg = tanh(sh_gt2[128 + tid]);
    double og = 1.0/(1.0 + exp(-sh_gt2[192 + tid]));
    double c = fg * S[SD_C2 + pb*H2_SZ + tid] + ig*gg;
    double h = og * tanh(c);
    D[SD_C2 + b*H2_SZ + tid] = c; D[SD_H2 + b*H2_SZ + tid] = h;
    sh_h2n[tid] = h;
    ((double*)(ws + XS_F))[b*128 + tid] = h;
  }
  __syncthreads();
  // q: 16-deep staged row load -> QD (read by energy kernel next dispatch)
  if (tid < 64) {
    double acc = (double)bq[tid];
    const float4* wr = (const float4*)(Wq + (size_t)tid*64);
    float4 st[16];
    #pragma unroll
    for (int u = 0; u < 16; ++u) st[u] = wr[u];
    #pragma unroll
    for (int j = 0; j < 16; ++j) {
      acc += (double)st[j].x*sh_h2n[4*j]   + (double)st[j].y*sh_h2n[4*j+1]
           + (double)st[j].z*sh_h2n[4*j+2] + (double)st[j].w*sh_h2n[4*j+3];
    }
    ((double*)(ws + QD_F))[b*64 + tid] = acc;
  }
}

// ================= energy: chunk energies + online (m,s) partials ===========
// Grid 80: bm=blk>>3 (beam), ch=blk&7 (chunk). blk%8==ch -> all beams' chunk c
// share XCD c's L2 slice of enc_key. Round-0-verified reduction semantics.
__global__ __launch_bounds__(256, 2) void energy_kernel(
    float* __restrict__ ws, const float* __restrict__ enc_key)
{
  const int tid = threadIdx.x;
  const int bm = blockIdx.x >> 3, ch = blockIdx.x & 7;
  __shared__ double qs[64], rm[256], rs[256];
  if (tid < 64) qs[tid] = ((const double*)(ws + QD_F))[bm*64 + tid];
  __syncthreads();
  const int t = ch*256 + tid;
  const float4* kr = (const float4*)(enc_key + (size_t)t*64);
  float4 st[16];
  #pragma unroll
  for (int u = 0; u < 16; ++u) st[u] = kr[u];
  double e = 0.0;
  #pragma unroll
  for (int j = 0; j < 16; ++j) {
    e += (double)st[j].x*qs[4*j]   + (double)st[j].y*qs[4*j+1]
       + (double)st[j].z*qs[4*j+2] + (double)st[j].w*qs[4*j+3];
  }
  ((double*)(ws + ENG_F))[bm*2048 + t] = e;
  rm[tid] = e; rs[tid] = 1.0;
  __syncthreads();
  for (int s2 = 128; s2 > 0; s2 >>= 1) {
    if (tid < s2) {
      double m1 = rm[tid], m2 = rm[tid + s2];
      double nm = fmax(m1, m2);
      rs[tid] = rs[tid]*exp(m1 - nm) + rs[tid + s2]*exp(m2 - nm);
      rm[tid] = nm;
    }
    __syncthreads();
  }
  if (tid == 0) {
    ((double*)(ws + MC_F))[bm*8 + ch]  = rm[0];
    ((double*)(ws + SCC_F))[bm*8 + ch] = rs[0];
  }
}

// ================= ctx: matt + chunk msum/ctx partials (grid 80) ============
__global__ __launch_bounds__(256, 2) void ctx_kernel(
    float* __restrict__ ws, const float* __restrict__ enc_values,
    const float* __restrict__ maskp)
{
  const int tid = threadIdx.x;
  const int bm = blockIdx.x >> 3, ch = blockIdx.x & 7;
  __shared__ double e_s[256], red[256];
  __shared__ float  m_s[256];
  __shared__ double mxS, SsS;
  e_s[tid] = ((const double*)(ws + ENG_F))[bm*2048 + ch*256 + tid];
  m_s[tid] = maskp[ch*256 + tid];
  if (tid == 0) {
    double m = -1e300, s = 0.0;
    for (int c = 0; c < 8; ++c) {
      double mc = ((const double*)(ws + MC_F))[bm*8 + c];
      double sc = ((const double*)(ws + SCC_F))[bm*8 + c];
      double nm = fmax(m, mc);
      s = s*exp(m - nm) + sc*exp(mc - nm);
      m = nm;
    }
    mxS = m; SsS = s;
  }
  __syncthreads();
  const double mx = mxS, Ss = SsS;
  double matt = (double)m_s[tid] * (exp(e_s[tid] - mx)/Ss);
  red[tid] = matt; __syncthreads();
  for (int s2 = 128; s2 > 0; s2 >>= 1) { if (tid < s2) red[tid] += red[tid + s2]; __syncthreads(); }
  if (tid == 0) ((double*)(ws + MSC_F))[bm*8 + ch] = red[0];
  __syncthreads();
  const int v = tid & 63, g4 = tid >> 6;
  double acc = 0.0;
  float ev[16];
  for (int k0 = 0; k0 < 64; k0 += 16) {
    #pragma unroll
    for (int u = 0; u < 16; ++u) {
      int tl = g4 + 4*(k0 + u);
      ev[u] = enc_values[(size_t)(ch*256 + tl)*64 + v];
    }
    #pragma unroll
    for (int u = 0; u < 16; ++u) {
      int tl = g4 + 4*(k0 + u);
      double mt = (double)m_s[tl] * (exp(e_s[tl] - mx)/Ss);
      acc += mt * (double)ev[u];
    }
  }
  red[tid] = acc; __syncthreads();
  if (g4 == 0)
    ((double*)(ws + CTXC_F))[(bm*8 + ch)*64 + v] = red[v] + red[64+v] + red[128+v] + red[192+v];
}

// ================= stepB: ctx fold + logits + LSE + block top-10 (grid 256) ==
__global__ __launch_bounds__(NTHR, 2) void stepB_kernel(
    float* __restrict__ ws, int step,
    const float* __restrict__ Wc, const float* __restrict__ bc)
{
  const int tid  = threadIdx.x;
  const int blk  = blockIdx.x;
  const int lane = tid & 63;
  const int wv   = tid >> 6;

  __shared__ double sh_xs[K_BEAM*XSTR];  // stride 132
  __shared__ float  sh_lg[VC*K_BEAM];

  const int v0 = blk * VC;
  const int vn = min(VC, V_SZ - v0);
  const int par = step & 1;
  double* D = (double*)(ws + (par == 0 ? ST_B_F : ST_A_F));

  // ---- stage XS: h2 from stepA1; ctx folded from chunk partials
  //      (round-0 c_kernel fold order: ms = sum msc, cv = sum ctxc, cv/ms) ----
  for (int i2 = tid; i2 < 640; i2 += NTHR) {
    int b2 = i2 >> 6, v = i2 & 63;
    sh_xs[b2*XSTR + v] = ((const double*)(ws + XS_F))[b2*128 + v];
    double msv = 0.0;
    for (int c = 0; c < 8; ++c) msv += ((const double*)(ws + MSC_F))[b2*8 + c];
    msv = fmax(msv, 2e-30);
    double cv = 0.0;
    for (int c = 0; c < 8; ++c) cv += ((const double*)(ws + CTXC_F))[(b2*8 + c)*64 + v];
    cv /= msv;
    sh_xs[b2*XSTR + 64 + v] = cv;
    if (blk == 0) D[SD_CTX + b2*64 + v] = cv;   // next-step stepA1 reads it
  }
  __syncthreads();

  // ---- logits GEMV: 8 lanes/row, 8 rows/wave-iteration; beam loop unroll 1
  //      (R10: removed the 60MB/dispatch scratch spill) ----
  {
    const int g = lane >> 3, k = lane & 7;
    for (int r0 = wv * 8; r0 < vn; r0 += 64) {
      const int r = r0 + g;
      const bool act = (r < vn);
      float4 rw0, rw1, rw2, rw3;
      double bcv = 0.0;
      if (act) {
        const float4* wr4 = (const float4*)(Wc + (size_t)(v0 + r)*128);
        rw0 = wr4[k]; rw1 = wr4[k + 8]; rw2 = wr4[k + 16]; rw3 = wr4[k + 24];
        bcv = (double)bc[v0 + r];
      } else {
        rw0 = rw1 = rw2 = rw3 = make_float4(0.f, 0.f, 0.f, 0.f);
      }
      #pragma unroll 1
      for (int b2 = 0; b2 < K_BEAM; ++b2) {
        const double* xb = &sh_xs[b2*XSTR];
        double p = 0.0;
        {
          const double* xp = xb + (k + 0)*4;
          p += (double)rw0.x*xp[0]; p += (double)rw0.y*xp[1];
          p += (double)rw0.z*xp[2]; p += (double)rw0.w*xp[3];
        }
        {
          const double* xp = xb + (k + 8)*4;
          p += (double)rw1.x*xp[0]; p += (double)rw1.y*xp[1];
          p += (double)rw1.z*xp[2]; p += (double)rw1.w*xp[3];
        }
        {
          const double* xp = xb + (k + 16)*4;
          p += (double)rw2.x*xp[0]; p += (double)rw2.y*xp[1];
          p += (double)rw2.z*xp[2]; p += (double)rw2.w*xp[3];
        }
        {
          const double* xp = xb + (k + 24)*4;
          p += (double)rw3.x*xp[0]; p += (double)rw3.y*xp[1];
          p += (double)rw3.z*xp[2]; p += (double)rw3.w*xp[3];
        }
        p += __shfl_xor(p, 1, 64);
        p += __shfl_xor(p, 2, 64);
        p += __shfl_xor(p, 4, 64);
        if (act && k == 0) sh_lg[r*K_BEAM + b2] = (float)(p + bcv);
      }
    }
  }
  __syncthreads();

  // ---- LSE partials + per-block top-10 per beam (plain stores) ----
  {
    double* lse_m = (double*)(ws + LSEM_F);
    double* lse_s = (double*)(ws + LSES_F);
    float*  cvv   = ws + CANDV_F;
    int*    cii   = (int*)(ws + CANDI_F);
    for (int b2 = wv; b2 < K_BEAM; b2 += 8) {
      double m = -1e300, s = 0.0;
      for (int vl = lane; vl < vn; vl += 64) {
        double val = (double)sh_lg[vl*K_BEAM + b2];
        double nm = fmax(m, val);
        s = s*exp(m - nm) + exp(val - nm); m = nm;
      }
      wave_merge_ms_d(m, s);
      if (lane == 0) { lse_m[blk*K_BEAM + b2] = m; lse_s[blk*K_BEAM + b2] = s; }
      #pragma unroll
      for (int pick = 0; pick < 10; ++pick) {
        float bv = -3e38f; int bi = 0x7ffffff0;
        for (int vl = lane; vl < vn; vl += 64) {
          float val = sh_lg[vl*K_BEAM + b2];
          if (val > bv || (val == bv && vl < bi)) { bv = val; bi = vl; }
        }
        wave_argmax_f(bv, bi);
        bv = __shfl(bv, 0, 64); bi = __shfl(bi, 0, 64);
        int wi = min(max(bi, 0), vn - 1);
        if (lane == 0) {
          cvv[(blk*K_BEAM + b2)*10 + pick] = bv;
          cii[(blk*K_BEAM + b2)*10 + pick] = v0 + wi;
        }
        if (bi >= 0 && bi < vn && (bi & 63) == lane) sh_lg[bi*K_BEAM + b2] = -3e38f;
      }
    }
  }
}

// ================= stepC: per-beam SEL, one block per beam (grid 10) ========
__global__ __launch_bounds__(NTHR) void stepC_kernel(float* __restrict__ ws, int step)
{
  const int tid  = threadIdx.x;
  const int j    = blockIdx.x;
  const int lane = tid & 63;
  const int wv   = tid >> 6;

  __shared__ double sh_wtv[80];
  __shared__ int    sh_wti[80];
  __shared__ double sh_base;

  const int par = step & 1;
  const float* mcur = ws + (par == 0 ? META_B_F : META_A_F);
  const double scj = ((const double*)(mcur + M_SC))[j];
  const int finj   = ((const int*)(mcur + M_FIN))[j];
  const bool masked = finj || (step == 0 && j > 0);

  if (wv == 0) {
    double m = -1e300, s = 0.0;
    for (int c = lane; c < NBLK; c += 64) {
      double mc  = ((const double*)(ws + LSEM_F))[c*K_BEAM + j];
      double sc2 = ((const double*)(ws + LSES_F))[c*K_BEAM + j];
      double nm = fmax(m, mc);
      s = s*exp(m - nm) + sc2*exp(mc - nm); m = nm;
    }
    wave_merge_ms_d(m, s);
    if (lane == 0) sh_base = scj - (m + log(s));
  }
  __syncthreads();
  const double base = sh_base;

  float rv[5]; int ri[5];
  #pragma unroll
  for (int k = 0; k < 5; ++k) {
    int c = wv*320 + 64*k + lane;
    int blkc = c / 10, p = c - blkc*10;
    int idx = (blkc*K_BEAM + j)*10 + p;
    rv[k] = (ws + CANDV_F)[idx];
    ri[k] = ((const int*)(ws + CANDI_F))[idx];
  }
  #pragma unroll
  for (int pick = 0; pick < 10; ++pick) {
    double lv = -1e301; int li = 0x7ffffff0;
    if (!masked) {
      #pragma unroll
      for (int k = 0; k < 5; ++k) {
        double val = base + (double)rv[k];
        int v = ri[k];
        if (val > lv || (val == lv && v < li)) { lv = val; li = v; }
      }
    }
    #pragma unroll
    for (int off = 32; off > 0; off >>= 1) {
      double ov = __shfl_down(lv, off, 64);
      int    oi = __shfl_down(li, off, 64);
      if (ov > lv || (ov == lv && oi < li)) { lv = ov; li = oi; }
    }
    lv = __shfl(lv, 0, 64); li = __shfl(li, 0, 64);
    if (!masked) {
      #pragma unroll
      for (int k = 0; k < 5; ++k) if (ri[k] == li) rv[k] = -3e38f;
    }
    if (lane == 0) { sh_wtv[wv*10 + pick] = lv; sh_wti[wv*10 + pick] = li; }
  }
  __syncthreads();

  if (wv == 0) {
    double av = (lane < 80) ? sh_wtv[lane] : -1e305;
    int    ai = (lane < 80) ? sh_wti[lane] : 0x7fffffff;
    const int c1 = lane + 64;
    double bv2 = (c1 < 80) ? sh_wtv[c1] : -1e305;
    int    bi2 = (c1 < 80) ? sh_wti[c1] : 0x7fffffff;
    #pragma unroll
    for (int pick = 0; pick < 10; ++pick) {
      bool tb = (bv2 > av) || (bv2 == av && bi2 < ai);
      double lv = tb ? bv2 : av;
      int    li = tb ? bi2 : ai;
      int    ls = tb ? c1  : lane;
      #pragma unroll
      for (int off = 32; off > 0; off >>= 1) {
        double ov = __shfl_down(lv, off, 64);
        int    oi = __shfl_down(li, off, 64);
        int    os = __shfl_down(ls, off, 64);
        if (ov > lv || (ov == lv && oi < li)) { lv = ov; li = oi; ls = os; }
      }
      ls = __shfl(ls, 0, 64);
      if (ls == lane) { av  = -1e305; ai  = 0x7fffffff; }
      if (ls == c1)   { bv2 = -1e305; bi2 = 0x7fffffff; }
      if (lane == 0) {
        double outv; int outf;
        if (finj) {
          outv = (pick == 0) ? scj : -1e301;
          outf = (pick == 0) ? (j*V_SZ + EOS_TOK) : 0x7ffffff0;
        } else if (step == 0 && j > 0) {
          outv = -1e301; outf = 0x7ffffff0;
        } else {
          outv = lv;
          outf = j*V_SZ + min(max(li, 0), V_SZ - 1);
        }
        ((double*)(ws + B10V_F))[j*10 + pick] = outv;
        ((int*)(ws + B10F_F))[j*10 + pick] = outf;
      }
    }
  }
}

// ================= final: merge100 + gather + output (1 block) ==============
__global__ __launch_bounds__(NTHR) void final_kernel(float* __restrict__ ws,
                                                     float* __restrict__ out)
{
  const int tid  = threadIdx.x;
  const int lane = tid & 63;
  const int wv   = tid >> 6;
  __shared__ double sh_selv[10];
  __shared__ int    sh_self[10];
  __shared__ int    sh_seqF[K_BEAM*SEQ_LEN];
  __shared__ int    sh_fpb[K_BEAM], sh_ftok[K_BEAM];

  if (wv == 0) merge100(ws, sh_selv, sh_self, lane);
  __syncthreads();
  const float* mA = ws + META_A_F;              // dst of step 29 (odd -> A)
  const int* seqA = (const int*)(mA + M_SEQ);
  if (tid < K_BEAM) {
    int f = sh_self[tid];
    int pb = f / V_SZ, tk2 = f - pb*V_SZ;
    sh_fpb[tid]  = min(max(pb, 0), K_BEAM - 1);
    sh_ftok[tid] = min(max(tk2, 0), V_SZ - 1);
  }
  __syncthreads();
  for (int t = tid; t < K_BEAM*SEQ_LEN; t += NTHR) {
    int j2 = t / SEQ_LEN, p = t - j2*SEQ_LEN;
    sh_seqF[t] = (p == MAXLEN) ? sh_ftok[j2] : seqA[sh_fpb[j2]*SEQ_LEN + p];
  }
  __syncthreads();
  if (tid < K_BEAM) {
    int first = -1;
    for (int p = 1; p <= MAXLEN; ++p)
      if (sh_seqF[tid*SEQ_LEN + p] == EOS_TOK) { first = p - 1; break; }
    double len = (first >= 0) ? (double)(first + 2) : (double)(MAXLEN + 2);
    double scv = sh_selv[tid];
    out[K_BEAM*SEQ_LEN + tid] = (float)scv;
    out[K_BEAM*SEQ_LEN + K_BEAM + tid] = (float)(scv / pow(len, 1.2));
  }
  for (int t = tid; t < K_BEAM*SEQ_LEN; t += NTHR) out[t] = (float)sh_seqF[t];
}

// ---------------- host ----------------
extern "C" void kernel_launch(void* const* d_in, const int* in_sizes, int n_in,
                              void* d_out, int out_size, void* d_ws, size_t ws_size,
                              hipStream_t stream) {
  (void)in_sizes; (void)n_in; (void)out_size; (void)ws_size;
  const float* enc_key    = (const float*)d_in[0];
  const float* enc_values = (const float*)d_in[1];
  const float* maskp      = (const float*)d_in[2];
  const float* embedding  = (const float*)d_in[3];
  const float* W_ih1      = (const float*)d_in[4];
  const float* W_hh1      = (const float*)d_in[5];
  const float* b_ih1      = (const float*)d_in[6];
  const float* b_hh1      = (const float*)d_in[7];
  const float* W_ih2      = (const float*)d_in[8];
  const float* W_hh2      = (const float*)d_in[9];
  const float* b_ih2      = (const float*)d_in[10];
  const float* b_hh2      = (const float*)d_in[11];
  const float* Wq         = (const float*)d_in[12];
  const float* bq         = (const float*)d_in[13];
  const float* Wc         = (const float*)d_in[14];
  const float* bc         = (const float*)d_in[15];
  float* ws  = (float*)d_ws;
  float* out = (float*)d_out;

  for (int i = 0; i < MAXLEN; ++i) {
    stepA1_kernel<<<8*K_BEAM, NTHR, 0, stream>>>(ws, i, embedding,
        W_ih1, W_hh1, b_ih1, b_hh1, W_ih2, W_hh2, b_ih2, b_hh2, Wq, bq);
    energy_kernel<<<8*K_BEAM, 256, 0, stream>>>(ws, enc_key);
    ctx_kernel<<<8*K_BEAM, 256, 0, stream>>>(ws, enc_values, maskp);
    stepB_kernel<<<NBLK, NTHR, 0, stream>>>(ws, i, Wc, bc);
    stepC_kernel<<<K_BEAM, NTHR, 0, stream>>>(ws, i);
  }
  final_kernel<<<1, NTHR, 0, stream>>>(ws, out);
}

// Round 13
// 3668.093 us; speedup vs baseline: 2.6601x; 1.0049x over previous
//
#include <hip/hip_runtime.h>
#include <math.h>

// ---------------- problem constants ----------------
#define K_BEAM  10
#define V_SZ    50257
#define E_SZ    128
#define H1_SZ   128
#define H2_SZ   64
#define Q_SZ    64
#define T_SZ    2048
#define MAXLEN  30
#define SEQ_LEN 31
#define SOS_TOK 1
#define EOS_TOK 2

#define NBLK 256            // stepB grid
#define NTHR 512            // threads per block (8 waves)
#define NTHR_A 1024         // stepA1 threads (16 waves: 2 threads/row LSTM1)
#define VC   197            // ceil(V_SZ / NBLK); last block vn = 22
#define XSTR 132            // sh_xs stride

// ---------------- workspace layout (float indices; f64 slots at even idx) ----
#define ST_A_F   0          // double[4480]: h1[10][128],c1[10][128],h2[10][64],c2,ctx
#define ST_B_F   8960
#define SD_H1    0
#define SD_C1    1280
#define SD_H2    2560
#define SD_C2    3200
#define SD_CTX   3840
#define META_A_F 17920      // SC double[10](@0), FIN i32[10](@20), PREV i32[10](@30), SEQ i32[10][31](@40)
#define META_B_F 18272
#define M_SC     0
#define M_FIN    20
#define M_PREV   30
#define M_SEQ    40
#define XS_F     19936      // double[10][128]: h2 half used (stepA1 -> stepB)
#define LSEM_F   83136      // double[256][10]
#define LSES_F   88256      // double[256][10]
#define CANDV_F  93376      // float[256][10][10]
#define CANDI_F  118976     // int[256][10][10]
#define B10V_F   144576     // double[10][10] per-beam top10 values
#define B10F_F   144776     // int[10][10]   per-beam top10 flat indices
#define QD_F     150016     // double[10][64] q vectors (stepA1 -> energy)
#define ENG_F    151296     // double[10][2048] energies (energy -> ctx)
#define MC_F     192256     // double[10][8] chunk max
#define SCC_F    192416     // double[10][8] chunk sumexp
#define MSC_F    192576     // double[10][8] chunk msum
#define CTXC_F   192736     // double[10][8][64] chunk ctx partials
// ends 202976 floats = 812 KB (< 2.1 MB verified ws)

// ---------------- wave helpers ----------------
__device__ __forceinline__ void wave_merge_ms_d(double& m, double& s) {
  #pragma unroll
  for (int off = 32; off > 0; off >>= 1) {
    double om = __shfl_down(m, off, 64);
    double os = __shfl_down(s, off, 64);
    double nm = fmax(m, om);
    s = s * exp(m - nm) + os * exp(om - nm);
    m = nm;
  }
}
__device__ __forceinline__ void wave_argmax_f(float& v, int& i) {
  #pragma unroll
  for (int off = 32; off > 0; off >>= 1) {
    float ov = __shfl_down(v, off, 64);
    int   oi = __shfl_down(i, off, 64);
    if (ov > v || (ov == v && oi < i)) { v = ov; i = oi; }
  }
}

// merge 100 per-beam candidates (B10V/B10F) -> global top-10. Wave 0 executes.
__device__ __forceinline__ void merge100(const float* ws, double* selv, int* self_, int lane) {
  const double* bv = (const double*)(ws + B10V_F);
  const int*    bf = (const int*)(ws + B10F_F);
  double av = (lane < 100) ? bv[lane] : -1e302;
  int    af = (lane < 100) ? bf[lane] : 0x7fffffff;
  const int c1 = lane + 64;
  double cv = (c1 < 100) ? bv[c1] : -1e302;
  int    cf = (c1 < 100) ? bf[c1] : 0x7fffffff;
  #pragma unroll
  for (int pick = 0; pick < 10; ++pick) {
    bool tb = (cv > av) || (cv == av && cf < af);
    double lv = tb ? cv : av;
    int    lf = tb ? cf : af;
    int    ls = tb ? c1 : lane;
    #pragma unroll
    for (int off = 32; off > 0; off >>= 1) {
      double ov = __shfl_down(lv, off, 64);
      int    of = __shfl_down(lf, off, 64);
      int    os = __shfl_down(ls, off, 64);
      if (ov > lv || (ov == lv && of < lf)) { lv = ov; lf = of; ls = os; }
    }
    ls = __shfl(ls, 0, 64);
    if (lane == 0) { selv[pick] = lv; self_[pick] = lf; }
    if (ls == lane) { av = -1e302; af = 0x7fffffff; }
    if (ls == c1)   { cv = -1e302; cf = 0x7fffffff; }
  }
}

// ================= stepA1: pick decode + LSTM1/2 + q (grid 80, pin %8==0) ====
// R12 post-mortem: VGPR fell to 36 -> staged loads re-serialized; 44.5us is
// LSTM weight-load latency on 8 waves. Fix: 1024 threads, 2 threads/row for
// LSTM1 using the ROUND-0-VERIFIED lo/hi split (lo = b+wi[0..40), hi =
// wi[40..48)+wh, g = lo+hi), halving the per-thread chain and doubling waves.
// LSTM2 gets the same 2-thread split (lo2 = b+wi2, hi2 = wh2).
__global__ __launch_bounds__(NTHR_A) void stepA1_kernel(
    float* __restrict__ ws, int step,
    const float* __restrict__ embedding,
    const float* __restrict__ W_ih1, const float* __restrict__ W_hh1,
    const float* __restrict__ b_ih1, const float* __restrict__ b_hh1,
    const float* __restrict__ W_ih2, const float* __restrict__ W_hh2,
    const float* __restrict__ b_ih2, const float* __restrict__ b_hh2,
    const float* __restrict__ Wq, const float* __restrict__ bq)
{
  const int blk = blockIdx.x;
  if (blk & 7) return;                 // XCD-pin: blocks 0,8,...,72 (R11: 8x less fetch)
  const int b = blk >> 3;

  const int tid  = threadIdx.x;
  const int lane = tid & 63;
  const int wv   = tid >> 6;

  __shared__ double sh_xin[192];
  __shared__ double sh_h1p[128];
  __shared__ double sh_lo[512];        // LSTM1 lo partial / LSTM2 lo partial
  __shared__ double sh_hi[512];        // LSTM1 hi partial / LSTM2 hi partial
  __shared__ double sh_h1n[128];
  __shared__ double sh_h2p[64];
  __shared__ double sh_h2n[64];
  __shared__ double sh_selv[10];
  __shared__ int    sh_self[10];
  __shared__ int    sh_pb, sh_tok;

  const int par = step & 1;
  const double* S = (const double*)(ws + (par == 0 ? ST_A_F : ST_B_F));
  double*       D = (double*)(ws + (par == 0 ? ST_B_F : ST_A_F));
  const float* msrc = ws + (par == 0 ? META_A_F : META_B_F);
  float*       mdst = ws + (par == 0 ? META_B_F : META_A_F);

  // ---- step 0: init own beam's state ----
  if (step == 0) {
    double* SA = (double*)(ws + ST_A_F);
    if (tid < 128) { SA[SD_H1 + b*H1_SZ + tid] = 0.0; SA[SD_C1 + b*H1_SZ + tid] = 0.0; }
    if (tid >= 128 && tid < 192) {
      int i2 = tid - 128;
      SA[SD_H2 + b*H2_SZ + i2] = 0.0; SA[SD_C2 + b*H2_SZ + i2] = 0.0;
      SA[SD_CTX + b*Q_SZ + i2] = 0.0;
    }
    float* mA = ws + META_A_F;
    if (tid == 0) {
      ((double*)(mA + M_SC))[b] = 0.0;
      ((int*)(mA + M_FIN))[b] = 0;
      ((int*)(mA + M_PREV))[b] = SOS_TOK;
    }
    if (tid < SEQ_LEN) ((int*)(mA + M_SEQ))[b*SEQ_LEN + tid] = SOS_TOK;
    __syncthreads();
  }

  // ---- decode pick for this beam ----
  if (step == 0) {
    if (tid == 0) {
      int tok = ((const int*)(msrc + M_PREV))[b];
      double sc = ((const double*)(msrc + M_SC))[b];
      int fin = ((const int*)(msrc + M_FIN))[b];
      sh_pb = b; sh_tok = tok;
      ((double*)(mdst + M_SC))[b] = sc;
      ((int*)(mdst + M_FIN))[b] = fin;
      ((int*)(mdst + M_PREV))[b] = tok;
    }
  } else {
    if (wv == 0) merge100(ws, sh_selv, sh_self, lane);
    __syncthreads();
    if (tid == 0) {
      int f = sh_self[b];
      int pb = f / V_SZ; int tok = f - pb*V_SZ;
      pb = min(max(pb, 0), K_BEAM - 1); tok = min(max(tok, 0), V_SZ - 1);
      double sc = sh_selv[b];
      int fin = ((const int*)(msrc + M_FIN))[pb] | (tok == EOS_TOK);
      sh_pb = pb; sh_tok = tok;
      ((double*)(mdst + M_SC))[b] = sc;
      ((int*)(mdst + M_FIN))[b] = fin;
      ((int*)(mdst + M_PREV))[b] = tok;
    }
  }
  __syncthreads();
  const int pb = sh_pb, tok = sh_tok;

  // seq copy + input staging
  if (tid < SEQ_LEN) {
    int v = ((const int*)(msrc + M_SEQ))[pb*SEQ_LEN + tid];
    if (step > 0 && tid == step) v = tok;
    ((int*)(mdst + M_SEQ))[b*SEQ_LEN + tid] = v;
  }
  if (tid < 128)                     sh_xin[tid] = (double)embedding[(size_t)tok*E_SZ + tid];
  else if (tid < 192)                sh_xin[tid] = S[SD_CTX + pb*Q_SZ + (tid - 128)];
  if (tid >= 256 && tid < 384)       sh_h1p[tid - 256] = S[SD_H1 + pb*H1_SZ + (tid - 256)];
  __syncthreads();

  // ---- LSTM1 gates: 512 rows, 2 threads/row (round-0 lo/hi split) ----
  if (tid < 512) {
    // lo: bias + wi[0..40) (40 float4), 8-deep staged
    const int r = tid;
    double acc = (double)b_ih1[r] + (double)b_hh1[r];
    const float4* wi = (const float4*)(W_ih1 + (size_t)r*192);
    float4 st[8];
    for (int j0 = 0; j0 < 40; j0 += 8) {
      #pragma unroll
      for (int u = 0; u < 8; ++u) st[u] = wi[j0 + u];
      #pragma unroll
      for (int u = 0; u < 8; ++u) {
        const int j = j0 + u;
        acc += (double)st[u].x*sh_xin[4*j]   + (double)st[u].y*sh_xin[4*j+1]
             + (double)st[u].z*sh_xin[4*j+2] + (double)st[u].w*sh_xin[4*j+3];
      }
    }
    sh_lo[r] = acc;
  } else {
    // hi: wi[40..48) + wh[0..32) (40 float4), 8-deep staged
    const int r = tid - 512;
    double acc = 0.0;
    const float4* wi = (const float4*)(W_ih1 + (size_t)r*192);
    float4 st[8];
    {
      #pragma unroll
      for (int u = 0; u < 8; ++u) st[u] = wi[40 + u];
      #pragma unroll
      for (int u = 0; u < 8; ++u) {
        const int j = 40 + u;
        acc += (double)st[u].x*sh_xin[4*j]   + (double)st[u].y*sh_xin[4*j+1]
             + (double)st[u].z*sh_xin[4*j+2] + (double)st[u].w*sh_xin[4*j+3];
      }
    }
    const float4* wh = (const float4*)(W_hh1 + (size_t)r*128);
    for (int j0 = 0; j0 < 32; j0 += 8) {
      #pragma unroll
      for (int u = 0; u < 8; ++u) st[u] = wh[j0 + u];
      #pragma unroll
      for (int u = 0; u < 8; ++u) {
        const int j = j0 + u;
        acc += (double)st[u].x*sh_h1p[4*j]   + (double)st[u].y*sh_h1p[4*j+1]
             + (double)st[u].z*sh_h1p[4*j+2] + (double)st[u].w*sh_h1p[4*j+3];
      }
    }
    sh_hi[r] = acc;
  }
  __syncthreads();
  // LSTM1 activation: gate g[x] = lo[x] + hi[x] (round-0 order)
  if (tid < 128) {
    double ig = 1.0/(1.0 + exp(-(sh_lo[tid]       + sh_hi[tid])));
    double fg = 1.0/(1.0 + exp(-(sh_lo[128 + tid] + sh_hi[128 + tid])));
    double gg = tanh(sh_lo[256 + tid] + sh_hi[256 + tid]);
    double og = 1.0/(1.0 + exp(-(sh_lo[384 + tid] + sh_hi[384 + tid])));
    double c = fg * S[SD_C1 + pb*H1_SZ + tid] + ig*gg;
    double h = og * tanh(c);
    D[SD_C1 + b*H1_SZ + tid] = c; D[SD_H1 + b*H1_SZ + tid] = h;
    sh_h1n[tid] = h;
  }
  if (tid >= 128 && tid < 192) sh_h2p[tid - 128] = S[SD_H2 + pb*H2_SZ + (tid - 128)];
  __syncthreads();

  // ---- LSTM2 gates: 256 rows, 2 threads/row (lo2 = b+wi2, hi2 = wh2) ----
  if (tid < 256) {
    const int r = tid;
    double acc = (double)b_ih2[r] + (double)b_hh2[r];
    const float4* wi2 = (const float4*)(W_ih2 + (size_t)r*128);
    float4 st[8];
    for (int j0 = 0; j0 < 32; j0 += 8) {
      #pragma unroll
      for (int u = 0; u < 8; ++u) st[u] = wi2[j0 + u];
      #pragma unroll
      for (int u = 0; u < 8; ++u) {
        const int j = j0 + u;
        acc += (double)st[u].x*sh_h1n[4*j]   + (double)st[u].y*sh_h1n[4*j+1]
             + (double)st[u].z*sh_h1n[4*j+2] + (double)st[u].w*sh_h1n[4*j+3];
      }
    }
    sh_lo[r] = acc;
  } else if (tid >= 512 && tid < 768) {
    const int r = tid - 512;
    double acc = 0.0;
    const float4* wh2 = (const float4*)(W_hh2 + (size_t)r*64);
    float4 st[8];
    for (int j0 = 0; j0 < 16; j0 += 8) {
      #pragma unroll
      for (int u = 0; u < 8; ++u) st[u] = wh2[j0 + u];
      #pragma unroll
      for (int u = 0; u < 8; ++u) {
        const int j = j0 + u;
        acc += (double)st[u].x*sh_h2p[4*j]   + (double)st[u].y*sh_h2p[4*j+1]
             + (double)st[u].z*sh_h2p[4*j+2] + (double)st[u].w*sh_h2p[4*j+3];
      }
    }
    sh_hi[r] = acc;
  }
  __syncthreads();
  // LSTM2 activation + h2 out: gate g[x] = lo2[x] + hi2[x]
  if (tid < 64) {
    double ig = 1.0/(1.0 + exp(-(sh_lo[tid]       + sh_hi[tid])));
    double fg = 1.0/(1.0 + exp(-(sh_lo[64 + tid]  + sh_hi[64 + tid])));
    double gg = tanh(sh_lo[128 + tid] + sh_hi[128 + tid]);
    double og = 1.0/(1.0 + exp(-(sh_lo[192 + tid] + sh_hi[192 + tid])));
    double c = fg * S[SD_C2 + pb*H2_SZ + tid] + ig*gg;
    double h = og * tanh(c);
    D[SD_C2 + b*H2_SZ + tid] = c; D[SD_H2 + b*H2_SZ + tid] = h;
    sh_h2n[tid] = h;
    ((double*)(ws + XS_F))[b*128 + tid] = h;
  }
  __syncthreads();
  // q: 16-deep staged row load -> QD (read by energy kernel next dispatch)
  if (tid < 64) {
    double acc = (double)bq[tid];
    const float4* wr = (const float4*)(Wq + (size_t)tid*64);
    float4 st[16];
    #pragma unroll
    for (int u = 0; u < 16; ++u) st[u] = wr[u];
    #pragma unroll
    for (int j = 0; j < 16; ++j) {
      acc += (double)st[j].x*sh_h2n[4*j]   + (double)st[j].y*sh_h2n[4*j+1]
           + (double)st[j].z*sh_h2n[4*j+2] + (double)st[j].w*sh_h2n[4*j+3];
    }
    ((double*)(ws + QD_F))[b*64 + tid] = acc;
  }
}

// ================= energy: chunk energies + online (m,s) partials ===========
__global__ __launch_bounds__(256, 2) void energy_kernel(
    float* __restrict__ ws, const float* __restrict__ enc_key)
{
  const int tid = threadIdx.x;
  const int bm = blockIdx.x >> 3, ch = blockIdx.x & 7;
  __shared__ double qs[64], rm[256], rs[256];
  if (tid < 64) qs[tid] = ((const double*)(ws + QD_F))[bm*64 + tid];
  __syncthreads();
  const int t = ch*256 + tid;
  const float4* kr = (const float4*)(enc_key + (size_t)t*64);
  float4 st[16];
  #pragma unroll
  for (int u = 0; u < 16; ++u) st[u] = kr[u];
  double e = 0.0;
  #pragma unroll
  for (int j = 0; j < 16; ++j) {
    e += (double)st[j].x*qs[4*j]   + (double)st[j].y*qs[4*j+1]
       + (double)st[j].z*qs[4*j+2] + (double)st[j].w*qs[4*j+3];
  }
  ((double*)(ws + ENG_F))[bm*2048 + t] = e;
  rm[tid] = e; rs[tid] = 1.0;
  __syncthreads();
  for (int s2 = 128; s2 > 0; s2 >>= 1) {
    if (tid < s2) {
      double m1 = rm[tid], m2 = rm[tid + s2];
      double nm = fmax(m1, m2);
      rs[tid] = rs[tid]*exp(m1 - nm) + rs[tid + s2]*exp(m2 - nm);
      rm[tid] = nm;
    }
    __syncthreads();
  }
  if (tid == 0) {
    ((double*)(ws + MC_F))[bm*8 + ch]  = rm[0];
    ((double*)(ws + SCC_F))[bm*8 + ch] = rs[0];
  }
}

// ================= ctx: matt + chunk msum/ctx partials (grid 80) ============
__global__ __launch_bounds__(256, 2) void ctx_kernel(
    float* __restrict__ ws, const float* __restrict__ enc_values,
    const float* __restrict__ maskp)
{
  const int tid = threadIdx.x;
  const int bm = blockIdx.x >> 3, ch = blockIdx.x & 7;
  __shared__ double e_s[256], red[256];
  __shared__ float  m_s[256];
  __shared__ double mxS, SsS;
  e_s[tid] = ((const double*)(ws + ENG_F))[bm*2048 + ch*256 + tid];
  m_s[tid] = maskp[ch*256 + tid];
  if (tid == 0) {
    double m = -1e300, s = 0.0;
    for (int c = 0; c < 8; ++c) {
      double mc = ((const double*)(ws + MC_F))[bm*8 + c];
      double sc = ((const double*)(ws + SCC_F))[bm*8 + c];
      double nm = fmax(m, mc);
      s = s*exp(m - nm) + sc*exp(mc - nm);
      m = nm;
    }
    mxS = m; SsS = s;
  }
  __syncthreads();
  const double mx = mxS, Ss = SsS;
  double matt = (double)m_s[tid] * (exp(e_s[tid] - mx)/Ss);
  red[tid] = matt; __syncthreads();
  for (int s2 = 128; s2 > 0; s2 >>= 1) { if (tid < s2) red[tid] += red[tid + s2]; __syncthreads(); }
  if (tid == 0) ((double*)(ws + MSC_F))[bm*8 + ch] = red[0];
  __syncthreads();
  const int v = tid & 63, g4 = tid >> 6;
  double acc = 0.0;
  float ev[16];
  for (int k0 = 0; k0 < 64; k0 += 16) {
    #pragma unroll
    for (int u = 0; u < 16; ++u) {
      int tl = g4 + 4*(k0 + u);
      ev[u] = enc_values[(size_t)(ch*256 + tl)*64 + v];
    }
    #pragma unroll
    for (int u = 0; u < 16; ++u) {
      int tl = g4 + 4*(k0 + u);
      double mt = (double)m_s[tl] * (exp(e_s[tl] - mx)/Ss);
      acc += mt * (double)ev[u];
    }
  }
  red[tid] = acc; __syncthreads();
  if (g4 == 0)
    ((double*)(ws + CTXC_F))[(bm*8 + ch)*64 + v] = red[v] + red[64+v] + red[128+v] + red[192+v];
}

// ================= stepB: ctx fold + logits + LSE + block top-10 (grid 256) ==
__global__ __launch_bounds__(NTHR, 2) void stepB_kernel(
    float* __restrict__ ws, int step,
    const float* __restrict__ Wc, const float* __restrict__ bc)
{
  const int tid  = threadIdx.x;
  const int blk  = blockIdx.x;
  const int lane = tid & 63;
  const int wv   = tid >> 6;

  __shared__ double sh_xs[K_BEAM*XSTR];  // stride 132
  __shared__ float  sh_lg[VC*K_BEAM];

  const int v0 = blk * VC;
  const int vn = min(VC, V_SZ - v0);
  const int par = step & 1;
  double* D = (double*)(ws + (par == 0 ? ST_B_F : ST_A_F));

  // ---- stage XS: h2 from stepA1; ctx folded from chunk partials ----
  for (int i2 = tid; i2 < 640; i2 += NTHR) {
    int b2 = i2 >> 6, v = i2 & 63;
    sh_xs[b2*XSTR + v] = ((const double*)(ws + XS_F))[b2*128 + v];
    double msv = 0.0;
    for (int c = 0; c < 8; ++c) msv += ((const double*)(ws + MSC_F))[b2*8 + c];
    msv = fmax(msv, 2e-30);
    double cv = 0.0;
    for (int c = 0; c < 8; ++c) cv += ((const double*)(ws + CTXC_F))[(b2*8 + c)*64 + v];
    cv /= msv;
    sh_xs[b2*XSTR + 64 + v] = cv;
    if (blk == 0) D[SD_CTX + b2*64 + v] = cv;   // next-step stepA1 reads it
  }
  __syncthreads();

  // ---- logits GEMV: 8 lanes/row, 8 rows/wave-iteration; beam loop unroll 1 ----
  {
    const int g = lane >> 3, k = lane & 7;
    for (int r0 = wv * 8; r0 < vn; r0 += 64) {
      const int r = r0 + g;
      const bool act = (r < vn);
      float4 rw0, rw1, rw2, rw3;
      double bcv = 0.0;
      if (act) {
        const float4* wr4 = (const float4*)(Wc + (size_t)(v0 + r)*128);
        rw0 = wr4[k]; rw1 = wr4[k + 8]; rw2 = wr4[k + 16]; rw3 = wr4[k + 24];
        bcv = (double)bc[v0 + r];
      } else {
        rw0 = rw1 = rw2 = rw3 = make_float4(0.f, 0.f, 0.f, 0.f);
      }
      #pragma unroll 1
      for (int b2 = 0; b2 < K_BEAM; ++b2) {
        const double* xb = &sh_xs[b2*XSTR];
        double p = 0.0;
        {
          const double* xp = xb + (k + 0)*4;
          p += (double)rw0.x*xp[0]; p += (double)rw0.y*xp[1];
          p += (double)rw0.z*xp[2]; p += (double)rw0.w*xp[3];
        }
        {
          const double* xp = xb + (k + 8)*4;
          p += (double)rw1.x*xp[0]; p += (double)rw1.y*xp[1];
          p += (double)rw1.z*xp[2]; p += (double)rw1.w*xp[3];
        }
        {
          const double* xp = xb + (k + 16)*4;
          p += (double)rw2.x*xp[0]; p += (double)rw2.y*xp[1];
          p += (double)rw2.z*xp[2]; p += (double)rw2.w*xp[3];
        }
        {
          const double* xp = xb + (k + 24)*4;
          p += (double)rw3.x*xp[0]; p += (double)rw3.y*xp[1];
          p += (double)rw3.z*xp[2]; p += (double)rw3.w*xp[3];
        }
        p += __shfl_xor(p, 1, 64);
        p += __shfl_xor(p, 2, 64);
        p += __shfl_xor(p, 4, 64);
        if (act && k == 0) sh_lg[r*K_BEAM + b2] = (float)(p + bcv);
      }
    }
  }
  __syncthreads();

  // ---- LSE partials + per-block top-10 per beam (plain stores) ----
  {
    double* lse_m = (double*)(ws + LSEM_F);
    double* lse_s = (double*)(ws + LSES_F);
    float*  cvv   = ws + CANDV_F;
    int*    cii   = (int*)(ws + CANDI_F);
    for (int b2 = wv; b2 < K_BEAM; b2 += 8) {
      double m = -1e300, s = 0.0;
      for (int vl = lane; vl < vn; vl += 64) {
        double val = (double)sh_lg[vl*K_BEAM + b2];
        double nm = fmax(m, val);
        s = s*exp(m - nm) + exp(val - nm); m = nm;
      }
      wave_merge_ms_d(m, s);
      if (lane == 0) { lse_m[blk*K_BEAM + b2] = m; lse_s[blk*K_BEAM + b2] = s; }
      #pragma unroll
      for (int pick = 0; pick < 10; ++pick) {
        float bv = -3e38f; int bi = 0x7ffffff0;
        for (int vl = lane; vl < vn; vl += 64) {
          float val = sh_lg[vl*K_BEAM + b2];
          if (val > bv || (val == bv && vl < bi)) { bv = val; bi = vl; }
        }
        wave_argmax_f(bv, bi);
        bv = __shfl(bv, 0, 64); bi = __shfl(bi, 0, 64);
        int wi = min(max(bi, 0), vn - 1);
        if (lane == 0) {
          cvv[(blk*K_BEAM + b2)*10 + pick] = bv;
          cii[(blk*K_BEAM + b2)*10 + pick] = v0 + wi;
        }
        if (bi >= 0 && bi < vn && (bi & 63) == lane) sh_lg[bi*K_BEAM + b2] = -3e38f;
      }
    }
  }
}

// ================= stepC: per-beam SEL, one block per beam (grid 10) ========
__global__ __launch_bounds__(NTHR) void stepC_kernel(float* __restrict__ ws, int step)
{
  const int tid  = threadIdx.x;
  const int j    = blockIdx.x;
  const int lane = tid & 63;
  const int wv   = tid >> 6;

  __shared__ double sh_wtv[80];
  __shared__ int    sh_wti[80];
  __shared__ double sh_base;

  const int par = step & 1;
  const float* mcur = ws + (par == 0 ? META_B_F : META_A_F);
  const double scj = ((const double*)(mcur + M_SC))[j];
  const int finj   = ((const int*)(mcur + M_FIN))[j];
  const bool masked = finj || (step == 0 && j > 0);

  if (wv == 0) {
    double m = -1e300, s = 0.0;
    for (int c = lane; c < NBLK; c += 64) {
      double mc  = ((const double*)(ws + LSEM_F))[c*K_BEAM + j];
      double sc2 = ((const double*)(ws + LSES_F))[c*K_BEAM + j];
      double nm = fmax(m, mc);
      s = s*exp(m - nm) + sc2*exp(mc - nm); m = nm;
    }
    wave_merge_ms_d(m, s);
    if (lane == 0) sh_base = scj - (m + log(s));
  }
  __syncthreads();
  const double base = sh_base;

  float rv[5]; int ri[5];
  #pragma unroll
  for (int k = 0; k < 5; ++k) {
    int c = wv*320 + 64*k + lane;
    int blkc = c / 10, p = c - blkc*10;
    int idx = (blkc*K_BEAM + j)*10 + p;
    rv[k] = (ws + CANDV_F)[idx];
    ri[k] = ((const int*)(ws + CANDI_F))[idx];
  }
  #pragma unroll
  for (int pick = 0; pick < 10; ++pick) {
    double lv = -1e301; int li = 0x7ffffff0;
    if (!masked) {
      #pragma unroll
      for (int k = 0; k < 5; ++k) {
        double val = base + (double)rv[k];
        int v = ri[k];
        if (val > lv || (val == lv && v < li)) { lv = val; li = v; }
      }
    }
    #pragma unroll
    for (int off = 32; off > 0; off >>= 1) {
      double ov = __shfl_down(lv, off, 64);
      int    oi = __shfl_down(li, off, 64);
      if (ov > lv || (ov == lv && oi < li)) { lv = ov; li = oi; }
    }
    lv = __shfl(lv, 0, 64); li = __shfl(li, 0, 64);
    if (!masked) {
      #pragma unroll
      for (int k = 0; k < 5; ++k) if (ri[k] == li) rv[k] = -3e38f;
    }
    if (lane == 0) { sh_wtv[wv*10 + pick] = lv; sh_wti[wv*10 + pick] = li; }
  }
  __syncthreads();

  if (wv == 0) {
    double av = (lane < 80) ? sh_wtv[lane] : -1e305;
    int    ai = (lane < 80) ? sh_wti[lane] : 0x7fffffff;
    const int c1 = lane + 64;
    double bv2 = (c1 < 80) ? sh_wtv[c1] : -1e305;
    int    bi2 = (c1 < 80) ? sh_wti[c1] : 0x7fffffff;
    #pragma unroll
    for (int pick = 0; pick < 10; ++pick) {
      bool tb = (bv2 > av) || (bv2 == av && bi2 < ai);
      double lv = tb ? bv2 : av;
      int    li = tb ? bi2 : ai;
      int    ls = tb ? c1  : lane;
      #pragma unroll
      for (int off = 32; off > 0; off >>= 1) {
        double ov = __shfl_down(lv, off, 64);
        int    oi = __shfl_down(li, off, 64);
        int    os = __shfl_down(ls, off, 64);
        if (ov > lv || (ov == lv && oi < li)) { lv = ov; li = oi; ls = os; }
      }
      ls = __shfl(ls, 0, 64);
      if (ls == lane) { av  = -1e305; ai  = 0x7fffffff; }
      if (ls == c1)   { bv2 = -1e305; bi2 = 0x7fffffff; }
      if (lane == 0) {
        double outv; int outf;
        if (finj) {
          outv = (pick == 0) ? scj : -1e301;
          outf = (pick == 0) ? (j*V_SZ + EOS_TOK) : 0x7ffffff0;
        } else if (step == 0 && j > 0) {
          outv = -1e301; outf = 0x7ffffff0;
        } else {
          outv = lv;
          outf = j*V_SZ + min(max(li, 0), V_SZ - 1);
        }
        ((double*)(ws + B10V_F))[j*10 + pick] = outv;
        ((int*)(ws + B10F_F))[j*10 + pick] = outf;
      }
    }
  }
}

// ================= final: merge100 + gather + output (1 block) ==============
__global__ __launch_bounds__(NTHR) void final_kernel(float* __restrict__ ws,
                                                     float* __restrict__ out)
{
  const int tid  = threadIdx.x;
  const int lane = tid & 63;
  const int wv   = tid >> 6;
  __shared__ double sh_selv[10];
  __shared__ int    sh_self[10];
  __shared__ int    sh_seqF[K_BEAM*SEQ_LEN];
  __shared__ int    sh_fpb[K_BEAM], sh_ftok[K_BEAM];

  if (wv == 0) merge100(ws, sh_selv, sh_self, lane);
  __syncthreads();
  const float* mA = ws + META_A_F;              // dst of step 29 (odd -> A)
  const int* seqA = (const int*)(mA + M_SEQ);
  if (tid < K_BEAM) {
    int f = sh_self[tid];
    int pb = f / V_SZ, tk2 = f - pb*V_SZ;
    sh_fpb[tid]  = min(max(pb, 0), K_BEAM - 1);
    sh_ftok[tid] = min(max(tk2, 0), V_SZ - 1);
  }
  __syncthreads();
  for (int t = tid; t < K_BEAM*SEQ_LEN; t += NTHR) {
    int j2 = t / SEQ_LEN, p = t - j2*SEQ_LEN;
    sh_seqF[t] = (p == MAXLEN) ? sh_ftok[j2] : seqA[sh_fpb[j2]*SEQ_LEN + p];
  }
  __syncthreads();
  if (tid < K_BEAM) {
    int first = -1;
    for (int p = 1; p <= MAXLEN; ++p)
      if (sh_seqF[tid*SEQ_LEN + p] == EOS_TOK) { first = p - 1; break; }
    double len = (first >= 0) ? (double)(first + 2) : (double)(MAXLEN + 2);
    double scv = sh_selv[tid];
    out[K_BEAM*SEQ_LEN + tid] = (float)scv;
    out[K_BEAM*SEQ_LEN + K_BEAM + tid] = (float)(scv / pow(len, 1.2));
  }
  for (int t = tid; t < K_BEAM*SEQ_LEN; t += NTHR) out[t] = (float)sh_seqF[t];
}

// ---------------- host ----------------
extern "C" void kernel_launch(void* const* d_in, const int* in_sizes, int n_in,
                              void* d_out, int out_size, void* d_ws, size_t ws_size,
                              hipStream_t stream) {
  (void)in_sizes; (void)n_in; (void)out_size; (void)ws_size;
  const float* enc_key    = (const float*)d_in[0];
  const float* enc_values = (const float*)d_in[1];
  const float* maskp      = (const float*)d_in[2];
  const float* embedding  = (const float*)d_in[3];
  const float* W_ih1      = (const float*)d_in[4];
  const float* W_hh1      = (const float*)d_in[5];
  const float* b_ih1      = (const float*)d_in[6];
  const float* b_hh1      = (const float*)d_in[7];
  const float* W_ih2      = (const float*)d_in[8];
  const float* W_hh2      = (const float*)d_in[9];
  const float* b_ih2      = (const float*)d_in[10];
  const float* b_hh2      = (const float*)d_in[11];
  const float* Wq         = (const float*)d_in[12];
  const float* bq         = (const float*)d_in[13];
  const float* Wc         = (const float*)d_in[14];
  const float* bc         = (const float*)d_in[15];
  float* ws  = (float*)d_ws;
  float* out = (float*)d_out;

  for (int i = 0; i < MAXLEN; ++i) {
    stepA1_kernel<<<8*K_BEAM, NTHR_A, 0, stream>>>(ws, i, embedding,
        W_ih1, W_hh1, b_ih1, b_hh1, W_ih2, W_hh2, b_ih2, b_hh2, Wq, bq);
    energy_kernel<<<8*K_BEAM, 256, 0, stream>>>(ws, enc_key);
    ctx_kernel<<<8*K_BEAM, 256, 0, stream>>>(ws, enc_values, maskp);
    stepB_kernel<<<NBLK, NTHR, 0, stream>>>(ws, i, Wc, bc);
    stepC_kernel<<<K_BEAM, NTHR, 0, stream>>>(ws, i);
  }
  final_kernel<<<1, NTHR, 0, stream>>>(ws, out);
}